// Round 24
// baseline (1435.376 us; speedup 1.0000x reference)
//
#include <hip/hip_runtime.h>

typedef unsigned int u32;
typedef unsigned short u16;

// problem sizes
#define BB 16
#define NN 2048
#define KK 20
#define EE (BB*NN*KK)      // 655360 edges
#define PP (BB*NN)         // 32768 points
#define NCHK 8             // kNN candidate chunks
#define CHKSZ (NN/NCHK)    // 256 candidates per chunk

// output element offsets (fp32 elements, tuple flattened in return order)
#define O_XPER 0
#define O_XCUB 3932160
#define O_Z    3962880
#define O_MU   3966976
#define O_LV   3971072
#define O_ASG  3975168

// ---- static device scratch: all write-before-read each call, no atomics ----
__device__ double g_part[524288];             // stats partials / kNN counters (4 MB)
__device__ double g_std[2560];                // reduced double sums
__device__ float  g_st[2560];                 // BN A/B per stage + stage3 A/B
__device__ float  g_zf[BB*256];               // z
__device__ float  g_Kf[BB*1024];              // Kf (B,64,16)
__device__ u16    g_idx[EE];                  // kNN indices
__device__ float  g_xpf[(size_t)PP*120];      // point-major x_per mirror (15.7 MB)
__device__ float  g_e1[(size_t)EE*60];        // knn chunk-tops -> y2a -> s3 partials
__device__ float  g_e2[(size_t)EE*60];        // knn T -> y1b -> U/V -> y2b

// double-sum bases in g_std: per 60-ch stage {sum@+0, sq@+64}
#define S1B_D 128
#define S2A_D 256
#define S2B_D 384
// A/B bases in g_st: per 60-ch stage {A@+0, B@+64}
#define S1A_AB 0
#define S1B_AB 128
#define S2A_AB 256
#define S2B_AB 384
#define S3A 512
#define S3B 1536

// stage3 partial layout in g_e1 (floats): MX@0, MN@131072, S@262144, Q@393216
#define P3_MX 0
#define P3_MN 131072
#define P3_S  262144
#define P3_Q  393216

#define NEG_BIG -1.0e30f

__device__ __forceinline__ float lrelu(float x){ return x > 0.f ? x : 0.2f*x; }

__device__ __forceinline__ void xrow(int bn, int c0, int cnt, float* d){
  const float* s = g_xpf + (size_t)bn*120 + c0;
  #pragma unroll 4
  for (int i=0;i<cnt;i+=4){
    float4 v = *(const float4*)(s+i);
    d[i]=v.x; d[i+1]=v.y; d[i+2]=v.z; d[i+3]=v.w;
  }
}

// shared pd computation: MUST be bit-identical across all kNN kernels
__device__ __forceinline__ float pdcalc(float4 pm, float qx, float qy, float qz, float qw){
  float dot = fmaf(qx,pm.x, fmaf(qy,pm.y, qz*pm.z));
  float t = fmaf(2.f, dot, -qw);
  return t - pm.w;                      // == -||q-p||^2
}

// ---- float-only top-20 chain (distances only; 2 VALU ops per stage)
#define KT_DECL \
  float td0=NEG_BIG,td1=NEG_BIG,td2=NEG_BIG,td3=NEG_BIG,td4=NEG_BIG, \
        td5=NEG_BIG,td6=NEG_BIG,td7=NEG_BIG,td8=NEG_BIG,td9=NEG_BIG, \
        td10=NEG_BIG,td11=NEG_BIG,td12=NEG_BIG,td13=NEG_BIG,td14=NEG_BIG, \
        td15=NEG_BIG,td16=NEG_BIG,td17=NEG_BIG,td18=NEG_BIG,td19=NEG_BIG;
#define KT_CSW(u,l) { float mx = fmaxf(td##u, td##l); float mn = fminf(td##u, td##l); td##u = mx; td##l = mn; }
#define KT_INSERT(pd) \
  if ((pd) > td19){ \
    td19 = (pd); \
    KT_CSW(18,19) KT_CSW(17,18) KT_CSW(16,17) KT_CSW(15,16) \
    KT_CSW(14,15) KT_CSW(13,14) KT_CSW(12,13) KT_CSW(11,12) \
    KT_CSW(10,11) KT_CSW(9,10)  KT_CSW(8,9)   KT_CSW(7,8)   \
    KT_CSW(6,7)   KT_CSW(5,6)   KT_CSW(4,5)   KT_CSW(3,4)   \
    KT_CSW(2,3)   KT_CSW(1,2)   KT_CSW(0,1) }

// ---------------- kNN pass 1
__global__ __launch_bounds__(128) void k_knnt(const float* __restrict__ xyz){
  __shared__ float4 cand[CHKSZ];
  int qg = blockIdx.x >> 3;
  int c  = blockIdx.x & 7;
  int b  = qg >> 4;
  int n0 = (qg & 15) << 7;
  int t  = threadIdx.x;
  int m0 = c*CHKSZ;
  for (int i=t;i<CHKSZ;i+=128){
    const float* s = xyz + ((size_t)((b<<11)+m0+i))*3;
    float x=s[0], y=s[1], z=s[2];
    cand[i] = make_float4(x,y,z, fmaf(x,x,fmaf(y,y,z*z)));
  }
  __syncthreads();
  int n = n0 + t;
  const float* qs = xyz + ((size_t)((b<<11)+n))*3;
  float qx=qs[0], qy=qs[1], qz=qs[2];
  float qw = fmaf(qx,qx,fmaf(qy,qy,qz*qz));
  KT_DECL
  for (int i=0;i<CHKSZ;i++){
    float pd = pdcalc(cand[i], qx,qy,qz,qw);
    KT_INSERT(pd)
  }
  int p = (b<<11) + n;
  float* outd = g_e1;
  #define KOUT(k) outd[(size_t)(c*KK+k)*PP + p] = td##k;
  KOUT(0) KOUT(1) KOUT(2) KOUT(3) KOUT(4) KOUT(5) KOUT(6) KOUT(7) KOUT(8) KOUT(9)
  KOUT(10) KOUT(11) KOUT(12) KOUT(13) KOUT(14) KOUT(15) KOUT(16) KOUT(17) KOUT(18) KOUT(19)
  #undef KOUT
}

// ---------------- kNN pass 2: exact 20th-largest threshold T[q]
__global__ __launch_bounds__(256) void k_knnu(){
  int q = blockIdx.x*256 + threadIdx.x;
  const float* ind = g_e1;
  KT_DECL
  for (int i=0;i<NCHK*KK;i++){
    float pd = ind[(size_t)i*PP + q];
    KT_INSERT(pd)
  }
  g_e2[q] = td19;
}

// ---------------- kNN pass 3: count pd>T, pd==T per (query, chunk)
__global__ __launch_bounds__(256) void k_knns1(const float* __restrict__ xyz){
  __shared__ float4 cand[CHKSZ];
  int gid = blockIdx.x*256 + threadIdx.x;
  int c = gid >> 15;
  int q = gid & (PP-1);
  int b = q >> 11;
  int t = threadIdx.x;
  for (int i=t;i<CHKSZ;i+=256){
    const float* s = xyz + ((size_t)((b<<11)+c*CHKSZ+i))*3;
    float x=s[0], y=s[1], z=s[2];
    cand[i] = make_float4(x,y,z, fmaf(x,x,fmaf(y,y,z*z)));
  }
  __syncthreads();
  const float* qs = xyz + (size_t)q*3;
  float qx=qs[0], qy=qs[1], qz=qs[2];
  float qw = fmaf(qx,qx,fmaf(qy,qy,qz*qz));
  float T = g_e2[q];
  u32 cgt=0, ceq=0;
  for (int i=0;i<CHKSZ;i++){
    float pd = pdcalc(cand[i], qx,qy,qz,qw);
    cgt += (pd > T) ? 1u : 0u;
    ceq += (pd == T) ? 1u : 0u;
  }
  u32* cntg = (u32*)g_part;
  u32* cnte = cntg + NCHK*PP;
  cntg[c*PP + q] = cgt;
  cnte[c*PP + q] = ceq;
}

// ---------------- kNN pass 4: prefix over chunks
__global__ __launch_bounds__(256) void k_knns2(){
  int q = blockIdx.x*256 + threadIdx.x;
  u32* cntg = (u32*)g_part;
  u32* cnte = cntg + NCHK*PP;
  u32* bg   = cnte + NCHK*PP;
  u32* be   = bg   + NCHK*PP;
  u32 acc = 0;
  for (int c=0;c<NCHK;c++){ bg[c*PP+q] = acc; acc += cntg[c*PP+q]; }
  u32 eacc = acc;
  for (int c=0;c<NCHK;c++){ be[c*PP+q] = eacc; eacc += cnte[c*PP+q]; }
}

// ---------------- kNN pass 5: write indices
__global__ __launch_bounds__(256) void k_knns3(const float* __restrict__ xyz){
  __shared__ float4 cand[CHKSZ];
  int gid = blockIdx.x*256 + threadIdx.x;
  int c = gid >> 15;
  int q = gid & (PP-1);
  int b = q >> 11;
  int t = threadIdx.x;
  for (int i=t;i<CHKSZ;i+=256){
    const float* s = xyz + ((size_t)((b<<11)+c*CHKSZ+i))*3;
    float x=s[0], y=s[1], z=s[2];
    cand[i] = make_float4(x,y,z, fmaf(x,x,fmaf(y,y,z*z)));
  }
  __syncthreads();
  const float* qs = xyz + (size_t)q*3;
  float qx=qs[0], qy=qs[1], qz=qs[2];
  float qw = fmaf(qx,qx,fmaf(qy,qy,qz*qz));
  float T = g_e2[q];
  const u32* cntg = (const u32*)g_part;
  const u32* cnte = cntg + NCHK*PP;
  const u32* bg   = cnte + NCHK*PP;
  const u32* be   = bg   + NCHK*PP;
  u32 wgt = bg[c*PP+q];
  u32 weq = be[c*PP+q];
  u16* o = g_idx + (size_t)q*KK;
  for (int i=0;i<CHKSZ;i++){
    float pd = pdcalc(cand[i], qx,qy,qz,qw);
    int m = c*CHKSZ + i;
    if (pd > T && wgt < KK){ o[wgt] = (u16)m; wgt++; }
    else if (pd == T && weq < KK){ o[weq] = (u16)m; weq++; }
  }
}

// ---------------- reduce per-block double partials into g_std[dbase..] (nblk blocks)
__global__ __launch_bounds__(256) void k_red60(int dbase, int nblk){
  __shared__ double red[256];
  int s = blockIdx.x;                   // slot 0..127
  int t = threadIdx.x;
  double acc = 0.0;
  for (int i=t;i<nblk;i+=256) acc += g_part[(size_t)i*128 + s];
  red[t] = acc; __syncthreads();
  for (int w=128; w>0; w>>=1){ if (t<w) red[t]+=red[t+w]; __syncthreads(); }
  if (t==0) g_std[dbase+s] = red[0];
}

// ---------------- BN finalize in double
__global__ __launch_bounds__(64) void k_fin(const float* __restrict__ g, const float* __restrict__ bb,
                                            int dbase, int abase, double invc){
  int c = threadIdx.x;
  if (c < 60){
    double m = g_std[dbase+c]*invc;
    double v = g_std[dbase+64+c]*invc - m*m;
    if (v < 0.0) v = 0.0;
    float r = (float)(1.0/sqrt(v + 1e-5));
    float a = r*g[c];
    g_st[abase+c] = a;
    g_st[abase+64+c] = bb[c] - (float)m*a;
  }
}

// ==== stage1a stats via 6x6 feat Gram: 320 blocks x 256 thr x 8 edges ====
__global__ __launch_bounds__(256) void k_gram1(const float* __restrict__ xyz){
  __shared__ double sred[128];
  int tid = threadIdx.x, lane = tid & 63, wv = tid >> 6;
  double acc[27];
  #pragma unroll
  for (int k=0;k<27;k++) acc[k]=0.0;
  for (int it=0; it<8; ++it){
    int edge = (it*320 + blockIdx.x)*256 + tid;
    int row = edge / KK;
    int b = row >> 11;
    int nbr = g_idx[edge];
    const float* cp = xyz + (size_t)row*3;
    const float* np2 = xyz + ((size_t)((b<<11)+nbr))*3;
    float f3=cp[0], f4=cp[1], f5=cp[2];
    float f0=np2[0]-f3, f1=np2[1]-f4, f2=np2[2]-f5;
    float f[6] = {f0,f1,f2,f3,f4,f5};
    #pragma unroll
    for (int i=0;i<6;i++) acc[i] += (double)f[i];
    int k=6;
    #pragma unroll
    for (int i=0;i<6;i++)
      #pragma unroll
      for (int j=i;j<6;j++){ acc[k] += (double)f[i]*(double)f[j]; k++; }
  }
  #pragma unroll
  for (int k=0;k<27;k++){
    double s = acc[k];
    #pragma unroll
    for (int m=1;m<64;m<<=1) s += __shfl_xor(s,m);
    if (lane==0) sred[wv*32+k] = s;
  }
  __syncthreads();
  if (tid < 27)
    g_part[(size_t)blockIdx.x*32 + tid] = sred[tid] + sred[32+tid] + sred[64+tid] + sred[96+tid];
}

// finalize stage1a stats from Gram: S = w.fsum, Q = w^T G w
__global__ __launch_bounds__(64) void k_fing1(const float* __restrict__ w1a,
                                              const float* __restrict__ gg, const float* __restrict__ bb){
  __shared__ double gsum[27];
  int t = threadIdx.x;
  if (t < 27){
    double s = 0.0;
    for (int i=0;i<320;i++) s += g_part[(size_t)i*32 + t];
    gsum[t] = s;
  }
  __syncthreads();
  if (t < 60){
    float w[6];
    #pragma unroll
    for (int i=0;i<6;i++) w[i] = w1a[t*6+i];
    double S = 0.0;
    #pragma unroll
    for (int i=0;i<6;i++) S += (double)w[i]*gsum[i];
    double Q = 0.0; int k = 6;
    #pragma unroll
    for (int i=0;i<6;i++)
      #pragma unroll
      for (int j=i;j<6;j++){
        double cf = (i==j) ? 1.0 : 2.0;
        Q += cf*(double)w[i]*(double)w[j]*gsum[k]; k++;
      }
    double inv1 = 1.0/(double)EE;
    double m = S*inv1;
    double v = Q*inv1 - m*m;
    if (v < 0.0) v = 0.0;
    float r = (float)(1.0/sqrt(v + 1e-5));
    float A = r*gg[t];
    g_st[S1A_AB+t] = A;
    g_st[S1A_AB+64+t] = bb[t] - (float)m*A;
  }
}

// ==== stage1 conv-b: recompute y1a inline; h=lrelu(affine); y1b=w1b.h -> g_e2 + stats ====
__global__ __launch_bounds__(256) void k_conv1b(const float* __restrict__ xyz,
                                                const float* __restrict__ w1a, const float* __restrict__ w1b){
  __shared__ float ws[360];
  __shared__ float wbs[3600];
  __shared__ float As[60], Bs[60];
  __shared__ double sred[512];
  int tid = threadIdx.x, lane = tid & 63, wv = tid >> 6;
  for (int i=tid;i<360;i+=256) ws[i]=w1a[i];
  for (int i=tid;i<3600;i+=256) wbs[i]=w1b[i];
  if (tid<60){ As[tid]=g_st[S1A_AB+tid]; Bs[tid]=g_st[S1A_AB+64+tid]; }
  __syncthreads();
  int edge = blockIdx.x*256 + tid;
  int row = edge / KK;
  int b = row >> 11;
  int nbr = g_idx[edge];
  const float* cp = xyz + (size_t)row*3;
  const float* np2 = xyz + ((size_t)((b<<11)+nbr))*3;
  float c0=cp[0], c1=cp[1], c2=cp[2];
  float d0=np2[0]-c0, d1=np2[1]-c1, d2=np2[2]-c2;
  float h[60];
  #pragma unroll 4
  for (int o=0;o<60;o++){
    float y = ws[o*6]*d0 + ws[o*6+1]*d1 + ws[o*6+2]*d2 + ws[o*6+3]*c0 + ws[o*6+4]*c1 + ws[o*6+5]*c2;
    h[o] = lrelu(fmaf(As[o], y, Bs[o]));
  }
  double rs=0.0, rq=0.0;
  for (int o=0;o<60;o++){
    float y=0.f;
    #pragma unroll
    for (int c=0;c<60;c++) y = fmaf(wbs[o*60+c], h[c], y);
    g_e2[(size_t)o*EE + edge] = y;
    float s=y, q=y*y;
    #pragma unroll
    for (int m=1;m<64;m<<=1){ s += __shfl_xor(s,m); q += __shfl_xor(q,m); }
    if (lane==o){ rs += (double)s; rq += (double)q; }
  }
  sred[wv*128 + lane] = rs;
  sred[wv*128 + 64 + lane] = rq;
  __syncthreads();
  if (tid < 128)
    g_part[(size_t)blockIdx.x*128 + tid] = sred[tid] + sred[128+tid] + sred[256+tid] + sred[384+tid];
}

// ==== stage1 final: x1[bn][o] = max_k lrelu(affine(y1b)).  60x128 blocks ====
__global__ __launch_bounds__(256) void k_final1s(float* __restrict__ outb){
  int o = blockIdx.x >> 7;
  int bn = ((blockIdx.x & 127) << 8) + threadIdx.x;
  int b = bn >> 11, n = bn & 2047;
  float A = g_st[S1B_AB+o], Bv = g_st[S1B_AB+64+o];
  const float* src = g_e2 + (size_t)o*EE + (size_t)bn*KK;
  float mx = NEG_BIG;
  #pragma unroll
  for (int k=0;k<KK;k++) mx = fmaxf(mx, lrelu(fmaf(A, src[k], Bv)));
  g_xpf[(size_t)bn*120 + o] = mx;
  outb[O_XPER + (size_t)(b*120+o)*NN + n] = mx;
}

// ==== stage2 point transforms: U = Wd.x1, V = (Wc-Wd).x1 -> g_e2 [p][64] ====
__global__ __launch_bounds__(256) void k_pgem2(const float* __restrict__ w2a){
  __shared__ float wd[3600], wcd[3600];
  int tid = threadIdx.x;
  for (int i=tid;i<3600;i+=256){
    int o = i/60, c = i%60;
    float a = w2a[o*120+c], bvl = w2a[o*120+60+c];
    wd[i] = a; wcd[i] = bvl - a;
  }
  __syncthreads();
  int p = blockIdx.x*256 + tid;
  float x[60];
  xrow(p, 0, 60, x);
  float* gU = g_e2;
  float* gV = g_e2 + (size_t)PP*64;
  #pragma unroll 4
  for (int o=0;o<60;o++){
    float u=0.f, v=0.f;
    #pragma unroll
    for (int c=0;c<60;c++){ u = fmaf(wd[o*60+c], x[c], u); v = fmaf(wcd[o*60+c], x[c], v); }
    gU[(size_t)p*64 + o] = u;
    gV[(size_t)p*64 + o] = v;
  }
}

// ==== stage2 conv-a: y2a = U[nbr] + V[center] -> g_e1 + butterfly stats ====
__global__ __launch_bounds__(256) void k_conv2a(){
  __shared__ double sred[512];
  int tid = threadIdx.x, lane = tid & 63, wv = tid >> 6;
  int edge = blockIdx.x*256 + tid;
  int row = edge / KK;
  int b = row >> 11;
  int nbr = g_idx[edge];
  int pn = (b<<11)+nbr;
  const float4* gU = (const float4*)g_e2;
  const float4* gV = (const float4*)(g_e2 + (size_t)PP*64);
  double rs=0.0, rq=0.0;
  #pragma unroll
  for (int o4=0;o4<15;o4++){
    float4 uu = gU[(size_t)pn*16 + o4];
    float4 vv = gV[(size_t)row*16 + o4];
    float y0=uu.x+vv.x, y1=uu.y+vv.y, y2=uu.z+vv.z, y3=uu.w+vv.w;
    g_e1[(size_t)(o4*4+0)*EE + edge] = y0;
    g_e1[(size_t)(o4*4+1)*EE + edge] = y1;
    g_e1[(size_t)(o4*4+2)*EE + edge] = y2;
    g_e1[(size_t)(o4*4+3)*EE + edge] = y3;
    float ys[4] = {y0,y1,y2,y3};
    #pragma unroll
    for (int j=0;j<4;j++){
      float s=ys[j], q=ys[j]*ys[j];
      #pragma unroll
      for (int m=1;m<64;m<<=1){ s += __shfl_xor(s,m); q += __shfl_xor(q,m); }
      if (lane==o4*4+j){ rs += (double)s; rq += (double)q; }
    }
  }
  sred[wv*128 + lane] = rs;
  sred[wv*128 + 64 + lane] = rq;
  __syncthreads();
  if (tid < 128)
    g_part[(size_t)blockIdx.x*128 + tid] = sred[tid] + sred[128+tid] + sred[256+tid] + sred[384+tid];
}

// ==== stage2 conv-b: h=lrelu(affine(y2a)); y2b=w2b.h -> g_e2 + stats ====
__global__ __launch_bounds__(256) void k_conv2b(const float* __restrict__ w2b){
  __shared__ float wbs[3600];
  __shared__ float As[60], Bs[60];
  __shared__ double sred[512];
  int tid = threadIdx.x, lane = tid & 63, wv = tid >> 6;
  for (int i=tid;i<3600;i+=256) wbs[i]=w2b[i];
  if (tid<60){ As[tid]=g_st[S2A_AB+tid]; Bs[tid]=g_st[S2A_AB+64+tid]; }
  __syncthreads();
  int edge = blockIdx.x*256 + tid;
  float h[60];
  #pragma unroll 4
  for (int o=0;o<60;o++) h[o] = lrelu(fmaf(As[o], g_e1[(size_t)o*EE + edge], Bs[o]));
  double rs=0.0, rq=0.0;
  for (int o=0;o<60;o++){
    float y=0.f;
    #pragma unroll
    for (int c=0;c<60;c++) y = fmaf(wbs[o*60+c], h[c], y);
    g_e2[(size_t)o*EE + edge] = y;
    float s=y, q=y*y;
    #pragma unroll
    for (int m=1;m<64;m<<=1){ s += __shfl_xor(s,m); q += __shfl_xor(q,m); }
    if (lane==o){ rs += (double)s; rq += (double)q; }
  }
  sred[wv*128 + lane] = rs;
  sred[wv*128 + 64 + lane] = rq;
  __syncthreads();
  if (tid < 128)
    g_part[(size_t)blockIdx.x*128 + tid] = sred[tid] + sred[128+tid] + sred[256+tid] + sred[384+tid];
}

// ==== stage2 final: x2 from g_e2 ====
__global__ __launch_bounds__(256) void k_final2s(float* __restrict__ outb){
  int o = blockIdx.x >> 7;
  int bn = ((blockIdx.x & 127) << 8) + threadIdx.x;
  int b = bn >> 11, n = bn & 2047;
  float A = g_st[S2B_AB+o], Bv = g_st[S2B_AB+64+o];
  const float* src = g_e2 + (size_t)o*EE + (size_t)bn*KK;
  float mx = NEG_BIG;
  #pragma unroll
  for (int k=0;k<KK;k++) mx = fmaxf(mx, lrelu(fmaf(A, src[k], Bv)));
  g_xpf[(size_t)bn*120 + 60 + o] = mx;
  outb[O_XPER + (size_t)(b*120+60+o)*NN + n] = mx;
}

// ==== stage3 fused, LDS-free: y3 from wave-uniform x loads; max/min/S/Q partials ====
// grid = 512 = seg(8) x b(16) x ec(4); 256 thr; e = ec*256+tid; 256 points per seg
__global__ __launch_bounds__(256) void k_max3s3(const float* __restrict__ wc3){
  int tid = threadIdx.x;
  int ec  = blockIdx.x & 3;
  int b   = (blockIdx.x >> 2) & 15;
  int seg = blockIdx.x >> 6;
  int e   = ec*256 + tid;
  float w[120];
  {
    const float4* wp = (const float4*)(wc3 + (size_t)e*120);
    #pragma unroll
    for (int c4=0;c4<30;c4++){
      float4 t = wp[c4];
      w[c4*4]=t.x; w[c4*4+1]=t.y; w[c4*4+2]=t.z; w[c4*4+3]=t.w;
    }
  }
  float mx = NEG_BIG, mn = -NEG_BIG, S = 0.f, Q = 0.f;
  int p0 = b*2048 + seg*256;
  for (int k=0;k<256;k++){
    const float4* xr = (const float4*)(g_xpf + (size_t)(p0+k)*120);  // wave-uniform
    float a0=0.f,a1=0.f,a2=0.f,a3=0.f;
    #pragma unroll
    for (int c4=0;c4<30;c4++){
      float4 xv = xr[c4];
      a0 = fmaf(w[c4*4],   xv.x, a0);
      a1 = fmaf(w[c4*4+1], xv.y, a1);
      a2 = fmaf(w[c4*4+2], xv.z, a2);
      a3 = fmaf(w[c4*4+3], xv.w, a3);
    }
    float y = (a0+a1)+(a2+a3);
    mx = fmaxf(mx, y);
    mn = fminf(mn, y);
    S += y;
    Q = fmaf(y, y, Q);
  }
  int slot = (seg*16+b)*1024 + e;
  g_e1[P3_MX + slot] = mx;
  g_e1[P3_MN + slot] = mn;
  g_e1[P3_S  + slot] = S;
  g_e1[P3_Q  + slot] = Q;
}

// stage3 finalize: reduce 128 S/Q partials per channel -> A3/B3
__global__ __launch_bounds__(64) void k_fin3R(const float* __restrict__ gg, const float* __restrict__ bb){
  int e = blockIdx.x*64 + threadIdx.x;  // grid 16
  double S=0.0, Q=0.0;
  for (int j=0;j<128;j++){
    S += (double)g_e1[P3_S + j*1024 + e];
    Q += (double)g_e1[P3_Q + j*1024 + e];
  }
  double inv3 = 1.0/(double)PP;
  double m = S*inv3;
  double v = Q*inv3 - m*m;
  if (v < 0.0) v = 0.0;
  float r = (float)(1.0/sqrt(v + 1e-5));
  float A = r*gg[e];
  g_st[S3A+e] = A;
  g_st[S3B+e] = bb[e] - (float)m*A;
}

// ---------------- VAE head: g from max/min + affine (monotone commute), then mu/lv/z
__global__ __launch_bounds__(256) void k_head(const float* __restrict__ eps,
                                              const float* __restrict__ wmu, const float* __restrict__ bmu,
                                              const float* __restrict__ wvar, const float* __restrict__ bvar,
                                              float* __restrict__ outb){
  int b = blockIdx.x, j = threadIdx.x;
  __shared__ float gs[1024];
  for (int i=j;i<1024;i+=256){
    float A = g_st[S3A+i], B = g_st[S3B+i];
    float M = NEG_BIG, m2 = -NEG_BIG;
    #pragma unroll
    for (int sg=0;sg<8;sg++){
      M  = fmaxf(M,  g_e1[P3_MX + (sg*16+b)*1024 + i]);
      m2 = fminf(m2, g_e1[P3_MN + (sg*16+b)*1024 + i]);
    }
    float y = (A > 0.f) ? M : ((A < 0.f) ? m2 : M);
    gs[i] = lrelu(fmaf(A, y, B));
  }
  __syncthreads();
  float mu = bmu[j], lv = bvar[j];
  const float4* wm = (const float4*)(wmu + (size_t)j*1024);
  const float4* wv = (const float4*)(wvar + (size_t)j*1024);
  #pragma unroll 4
  for (int e=0;e<256;e++){
    float4 a = wm[e], c = wv[e];
    const float* g4 = gs + e*4;
    mu = fmaf(a.x,g4[0], fmaf(a.y,g4[1], fmaf(a.z,g4[2], fmaf(a.w,g4[3], mu))));
    lv = fmaf(c.x,g4[0], fmaf(c.y,g4[1], fmaf(c.z,g4[2], fmaf(c.w,g4[3], lv))));
  }
  float z = fmaf(eps[b*256+j], expf(0.5f*lv), mu);
  g_zf[b*256+j] = z;
  outb[O_MU + b*256 + j] = mu;
  outb[O_LV + b*256 + j] = lv;
  outb[O_Z  + b*256 + j] = z;
}

// ---------------- cuboid branch
__global__ __launch_bounds__(256) void k_cuboid(const float* __restrict__ wenc,
                                                const float* __restrict__ wcub1, const float* __restrict__ wcub2,
                                                const float* __restrict__ wk, float* __restrict__ outb){
  int b = blockIdx.x, t = threadIdx.x;
  __shared__ float xc[320*16];
  __shared__ float hh[256*16];
  __shared__ float xq[120*16];
  for (int i=t;i<320*16;i+=256){
    int c = i>>4, m = i&15;
    xc[i] = (c<256) ? g_zf[b*256+c] : lrelu(wenc[(c-256)*16+m]);
  }
  __syncthreads();
  {
    float acc[16];
    #pragma unroll
    for (int m=0;m<16;m++) acc[m]=0.f;
    for (int c=0;c<320;c++){
      float wv = wcub1[(size_t)t*320+c];
      #pragma unroll
      for (int m=0;m<16;m++) acc[m] = fmaf(wv, xc[c*16+m], acc[m]);
    }
    #pragma unroll
    for (int m=0;m<16;m++) hh[t*16+m] = lrelu(acc[m]);
  }
  __syncthreads();
  if (t<120){
    float a2[16];
    #pragma unroll
    for (int m=0;m<16;m++) a2[m]=0.f;
    for (int c=0;c<256;c++){
      float wv = wcub2[(size_t)t*256+c];
      #pragma unroll
      for (int m=0;m<16;m++) a2[m] = fmaf(wv, hh[c*16+m], a2[m]);
    }
    #pragma unroll
    for (int m=0;m<16;m++){
      float v = lrelu(a2[m]);
      xq[t*16+m] = v;
      outb[O_XCUB + b*1920 + t*16 + m] = v;
    }
  }
  __syncthreads();
  if (t<64){
    float a3[16];
    #pragma unroll
    for (int m=0;m<16;m++) a3[m]=0.f;
    for (int c=0;c<120;c++){
      float wv = wk[t*120+c];
      #pragma unroll
      for (int m=0;m<16;m++) a3[m] = fmaf(wv, xq[c*16+m], a3[m]);
    }
    #pragma unroll
    for (int m=0;m<16;m++) g_Kf[b*1024 + t*16 + m] = a3[m];
  }
}

// ---------------- attention
__global__ __launch_bounds__(64) void k_attn(const float* __restrict__ wq, float* __restrict__ outb){
  int p = blockIdx.x*64 + threadIdx.x;
  int b = p >> 11;
  float x[120];
  xrow(p, 0, 120, x);
  float sc[16];
  #pragma unroll
  for (int m=0;m<16;m++) sc[m]=0.f;
  for (int a=0;a<64;a++){
    float q=0.f;
    #pragma unroll
    for (int c=0;c<120;c++) q = fmaf(wq[a*120+c], x[c], q);
    q *= 0.125f;
    const float* kf = g_Kf + b*1024 + a*16;
    #pragma unroll
    for (int m=0;m<16;m++) sc[m] = fmaf(kf[m], q, sc[m]);
  }
  float mx = sc[0];
  #pragma unroll
  for (int m=1;m<16;m++) mx = fmaxf(mx, sc[m]);
  float s=0.f;
  #pragma unroll
  for (int m=0;m<16;m++){ sc[m] = expf(sc[m]-mx); s += sc[m]; }
  float inv = 1.f/s;
  #pragma unroll
  for (int m=0;m<16;m++) outb[O_ASG + (size_t)p*16 + m] = sc[m]*inv;
}

extern "C" void kernel_launch(void* const* d_in, const int* in_sizes, int n_in,
                              void* d_out, int out_size, void* d_ws, size_t ws_size,
                              hipStream_t stream){
  const float* xyz  = (const float*)d_in[0];
  const float* eps  = (const float*)d_in[2];
  const float* w1a  = (const float*)d_in[3];
  const float* w1b  = (const float*)d_in[4];
  const float* w2a  = (const float*)d_in[5];
  const float* w2b  = (const float*)d_in[6];
  const float* wc3  = (const float*)d_in[7];
  const float* wmu  = (const float*)d_in[8];
  const float* bmu  = (const float*)d_in[9];
  const float* wvar = (const float*)d_in[10];
  const float* bvar = (const float*)d_in[11];
  const float* wenc = (const float*)d_in[12];
  const float* wcub1= (const float*)d_in[13];
  const float* wcub2= (const float*)d_in[14];
  const float* wq   = (const float*)d_in[15];
  const float* wk   = (const float*)d_in[16];
  const float* g1a  = (const float*)d_in[17];
  const float* b1a  = (const float*)d_in[18];
  const float* g1b  = (const float*)d_in[19];
  const float* b1b  = (const float*)d_in[20];
  const float* g2a  = (const float*)d_in[21];
  const float* b2a  = (const float*)d_in[22];
  const float* g2b  = (const float*)d_in[23];
  const float* b2b  = (const float*)d_in[24];
  const float* g3   = (const float*)d_in[25];
  const float* b3   = (const float*)d_in[26];
  float* outb = (float*)d_out;

  const double inv1 = 1.0/(double)EE;

  k_knnt<<<2048,128,0,stream>>>(xyz);
  k_knnu<<<128,256,0,stream>>>();
  k_knns1<<<1024,256,0,stream>>>(xyz);
  k_knns2<<<128,256,0,stream>>>();
  k_knns3<<<1024,256,0,stream>>>(xyz);
  // stage 1 (stats1a via feat-Gram; conv1a eliminated)
  k_gram1<<<320,256,0,stream>>>(xyz);
  k_fing1<<<1,64,0,stream>>>(w1a, g1a, b1a);
  k_conv1b<<<2560,256,0,stream>>>(xyz, w1a, w1b);
  k_red60<<<128,256,0,stream>>>(S1B_D, 2560);
  k_fin<<<1,64,0,stream>>>(g1b, b1b, S1B_D, S1B_AB, inv1);
  k_final1s<<<7680,256,0,stream>>>(outb);
  // stage 2
  k_pgem2<<<128,256,0,stream>>>(w2a);
  k_conv2a<<<2560,256,0,stream>>>();
  k_red60<<<128,256,0,stream>>>(S2A_D, 2560);
  k_fin<<<1,64,0,stream>>>(g2a, b2a, S2A_D, S2A_AB, inv1);
  k_conv2b<<<2560,256,0,stream>>>(w2b);
  k_red60<<<128,256,0,stream>>>(S2B_D, 2560);
  k_fin<<<1,64,0,stream>>>(g2b, b2b, S2B_D, S2B_AB, inv1);
  k_final2s<<<7680,256,0,stream>>>(outb);
  // stage 3 (fused, LDS-free: y3 never materialized)
  k_max3s3<<<512,256,0,stream>>>(wc3);
  k_fin3R<<<16,64,0,stream>>>(g3, b3);
  // heads
  k_head<<<16,256,0,stream>>>(eps, wmu, bmu, wvar, bvar, outb);
  k_cuboid<<<16,256,0,stream>>>(wenc, wcub1, wcub2, wk, outb);
  k_attn<<<512,64,0,stream>>>(wq, outb);
}

// Round 25
// 1300.411 us; speedup vs baseline: 1.1038x; 1.1038x over previous
//
#include <hip/hip_runtime.h>

typedef unsigned int u32;
typedef unsigned short u16;

// problem sizes
#define BB 16
#define NN 2048
#define KK 20
#define EE (BB*NN*KK)      // 655360 edges
#define PP (BB*NN)         // 32768 points
#define NCHK 8             // kNN candidate chunks
#define CHKSZ (NN/NCHK)    // 256 candidates per chunk

// output element offsets (fp32 elements, tuple flattened in return order)
#define O_XPER 0
#define O_XCUB 3932160
#define O_Z    3962880
#define O_MU   3966976
#define O_LV   3971072
#define O_ASG  3975168

// ---- static device scratch: all write-before-read each call, no atomics ----
__device__ double g_part[524288];             // stats partials / kNN counters (4 MB)
__device__ double g_std[2560];                // reduced double sums
__device__ float  g_st[2560];                 // BN A/B per stage + stage3 A/B
__device__ float  g_zf[BB*256];               // z
__device__ float  g_Kf[BB*1024];              // Kf (B,64,16)
__device__ u16    g_idx[EE];                  // kNN indices
__device__ float  g_xpf[(size_t)PP*120];      // point-major x_per mirror (15.7 MB)
__device__ float  g_e1[(size_t)EE*60];        // knn chunk-tops -> y2a
__device__ float  g_e2[(size_t)EE*60];        // knn T -> y1b -> U/V -> y2b

// double-sum bases in g_std: per 60-ch stage {sum@+0, sq@+64}
#define S1B_D 128
#define S2A_D 256
#define S2B_D 384
// A/B bases in g_st: per 60-ch stage {A@+0, B@+64}
#define S1A_AB 0
#define S1B_AB 128
#define S2A_AB 256
#define S2B_AB 384
#define S3A 512
#define S3B 1536

// g_part float region for stage3 partials (max/min/S/Q, 4x65536 floats)
#define MB_OFF 320000

#define NEG_BIG -1.0e30f

__device__ __forceinline__ float lrelu(float x){ return x > 0.f ? x : 0.2f*x; }

__device__ __forceinline__ void xrow(int bn, int c0, int cnt, float* d){
  const float* s = g_xpf + (size_t)bn*120 + c0;
  #pragma unroll 4
  for (int i=0;i<cnt;i+=4){
    float4 v = *(const float4*)(s+i);
    d[i]=v.x; d[i+1]=v.y; d[i+2]=v.z; d[i+3]=v.w;
  }
}

// shared pd computation: MUST be bit-identical across all kNN kernels
__device__ __forceinline__ float pdcalc(float4 pm, float qx, float qy, float qz, float qw){
  float dot = fmaf(qx,pm.x, fmaf(qy,pm.y, qz*pm.z));
  float t = fmaf(2.f, dot, -qw);
  return t - pm.w;                      // == -||q-p||^2
}

// ---- float-only top-20 chain (distances only; 2 VALU ops per stage)
#define KT_DECL \
  float td0=NEG_BIG,td1=NEG_BIG,td2=NEG_BIG,td3=NEG_BIG,td4=NEG_BIG, \
        td5=NEG_BIG,td6=NEG_BIG,td7=NEG_BIG,td8=NEG_BIG,td9=NEG_BIG, \
        td10=NEG_BIG,td11=NEG_BIG,td12=NEG_BIG,td13=NEG_BIG,td14=NEG_BIG, \
        td15=NEG_BIG,td16=NEG_BIG,td17=NEG_BIG,td18=NEG_BIG,td19=NEG_BIG;
#define KT_CSW(u,l) { float mx = fmaxf(td##u, td##l); float mn = fminf(td##u, td##l); td##u = mx; td##l = mn; }
#define KT_INSERT(pd) \
  if ((pd) > td19){ \
    td19 = (pd); \
    KT_CSW(18,19) KT_CSW(17,18) KT_CSW(16,17) KT_CSW(15,16) \
    KT_CSW(14,15) KT_CSW(13,14) KT_CSW(12,13) KT_CSW(11,12) \
    KT_CSW(10,11) KT_CSW(9,10)  KT_CSW(8,9)   KT_CSW(7,8)   \
    KT_CSW(6,7)   KT_CSW(5,6)   KT_CSW(4,5)   KT_CSW(3,4)   \
    KT_CSW(2,3)   KT_CSW(1,2)   KT_CSW(0,1) }

// ---------------- kNN pass 1
__global__ __launch_bounds__(128) void k_knnt(const float* __restrict__ xyz){
  __shared__ float4 cand[CHKSZ];
  int qg = blockIdx.x >> 3;
  int c  = blockIdx.x & 7;
  int b  = qg >> 4;
  int n0 = (qg & 15) << 7;
  int t  = threadIdx.x;
  int m0 = c*CHKSZ;
  for (int i=t;i<CHKSZ;i+=128){
    const float* s = xyz + ((size_t)((b<<11)+m0+i))*3;
    float x=s[0], y=s[1], z=s[2];
    cand[i] = make_float4(x,y,z, fmaf(x,x,fmaf(y,y,z*z)));
  }
  __syncthreads();
  int n = n0 + t;
  const float* qs = xyz + ((size_t)((b<<11)+n))*3;
  float qx=qs[0], qy=qs[1], qz=qs[2];
  float qw = fmaf(qx,qx,fmaf(qy,qy,qz*qz));
  KT_DECL
  for (int i=0;i<CHKSZ;i++){
    float pd = pdcalc(cand[i], qx,qy,qz,qw);
    KT_INSERT(pd)
  }
  int p = (b<<11) + n;
  float* outd = g_e1;
  #define KOUT(k) outd[(size_t)(c*KK+k)*PP + p] = td##k;
  KOUT(0) KOUT(1) KOUT(2) KOUT(3) KOUT(4) KOUT(5) KOUT(6) KOUT(7) KOUT(8) KOUT(9)
  KOUT(10) KOUT(11) KOUT(12) KOUT(13) KOUT(14) KOUT(15) KOUT(16) KOUT(17) KOUT(18) KOUT(19)
  #undef KOUT
}

// ---------------- kNN pass 2: exact 20th-largest threshold T[q]
__global__ __launch_bounds__(256) void k_knnu(){
  int q = blockIdx.x*256 + threadIdx.x;
  const float* ind = g_e1;
  KT_DECL
  for (int i=0;i<NCHK*KK;i++){
    float pd = ind[(size_t)i*PP + q];
    KT_INSERT(pd)
  }
  g_e2[q] = td19;
}

// ---------------- kNN pass 3: count pd>T, pd==T per (query, chunk)
__global__ __launch_bounds__(256) void k_knns1(const float* __restrict__ xyz){
  __shared__ float4 cand[CHKSZ];
  int gid = blockIdx.x*256 + threadIdx.x;
  int c = gid >> 15;
  int q = gid & (PP-1);
  int b = q >> 11;
  int t = threadIdx.x;
  for (int i=t;i<CHKSZ;i+=256){
    const float* s = xyz + ((size_t)((b<<11)+c*CHKSZ+i))*3;
    float x=s[0], y=s[1], z=s[2];
    cand[i] = make_float4(x,y,z, fmaf(x,x,fmaf(y,y,z*z)));
  }
  __syncthreads();
  const float* qs = xyz + (size_t)q*3;
  float qx=qs[0], qy=qs[1], qz=qs[2];
  float qw = fmaf(qx,qx,fmaf(qy,qy,qz*qz));
  float T = g_e2[q];
  u32 cgt=0, ceq=0;
  for (int i=0;i<CHKSZ;i++){
    float pd = pdcalc(cand[i], qx,qy,qz,qw);
    cgt += (pd > T) ? 1u : 0u;
    ceq += (pd == T) ? 1u : 0u;
  }
  u32* cntg = (u32*)g_part;
  u32* cnte = cntg + NCHK*PP;
  cntg[c*PP + q] = cgt;
  cnte[c*PP + q] = ceq;
}

// ---------------- kNN pass 4: prefix over chunks
__global__ __launch_bounds__(256) void k_knns2(){
  int q = blockIdx.x*256 + threadIdx.x;
  u32* cntg = (u32*)g_part;
  u32* cnte = cntg + NCHK*PP;
  u32* bg   = cnte + NCHK*PP;
  u32* be   = bg   + NCHK*PP;
  u32 acc = 0;
  for (int c=0;c<NCHK;c++){ bg[c*PP+q] = acc; acc += cntg[c*PP+q]; }
  u32 eacc = acc;
  for (int c=0;c<NCHK;c++){ be[c*PP+q] = eacc; eacc += cnte[c*PP+q]; }
}

// ---------------- kNN pass 5: write indices
__global__ __launch_bounds__(256) void k_knns3(const float* __restrict__ xyz){
  __shared__ float4 cand[CHKSZ];
  int gid = blockIdx.x*256 + threadIdx.x;
  int c = gid >> 15;
  int q = gid & (PP-1);
  int b = q >> 11;
  int t = threadIdx.x;
  for (int i=t;i<CHKSZ;i+=256){
    const float* s = xyz + ((size_t)((b<<11)+c*CHKSZ+i))*3;
    float x=s[0], y=s[1], z=s[2];
    cand[i] = make_float4(x,y,z, fmaf(x,x,fmaf(y,y,z*z)));
  }
  __syncthreads();
  const float* qs = xyz + (size_t)q*3;
  float qx=qs[0], qy=qs[1], qz=qs[2];
  float qw = fmaf(qx,qx,fmaf(qy,qy,qz*qz));
  float T = g_e2[q];
  const u32* cntg = (const u32*)g_part;
  const u32* cnte = cntg + NCHK*PP;
  const u32* bg   = cnte + NCHK*PP;
  const u32* be   = bg   + NCHK*PP;
  u32 wgt = bg[c*PP+q];
  u32 weq = be[c*PP+q];
  u16* o = g_idx + (size_t)q*KK;
  for (int i=0;i<CHKSZ;i++){
    float pd = pdcalc(cand[i], qx,qy,qz,qw);
    int m = c*CHKSZ + i;
    if (pd > T && wgt < KK){ o[wgt] = (u16)m; wgt++; }
    else if (pd == T && weq < KK){ o[weq] = (u16)m; weq++; }
  }
}

// ---------------- reduce per-block double partials into g_std[dbase..] (nblk blocks)
__global__ __launch_bounds__(256) void k_red60(int dbase, int nblk){
  __shared__ double red[256];
  int s = blockIdx.x;                   // slot 0..127
  int t = threadIdx.x;
  double acc = 0.0;
  for (int i=t;i<nblk;i+=256) acc += g_part[(size_t)i*128 + s];
  red[t] = acc; __syncthreads();
  for (int w=128; w>0; w>>=1){ if (t<w) red[t]+=red[t+w]; __syncthreads(); }
  if (t==0) g_std[dbase+s] = red[0];
}

// ---------------- BN finalize in double
__global__ __launch_bounds__(64) void k_fin(const float* __restrict__ g, const float* __restrict__ bb,
                                            int dbase, int abase, double invc){
  int c = threadIdx.x;
  if (c < 60){
    double m = g_std[dbase+c]*invc;
    double v = g_std[dbase+64+c]*invc - m*m;
    if (v < 0.0) v = 0.0;
    float r = (float)(1.0/sqrt(v + 1e-5));
    float a = r*g[c];
    g_st[abase+c] = a;
    g_st[abase+64+c] = bb[c] - (float)m*a;
  }
}

// ==== stage1a stats via 6x6 feat Gram: 320 blocks x 256 thr x 8 edges ====
__global__ __launch_bounds__(256) void k_gram1(const float* __restrict__ xyz){
  __shared__ double sred[128];
  int tid = threadIdx.x, lane = tid & 63, wv = tid >> 6;
  double acc[27];
  #pragma unroll
  for (int k=0;k<27;k++) acc[k]=0.0;
  for (int it=0; it<8; ++it){
    int edge = (it*320 + blockIdx.x)*256 + tid;
    int row = edge / KK;
    int b = row >> 11;
    int nbr = g_idx[edge];
    const float* cp = xyz + (size_t)row*3;
    const float* np2 = xyz + ((size_t)((b<<11)+nbr))*3;
    float f3=cp[0], f4=cp[1], f5=cp[2];
    float f0=np2[0]-f3, f1=np2[1]-f4, f2=np2[2]-f5;
    float f[6] = {f0,f1,f2,f3,f4,f5};
    #pragma unroll
    for (int i=0;i<6;i++) acc[i] += (double)f[i];
    int k=6;
    #pragma unroll
    for (int i=0;i<6;i++)
      #pragma unroll
      for (int j=i;j<6;j++){ acc[k] += (double)f[i]*(double)f[j]; k++; }
  }
  #pragma unroll
  for (int k=0;k<27;k++){
    double s = acc[k];
    #pragma unroll
    for (int m=1;m<64;m<<=1) s += __shfl_xor(s,m);
    if (lane==0) sred[wv*32+k] = s;
  }
  __syncthreads();
  if (tid < 27)
    g_part[(size_t)blockIdx.x*32 + tid] = sred[tid] + sred[32+tid] + sred[64+tid] + sred[96+tid];
}

// finalize stage1a stats from Gram: S = w.fsum, Q = w^T G w
__global__ __launch_bounds__(64) void k_fing1(const float* __restrict__ w1a,
                                              const float* __restrict__ gg, const float* __restrict__ bb){
  __shared__ double gsum[27];
  int t = threadIdx.x;
  if (t < 27){
    double s = 0.0;
    for (int i=0;i<320;i++) s += g_part[(size_t)i*32 + t];
    gsum[t] = s;
  }
  __syncthreads();
  if (t < 60){
    float w[6];
    #pragma unroll
    for (int i=0;i<6;i++) w[i] = w1a[t*6+i];
    double S = 0.0;
    #pragma unroll
    for (int i=0;i<6;i++) S += (double)w[i]*gsum[i];
    double Q = 0.0; int k = 6;
    #pragma unroll
    for (int i=0;i<6;i++)
      #pragma unroll
      for (int j=i;j<6;j++){
        double cf = (i==j) ? 1.0 : 2.0;
        Q += cf*(double)w[i]*(double)w[j]*gsum[k]; k++;
      }
    double inv1 = 1.0/(double)EE;
    double m = S*inv1;
    double v = Q*inv1 - m*m;
    if (v < 0.0) v = 0.0;
    float r = (float)(1.0/sqrt(v + 1e-5));
    float A = r*gg[t];
    g_st[S1A_AB+t] = A;
    g_st[S1A_AB+64+t] = bb[t] - (float)m*A;
  }
}

// ==== stage1 conv-b: recompute y1a inline; h=lrelu(affine); y1b=w1b.h -> g_e2 + stats ====
__global__ __launch_bounds__(256) void k_conv1b(const float* __restrict__ xyz,
                                                const float* __restrict__ w1a, const float* __restrict__ w1b){
  __shared__ float ws[360];
  __shared__ float wbs[3600];
  __shared__ float As[60], Bs[60];
  __shared__ double sred[512];
  int tid = threadIdx.x, lane = tid & 63, wv = tid >> 6;
  for (int i=tid;i<360;i+=256) ws[i]=w1a[i];
  for (int i=tid;i<3600;i+=256) wbs[i]=w1b[i];
  if (tid<60){ As[tid]=g_st[S1A_AB+tid]; Bs[tid]=g_st[S1A_AB+64+tid]; }
  __syncthreads();
  int edge = blockIdx.x*256 + tid;
  int row = edge / KK;
  int b = row >> 11;
  int nbr = g_idx[edge];
  const float* cp = xyz + (size_t)row*3;
  const float* np2 = xyz + ((size_t)((b<<11)+nbr))*3;
  float c0=cp[0], c1=cp[1], c2=cp[2];
  float d0=np2[0]-c0, d1=np2[1]-c1, d2=np2[2]-c2;
  float h[60];
  #pragma unroll 4
  for (int o=0;o<60;o++){
    float y = ws[o*6]*d0 + ws[o*6+1]*d1 + ws[o*6+2]*d2 + ws[o*6+3]*c0 + ws[o*6+4]*c1 + ws[o*6+5]*c2;
    h[o] = lrelu(fmaf(As[o], y, Bs[o]));
  }
  const float4* wb4 = (const float4*)wbs;
  double rs=0.0, rq=0.0;
  for (int o=0;o<60;o++){
    float y=0.f;
    #pragma unroll
    for (int c4=0;c4<15;c4++){
      float4 wvv = wb4[o*15+c4];
      y = fmaf(wvv.x, h[c4*4],   y);
      y = fmaf(wvv.y, h[c4*4+1], y);
      y = fmaf(wvv.z, h[c4*4+2], y);
      y = fmaf(wvv.w, h[c4*4+3], y);
    }
    g_e2[(size_t)o*EE + edge] = y;
    float s=y, q=y*y;
    #pragma unroll
    for (int m=1;m<64;m<<=1){ s += __shfl_xor(s,m); q += __shfl_xor(q,m); }
    if (lane==o){ rs += (double)s; rq += (double)q; }
  }
  sred[wv*128 + lane] = rs;
  sred[wv*128 + 64 + lane] = rq;
  __syncthreads();
  if (tid < 128)
    g_part[(size_t)blockIdx.x*128 + tid] = sred[tid] + sred[128+tid] + sred[256+tid] + sred[384+tid];
}

// ==== stage1 final: x1[bn][o] = max_k lrelu(affine(y1b)).  60x128 blocks ====
__global__ __launch_bounds__(256) void k_final1s(float* __restrict__ outb){
  int o = blockIdx.x >> 7;
  int bn = ((blockIdx.x & 127) << 8) + threadIdx.x;
  int b = bn >> 11, n = bn & 2047;
  float A = g_st[S1B_AB+o], Bv = g_st[S1B_AB+64+o];
  const float* src = g_e2 + (size_t)o*EE + (size_t)bn*KK;
  float mx = NEG_BIG;
  #pragma unroll
  for (int k=0;k<KK;k++) mx = fmaxf(mx, lrelu(fmaf(A, src[k], Bv)));
  g_xpf[(size_t)bn*120 + o] = mx;
  outb[O_XPER + (size_t)(b*120+o)*NN + n] = mx;
}

// ==== stage2 point transforms: U = Wd.x1, V = (Wc-Wd).x1 -> g_e2 [p][64] ====
__global__ __launch_bounds__(256) void k_pgem2(const float* __restrict__ w2a){
  __shared__ float wd[3600], wcd[3600];
  int tid = threadIdx.x;
  for (int i=tid;i<3600;i+=256){
    int o = i/60, c = i%60;
    float a = w2a[o*120+c], bvl = w2a[o*120+60+c];
    wd[i] = a; wcd[i] = bvl - a;
  }
  __syncthreads();
  int p = blockIdx.x*256 + tid;
  float x[60];
  xrow(p, 0, 60, x);
  float* gU = g_e2;
  float* gV = g_e2 + (size_t)PP*64;
  const float4* wd4  = (const float4*)wd;
  const float4* wcd4 = (const float4*)wcd;
  #pragma unroll 4
  for (int o=0;o<60;o++){
    float u=0.f, v=0.f;
    #pragma unroll
    for (int c4=0;c4<15;c4++){
      float4 a4 = wd4[o*15+c4];
      float4 b4 = wcd4[o*15+c4];
      u = fmaf(a4.x, x[c4*4],   u); v = fmaf(b4.x, x[c4*4],   v);
      u = fmaf(a4.y, x[c4*4+1], u); v = fmaf(b4.y, x[c4*4+1], v);
      u = fmaf(a4.z, x[c4*4+2], u); v = fmaf(b4.z, x[c4*4+2], v);
      u = fmaf(a4.w, x[c4*4+3], u); v = fmaf(b4.w, x[c4*4+3], v);
    }
    gU[(size_t)p*64 + o] = u;
    gV[(size_t)p*64 + o] = v;
  }
}

// ==== stage2 conv-a: y2a = U[nbr] + V[center] -> g_e1 + butterfly stats ====
__global__ __launch_bounds__(256) void k_conv2a(){
  __shared__ double sred[512];
  int tid = threadIdx.x, lane = tid & 63, wv = tid >> 6;
  int edge = blockIdx.x*256 + tid;
  int row = edge / KK;
  int b = row >> 11;
  int nbr = g_idx[edge];
  int pn = (b<<11)+nbr;
  const float4* gU = (const float4*)g_e2;
  const float4* gV = (const float4*)(g_e2 + (size_t)PP*64);
  double rs=0.0, rq=0.0;
  #pragma unroll
  for (int o4=0;o4<15;o4++){
    float4 uu = gU[(size_t)pn*16 + o4];
    float4 vv = gV[(size_t)row*16 + o4];
    float y0=uu.x+vv.x, y1=uu.y+vv.y, y2=uu.z+vv.z, y3=uu.w+vv.w;
    g_e1[(size_t)(o4*4+0)*EE + edge] = y0;
    g_e1[(size_t)(o4*4+1)*EE + edge] = y1;
    g_e1[(size_t)(o4*4+2)*EE + edge] = y2;
    g_e1[(size_t)(o4*4+3)*EE + edge] = y3;
    float ys[4] = {y0,y1,y2,y3};
    #pragma unroll
    for (int j=0;j<4;j++){
      float s=ys[j], q=ys[j]*ys[j];
      #pragma unroll
      for (int m=1;m<64;m<<=1){ s += __shfl_xor(s,m); q += __shfl_xor(q,m); }
      if (lane==o4*4+j){ rs += (double)s; rq += (double)q; }
    }
  }
  sred[wv*128 + lane] = rs;
  sred[wv*128 + 64 + lane] = rq;
  __syncthreads();
  if (tid < 128)
    g_part[(size_t)blockIdx.x*128 + tid] = sred[tid] + sred[128+tid] + sred[256+tid] + sred[384+tid];
}

// ==== stage2 conv-b: h=lrelu(affine(y2a)); y2b=w2b.h -> g_e2 + stats ====
__global__ __launch_bounds__(256) void k_conv2b(const float* __restrict__ w2b){
  __shared__ float wbs[3600];
  __shared__ float As[60], Bs[60];
  __shared__ double sred[512];
  int tid = threadIdx.x, lane = tid & 63, wv = tid >> 6;
  for (int i=tid;i<3600;i+=256) wbs[i]=w2b[i];
  if (tid<60){ As[tid]=g_st[S2A_AB+tid]; Bs[tid]=g_st[S2A_AB+64+tid]; }
  __syncthreads();
  int edge = blockIdx.x*256 + tid;
  float h[60];
  #pragma unroll 4
  for (int o=0;o<60;o++) h[o] = lrelu(fmaf(As[o], g_e1[(size_t)o*EE + edge], Bs[o]));
  const float4* wb4 = (const float4*)wbs;
  double rs=0.0, rq=0.0;
  for (int o=0;o<60;o++){
    float y=0.f;
    #pragma unroll
    for (int c4=0;c4<15;c4++){
      float4 wvv = wb4[o*15+c4];
      y = fmaf(wvv.x, h[c4*4],   y);
      y = fmaf(wvv.y, h[c4*4+1], y);
      y = fmaf(wvv.z, h[c4*4+2], y);
      y = fmaf(wvv.w, h[c4*4+3], y);
    }
    g_e2[(size_t)o*EE + edge] = y;
    float s=y, q=y*y;
    #pragma unroll
    for (int m=1;m<64;m<<=1){ s += __shfl_xor(s,m); q += __shfl_xor(q,m); }
    if (lane==o){ rs += (double)s; rq += (double)q; }
  }
  sred[wv*128 + lane] = rs;
  sred[wv*128 + 64 + lane] = rq;
  __syncthreads();
  if (tid < 128)
    g_part[(size_t)blockIdx.x*128 + tid] = sred[tid] + sred[128+tid] + sred[256+tid] + sred[384+tid];
}

// ==== stage2 final: x2 from g_e2 ====
__global__ __launch_bounds__(256) void k_final2s(float* __restrict__ outb){
  int o = blockIdx.x >> 7;
  int bn = ((blockIdx.x & 127) << 8) + threadIdx.x;
  int b = bn >> 11, n = bn & 2047;
  float A = g_st[S2B_AB+o], Bv = g_st[S2B_AB+64+o];
  const float* src = g_e2 + (size_t)o*EE + (size_t)bn*KK;
  float mx = NEG_BIG;
  #pragma unroll
  for (int k=0;k<KK;k++) mx = fmaxf(mx, lrelu(fmaf(A, src[k], Bv)));
  g_xpf[(size_t)bn*120 + 60 + o] = mx;
  outb[O_XPER + (size_t)(b*120+60+o)*NN + n] = mx;
}

// ==== stage3 fused: y3 in registers -> max/min + sum/sumsq partials, no materialization ====
// grid = 1024 = ec(16) x b(16) x seg(4); 256 thr = pj(4) x ei(64); seg covers 512 points
__global__ __launch_bounds__(256) void k_max3s2(const float* __restrict__ wc3){
  __shared__ float xt[64*120];          // 30.7 KB
  __shared__ float redA[256], redB[256], redS[256], redQ[256];
  int tid = threadIdx.x;
  int pj = tid>>6, ei = tid&63;
  int ec = blockIdx.x>>6;
  int b  = (blockIdx.x>>2)&15;
  int seg= blockIdx.x&3;
  int e  = ec*64 + ei;
  float w[120];
  {
    const float4* wp = (const float4*)(wc3 + (size_t)e*120);
    #pragma unroll
    for (int c4=0;c4<30;c4++){
      float4 t = wp[c4];
      w[c4*4]=t.x; w[c4*4+1]=t.y; w[c4*4+2]=t.z; w[c4*4+3]=t.w;
    }
  }
  float mx = NEG_BIG, mn = -NEG_BIG, S = 0.f, Q = 0.f;
  for (int tile=0; tile<8; tile++){
    int p0 = b*2048 + seg*512 + tile*64;
    __syncthreads();
    for (int v=tid; v<1920; v+=256){
      int pk = v/30, c4 = v%30;
      ((float4*)xt)[pk*30+c4] = *(const float4*)(g_xpf + (size_t)(p0+pk)*120 + c4*4);
    }
    __syncthreads();
    for (int k=pj*16; k<pj*16+16; k++){
      const float* xr = xt + k*120;
      float a0=0.f,a1=0.f,a2=0.f,a3=0.f;
      #pragma unroll
      for (int c=0;c<120;c+=4){
        a0 = fmaf(w[c],   xr[c],   a0);
        a1 = fmaf(w[c+1], xr[c+1], a1);
        a2 = fmaf(w[c+2], xr[c+2], a2);
        a3 = fmaf(w[c+3], xr[c+3], a3);
      }
      float y = (a0+a1)+(a2+a3);
      mx = fmaxf(mx, y);
      mn = fminf(mn, y);
      S += y;
      Q = fmaf(y, y, Q);
    }
  }
  __syncthreads();
  redA[tid]=mx; redB[tid]=mn; redS[tid]=S; redQ[tid]=Q;
  __syncthreads();
  if (pj==0){
    float M  = fmaxf(fmaxf(redA[ei],redA[64+ei]), fmaxf(redA[128+ei],redA[192+ei]));
    float m2 = fminf(fminf(redB[ei],redB[64+ei]), fminf(redB[128+ei],redB[192+ei]));
    float Ss = (redS[ei]+redS[64+ei])+(redS[128+ei]+redS[192+ei]);
    float Qs = (redQ[ei]+redQ[64+ei])+(redQ[128+ei]+redQ[192+ei]);
    float* MB = (float*)(g_part + MB_OFF);
    int slot = (seg*16+b)*1024 + e;
    MB[slot]          = M;
    MB[65536  + slot] = m2;
    MB[131072 + slot] = Ss;
    MB[196608 + slot] = Qs;
  }
}

// stage3 finalize: reduce 64 S/Q partials per channel -> A3/B3
__global__ __launch_bounds__(64) void k_fin3R(const float* __restrict__ gg, const float* __restrict__ bb){
  int e = blockIdx.x*64 + threadIdx.x;  // grid 16
  const float* MB = (const float*)(g_part + MB_OFF);
  double S=0.0, Q=0.0;
  for (int j=0;j<64;j++){
    S += (double)MB[131072 + j*1024 + e];
    Q += (double)MB[196608 + j*1024 + e];
  }
  double inv3 = 1.0/(double)PP;
  double m = S*inv3;
  double v = Q*inv3 - m*m;
  if (v < 0.0) v = 0.0;
  float r = (float)(1.0/sqrt(v + 1e-5));
  float A = r*gg[e];
  g_st[S3A+e] = A;
  g_st[S3B+e] = bb[e] - (float)m*A;
}

// ---------------- VAE head: g from max/min + affine (monotone commute), then mu/lv/z
__global__ __launch_bounds__(256) void k_head(const float* __restrict__ eps,
                                              const float* __restrict__ wmu, const float* __restrict__ bmu,
                                              const float* __restrict__ wvar, const float* __restrict__ bvar,
                                              float* __restrict__ outb){
  int b = blockIdx.x, j = threadIdx.x;
  __shared__ float gs[1024];
  const float* MB = (const float*)(g_part + MB_OFF);
  for (int i=j;i<1024;i+=256){
    float A = g_st[S3A+i], B = g_st[S3B+i];
    float M = NEG_BIG, m2 = -NEG_BIG;
    #pragma unroll
    for (int sg=0;sg<4;sg++){
      M  = fmaxf(M,  MB[(sg*16+b)*1024 + i]);
      m2 = fminf(m2, MB[65536 + (sg*16+b)*1024 + i]);
    }
    float y = (A > 0.f) ? M : ((A < 0.f) ? m2 : M);
    gs[i] = lrelu(fmaf(A, y, B));
  }
  __syncthreads();
  float mu = bmu[j], lv = bvar[j];
  const float4* wm = (const float4*)(wmu + (size_t)j*1024);
  const float4* wv = (const float4*)(wvar + (size_t)j*1024);
  #pragma unroll 4
  for (int e=0;e<256;e++){
    float4 a = wm[e], c = wv[e];
    const float* g4 = gs + e*4;
    mu = fmaf(a.x,g4[0], fmaf(a.y,g4[1], fmaf(a.z,g4[2], fmaf(a.w,g4[3], mu))));
    lv = fmaf(c.x,g4[0], fmaf(c.y,g4[1], fmaf(c.z,g4[2], fmaf(c.w,g4[3], lv))));
  }
  float z = fmaf(eps[b*256+j], expf(0.5f*lv), mu);
  g_zf[b*256+j] = z;
  outb[O_MU + b*256 + j] = mu;
  outb[O_LV + b*256 + j] = lv;
  outb[O_Z  + b*256 + j] = z;
}

// ---------------- cuboid branch
__global__ __launch_bounds__(256) void k_cuboid(const float* __restrict__ wenc,
                                                const float* __restrict__ wcub1, const float* __restrict__ wcub2,
                                                const float* __restrict__ wk, float* __restrict__ outb){
  int b = blockIdx.x, t = threadIdx.x;
  __shared__ float xc[320*16];
  __shared__ float hh[256*16];
  __shared__ float xq[120*16];
  for (int i=t;i<320*16;i+=256){
    int c = i>>4, m = i&15;
    xc[i] = (c<256) ? g_zf[b*256+c] : lrelu(wenc[(c-256)*16+m]);
  }
  __syncthreads();
  {
    float acc[16];
    #pragma unroll
    for (int m=0;m<16;m++) acc[m]=0.f;
    for (int c=0;c<320;c++){
      float wv = wcub1[(size_t)t*320+c];
      #pragma unroll
      for (int m=0;m<16;m++) acc[m] = fmaf(wv, xc[c*16+m], acc[m]);
    }
    #pragma unroll
    for (int m=0;m<16;m++) hh[t*16+m] = lrelu(acc[m]);
  }
  __syncthreads();
  if (t<120){
    float a2[16];
    #pragma unroll
    for (int m=0;m<16;m++) a2[m]=0.f;
    for (int c=0;c<256;c++){
      float wv = wcub2[(size_t)t*256+c];
      #pragma unroll
      for (int m=0;m<16;m++) a2[m] = fmaf(wv, hh[c*16+m], a2[m]);
    }
    #pragma unroll
    for (int m=0;m<16;m++){
      float v = lrelu(a2[m]);
      xq[t*16+m] = v;
      outb[O_XCUB + b*1920 + t*16 + m] = v;
    }
  }
  __syncthreads();
  if (t<64){
    float a3[16];
    #pragma unroll
    for (int m=0;m<16;m++) a3[m]=0.f;
    for (int c=0;c<120;c++){
      float wv = wk[t*120+c];
      #pragma unroll
      for (int m=0;m<16;m++) a3[m] = fmaf(wv, xq[c*16+m], a3[m]);
    }
    #pragma unroll
    for (int m=0;m<16;m++) g_Kf[b*1024 + t*16 + m] = a3[m];
  }
}

// ---------------- attention
__global__ __launch_bounds__(64) void k_attn(const float* __restrict__ wq, float* __restrict__ outb){
  int p = blockIdx.x*64 + threadIdx.x;
  int b = p >> 11;
  float x[120];
  xrow(p, 0, 120, x);
  float sc[16];
  #pragma unroll
  for (int m=0;m<16;m++) sc[m]=0.f;
  for (int a=0;a<64;a++){
    float q=0.f;
    #pragma unroll
    for (int c=0;c<120;c++) q = fmaf(wq[a*120+c], x[c], q);
    q *= 0.125f;
    const float* kf = g_Kf + b*1024 + a*16;
    #pragma unroll
    for (int m=0;m<16;m++) sc[m] = fmaf(kf[m], q, sc[m]);
  }
  float mx = sc[0];
  #pragma unroll
  for (int m=1;m<16;m++) mx = fmaxf(mx, sc[m]);
  float s=0.f;
  #pragma unroll
  for (int m=0;m<16;m++){ sc[m] = expf(sc[m]-mx); s += sc[m]; }
  float inv = 1.f/s;
  #pragma unroll
  for (int m=0;m<16;m++) outb[O_ASG + (size_t)p*16 + m] = sc[m]*inv;
}

extern "C" void kernel_launch(void* const* d_in, const int* in_sizes, int n_in,
                              void* d_out, int out_size, void* d_ws, size_t ws_size,
                              hipStream_t stream){
  const float* xyz  = (const float*)d_in[0];
  const float* eps  = (const float*)d_in[2];
  const float* w1a  = (const float*)d_in[3];
  const float* w1b  = (const float*)d_in[4];
  const float* w2a  = (const float*)d_in[5];
  const float* w2b  = (const float*)d_in[6];
  const float* wc3  = (const float*)d_in[7];
  const float* wmu  = (const float*)d_in[8];
  const float* bmu  = (const float*)d_in[9];
  const float* wvar = (const float*)d_in[10];
  const float* bvar = (const float*)d_in[11];
  const float* wenc = (const float*)d_in[12];
  const float* wcub1= (const float*)d_in[13];
  const float* wcub2= (const float*)d_in[14];
  const float* wq   = (const float*)d_in[15];
  const float* wk   = (const float*)d_in[16];
  const float* g1a  = (const float*)d_in[17];
  const float* b1a  = (const float*)d_in[18];
  const float* g1b  = (const float*)d_in[19];
  const float* b1b  = (const float*)d_in[20];
  const float* g2a  = (const float*)d_in[21];
  const float* b2a  = (const float*)d_in[22];
  const float* g2b  = (const float*)d_in[23];
  const float* b2b  = (const float*)d_in[24];
  const float* g3   = (const float*)d_in[25];
  const float* b3   = (const float*)d_in[26];
  float* outb = (float*)d_out;

  const double inv1 = 1.0/(double)EE;

  k_knnt<<<2048,128,0,stream>>>(xyz);
  k_knnu<<<128,256,0,stream>>>();
  k_knns1<<<1024,256,0,stream>>>(xyz);
  k_knns2<<<128,256,0,stream>>>();
  k_knns3<<<1024,256,0,stream>>>(xyz);
  // stage 1 (stats1a via feat-Gram; conv1a eliminated)
  k_gram1<<<320,256,0,stream>>>(xyz);
  k_fing1<<<1,64,0,stream>>>(w1a, g1a, b1a);
  k_conv1b<<<2560,256,0,stream>>>(xyz, w1a, w1b);
  k_red60<<<128,256,0,stream>>>(S1B_D, 2560);
  k_fin<<<1,64,0,stream>>>(g1b, b1b, S1B_D, S1B_AB, inv1);
  k_final1s<<<7680,256,0,stream>>>(outb);
  // stage 2
  k_pgem2<<<128,256,0,stream>>>(w2a);
  k_conv2a<<<2560,256,0,stream>>>();
  k_red60<<<128,256,0,stream>>>(S2A_D, 2560);
  k_fin<<<1,64,0,stream>>>(g2a, b2a, S2A_D, S2A_AB, inv1);
  k_conv2b<<<2560,256,0,stream>>>(w2b);
  k_red60<<<128,256,0,stream>>>(S2B_D, 2560);
  k_fin<<<1,64,0,stream>>>(g2b, b2b, S2B_D, S2B_AB, inv1);
  k_final2s<<<7680,256,0,stream>>>(outb);
  // stage 3 (fused: y3 never materialized; stats+max/min in one pass)
  k_max3s2<<<1024,256,0,stream>>>(wc3);
  k_fin3R<<<16,64,0,stream>>>(g3, b3);
  // heads
  k_head<<<16,256,0,stream>>>(eps, wmu, bmu, wvar, bvar, outb);
  k_cuboid<<<16,256,0,stream>>>(wenc, wcub1, wcub2, wk, outb);
  k_attn<<<512,64,0,stream>>>(wq, outb);
}

// Round 26
// 1300.238 us; speedup vs baseline: 1.1039x; 1.0001x over previous
//
#include <hip/hip_runtime.h>

typedef unsigned int u32;
typedef unsigned short u16;

// problem sizes
#define BB 16
#define NN 2048
#define KK 20
#define EE (BB*NN*KK)      // 655360 edges
#define PP (BB*NN)         // 32768 points
#define NCHK 8             // kNN candidate chunks
#define CHKSZ (NN/NCHK)    // 256 candidates per chunk

// output element offsets (fp32 elements, tuple flattened in return order)
#define O_XPER 0
#define O_XCUB 3932160
#define O_Z    3962880
#define O_MU   3966976
#define O_LV   3971072
#define O_ASG  3975168

// ---- static device scratch: all write-before-read each call, no atomics ----
__device__ double g_part[524288];             // stats partials / kNN counters (4 MB)
__device__ double g_std[2560];                // reduced double sums
__device__ float  g_st[2560];                 // BN A/B per stage + stage3 A/B
__device__ float  g_zf[BB*256];               // z
__device__ float  g_Kf[BB*1024];              // Kf (B,64,16)
__device__ u16    g_idx[EE];                  // kNN indices
__device__ float  g_xpf[(size_t)PP*120];      // point-major x_per mirror (15.7 MB)
__device__ float  g_e1[(size_t)EE*60];        // knn chunk-tops -> y2a
__device__ float  g_e2[(size_t)EE*60];        // knn T -> y1b -> U/V -> y2b

// double-sum bases in g_std: per 60-ch stage {sum@+0, sq@+64}
#define S1B_D 128
#define S2A_D 256
#define S2B_D 384
// A/B bases in g_st: per 60-ch stage {A@+0, B@+64}
#define S1A_AB 0
#define S1B_AB 128
#define S2A_AB 256
#define S2B_AB 384
#define S3A 512
#define S3B 1536

// g_part float region for stage3 partials (max/min/S/Q, 4x65536 floats)
#define MB_OFF 320000

#define NEG_BIG -1.0e30f

__device__ __forceinline__ float lrelu(float x){ return x > 0.f ? x : 0.2f*x; }

__device__ __forceinline__ void xrow(int bn, int c0, int cnt, float* d){
  const float* s = g_xpf + (size_t)bn*120 + c0;
  #pragma unroll 4
  for (int i=0;i<cnt;i+=4){
    float4 v = *(const float4*)(s+i);
    d[i]=v.x; d[i+1]=v.y; d[i+2]=v.z; d[i+3]=v.w;
  }
}

// shared pd computation: MUST be bit-identical across all kNN kernels
__device__ __forceinline__ float pdcalc(float4 pm, float qx, float qy, float qz, float qw){
  float dot = fmaf(qx,pm.x, fmaf(qy,pm.y, qz*pm.z));
  float t = fmaf(2.f, dot, -qw);
  return t - pm.w;                      // == -||q-p||^2
}

// ---- float-only top-20 chain (distances only; 2 VALU ops per stage)
#define KT_DECL \
  float td0=NEG_BIG,td1=NEG_BIG,td2=NEG_BIG,td3=NEG_BIG,td4=NEG_BIG, \
        td5=NEG_BIG,td6=NEG_BIG,td7=NEG_BIG,td8=NEG_BIG,td9=NEG_BIG, \
        td10=NEG_BIG,td11=NEG_BIG,td12=NEG_BIG,td13=NEG_BIG,td14=NEG_BIG, \
        td15=NEG_BIG,td16=NEG_BIG,td17=NEG_BIG,td18=NEG_BIG,td19=NEG_BIG;
#define KT_CSW(u,l) { float mx = fmaxf(td##u, td##l); float mn = fminf(td##u, td##l); td##u = mx; td##l = mn; }
#define KT_INSERT(pd) \
  if ((pd) > td19){ \
    td19 = (pd); \
    KT_CSW(18,19) KT_CSW(17,18) KT_CSW(16,17) KT_CSW(15,16) \
    KT_CSW(14,15) KT_CSW(13,14) KT_CSW(12,13) KT_CSW(11,12) \
    KT_CSW(10,11) KT_CSW(9,10)  KT_CSW(8,9)   KT_CSW(7,8)   \
    KT_CSW(6,7)   KT_CSW(5,6)   KT_CSW(4,5)   KT_CSW(3,4)   \
    KT_CSW(2,3)   KT_CSW(1,2)   KT_CSW(0,1) }

// ---------------- kNN pass 1
__global__ __launch_bounds__(128) void k_knnt(const float* __restrict__ xyz){
  __shared__ float4 cand[CHKSZ];
  int qg = blockIdx.x >> 3;
  int c  = blockIdx.x & 7;
  int b  = qg >> 4;
  int n0 = (qg & 15) << 7;
  int t  = threadIdx.x;
  int m0 = c*CHKSZ;
  for (int i=t;i<CHKSZ;i+=128){
    const float* s = xyz + ((size_t)((b<<11)+m0+i))*3;
    float x=s[0], y=s[1], z=s[2];
    cand[i] = make_float4(x,y,z, fmaf(x,x,fmaf(y,y,z*z)));
  }
  __syncthreads();
  int n = n0 + t;
  const float* qs = xyz + ((size_t)((b<<11)+n))*3;
  float qx=qs[0], qy=qs[1], qz=qs[2];
  float qw = fmaf(qx,qx,fmaf(qy,qy,qz*qz));
  KT_DECL
  for (int i=0;i<CHKSZ;i++){
    float pd = pdcalc(cand[i], qx,qy,qz,qw);
    KT_INSERT(pd)
  }
  int p = (b<<11) + n;
  float* outd = g_e1;
  #define KOUT(k) outd[(size_t)(c*KK+k)*PP + p] = td##k;
  KOUT(0) KOUT(1) KOUT(2) KOUT(3) KOUT(4) KOUT(5) KOUT(6) KOUT(7) KOUT(8) KOUT(9)
  KOUT(10) KOUT(11) KOUT(12) KOUT(13) KOUT(14) KOUT(15) KOUT(16) KOUT(17) KOUT(18) KOUT(19)
  #undef KOUT
}

// ---------------- kNN pass 2: exact 20th-largest threshold T[q]
__global__ __launch_bounds__(256) void k_knnu(){
  int q = blockIdx.x*256 + threadIdx.x;
  const float* ind = g_e1;
  KT_DECL
  for (int i=0;i<NCHK*KK;i++){
    float pd = ind[(size_t)i*PP + q];
    KT_INSERT(pd)
  }
  g_e2[q] = td19;
}

// ---------------- kNN pass 3: count pd>T, pd==T per (query, chunk)
__global__ __launch_bounds__(256) void k_knns1(const float* __restrict__ xyz){
  __shared__ float4 cand[CHKSZ];
  int gid = blockIdx.x*256 + threadIdx.x;
  int c = gid >> 15;
  int q = gid & (PP-1);
  int b = q >> 11;
  int t = threadIdx.x;
  for (int i=t;i<CHKSZ;i+=256){
    const float* s = xyz + ((size_t)((b<<11)+c*CHKSZ+i))*3;
    float x=s[0], y=s[1], z=s[2];
    cand[i] = make_float4(x,y,z, fmaf(x,x,fmaf(y,y,z*z)));
  }
  __syncthreads();
  const float* qs = xyz + (size_t)q*3;
  float qx=qs[0], qy=qs[1], qz=qs[2];
  float qw = fmaf(qx,qx,fmaf(qy,qy,qz*qz));
  float T = g_e2[q];
  u32 cgt=0, ceq=0;
  for (int i=0;i<CHKSZ;i++){
    float pd = pdcalc(cand[i], qx,qy,qz,qw);
    cgt += (pd > T) ? 1u : 0u;
    ceq += (pd == T) ? 1u : 0u;
  }
  u32* cntg = (u32*)g_part;
  u32* cnte = cntg + NCHK*PP;
  cntg[c*PP + q] = cgt;
  cnte[c*PP + q] = ceq;
}

// ---------------- kNN pass 4: prefix over chunks
__global__ __launch_bounds__(256) void k_knns2(){
  int q = blockIdx.x*256 + threadIdx.x;
  u32* cntg = (u32*)g_part;
  u32* cnte = cntg + NCHK*PP;
  u32* bg   = cnte + NCHK*PP;
  u32* be   = bg   + NCHK*PP;
  u32 acc = 0;
  for (int c=0;c<NCHK;c++){ bg[c*PP+q] = acc; acc += cntg[c*PP+q]; }
  u32 eacc = acc;
  for (int c=0;c<NCHK;c++){ be[c*PP+q] = eacc; eacc += cnte[c*PP+q]; }
}

// ---------------- kNN pass 5: write indices
__global__ __launch_bounds__(256) void k_knns3(const float* __restrict__ xyz){
  __shared__ float4 cand[CHKSZ];
  int gid = blockIdx.x*256 + threadIdx.x;
  int c = gid >> 15;
  int q = gid & (PP-1);
  int b = q >> 11;
  int t = threadIdx.x;
  for (int i=t;i<CHKSZ;i+=256){
    const float* s = xyz + ((size_t)((b<<11)+c*CHKSZ+i))*3;
    float x=s[0], y=s[1], z=s[2];
    cand[i] = make_float4(x,y,z, fmaf(x,x,fmaf(y,y,z*z)));
  }
  __syncthreads();
  const float* qs = xyz + (size_t)q*3;
  float qx=qs[0], qy=qs[1], qz=qs[2];
  float qw = fmaf(qx,qx,fmaf(qy,qy,qz*qz));
  float T = g_e2[q];
  const u32* cntg = (const u32*)g_part;
  const u32* cnte = cntg + NCHK*PP;
  const u32* bg   = cnte + NCHK*PP;
  const u32* be   = bg   + NCHK*PP;
  u32 wgt = bg[c*PP+q];
  u32 weq = be[c*PP+q];
  u16* o = g_idx + (size_t)q*KK;
  for (int i=0;i<CHKSZ;i++){
    float pd = pdcalc(cand[i], qx,qy,qz,qw);
    int m = c*CHKSZ + i;
    if (pd > T && wgt < KK){ o[wgt] = (u16)m; wgt++; }
    else if (pd == T && weq < KK){ o[weq] = (u16)m; weq++; }
  }
}

// ---------------- reduce per-block double partials into g_std[dbase..] (nblk blocks)
__global__ __launch_bounds__(256) void k_red60(int dbase, int nblk){
  __shared__ double red[256];
  int s = blockIdx.x;                   // slot 0..127
  int t = threadIdx.x;
  double acc = 0.0;
  for (int i=t;i<nblk;i+=256) acc += g_part[(size_t)i*128 + s];
  red[t] = acc; __syncthreads();
  for (int w=128; w>0; w>>=1){ if (t<w) red[t]+=red[t+w]; __syncthreads(); }
  if (t==0) g_std[dbase+s] = red[0];
}

// ---------------- BN finalize in double
__global__ __launch_bounds__(64) void k_fin(const float* __restrict__ g, const float* __restrict__ bb,
                                            int dbase, int abase, double invc){
  int c = threadIdx.x;
  if (c < 60){
    double m = g_std[dbase+c]*invc;
    double v = g_std[dbase+64+c]*invc - m*m;
    if (v < 0.0) v = 0.0;
    float r = (float)(1.0/sqrt(v + 1e-5));
    float a = r*g[c];
    g_st[abase+c] = a;
    g_st[abase+64+c] = bb[c] - (float)m*a;
  }
}

// ==== stage1a stats via 6x6 feat Gram: 320 blocks x 256 thr x 8 edges ====
__global__ __launch_bounds__(256) void k_gram1(const float* __restrict__ xyz){
  __shared__ double sred[128];
  int tid = threadIdx.x, lane = tid & 63, wv = tid >> 6;
  double acc[27];
  #pragma unroll
  for (int k=0;k<27;k++) acc[k]=0.0;
  for (int it=0; it<8; ++it){
    int edge = (it*320 + blockIdx.x)*256 + tid;
    int row = edge / KK;
    int b = row >> 11;
    int nbr = g_idx[edge];
    const float* cp = xyz + (size_t)row*3;
    const float* np2 = xyz + ((size_t)((b<<11)+nbr))*3;
    float f3=cp[0], f4=cp[1], f5=cp[2];
    float f0=np2[0]-f3, f1=np2[1]-f4, f2=np2[2]-f5;
    float f[6] = {f0,f1,f2,f3,f4,f5};
    #pragma unroll
    for (int i=0;i<6;i++) acc[i] += (double)f[i];
    int k=6;
    #pragma unroll
    for (int i=0;i<6;i++)
      #pragma unroll
      for (int j=i;j<6;j++){ acc[k] += (double)f[i]*(double)f[j]; k++; }
  }
  #pragma unroll
  for (int k=0;k<27;k++){
    double s = acc[k];
    #pragma unroll
    for (int m=1;m<64;m<<=1) s += __shfl_xor(s,m);
    if (lane==0) sred[wv*32+k] = s;
  }
  __syncthreads();
  if (tid < 27)
    g_part[(size_t)blockIdx.x*32 + tid] = sred[tid] + sred[32+tid] + sred[64+tid] + sred[96+tid];
}

// finalize stage1a stats from Gram: S = w.fsum, Q = w^T G w
__global__ __launch_bounds__(64) void k_fing1(const float* __restrict__ w1a,
                                              const float* __restrict__ gg, const float* __restrict__ bb){
  __shared__ double gsum[27];
  int t = threadIdx.x;
  if (t < 27){
    double s = 0.0;
    for (int i=0;i<320;i++) s += g_part[(size_t)i*32 + t];
    gsum[t] = s;
  }
  __syncthreads();
  if (t < 60){
    float w[6];
    #pragma unroll
    for (int i=0;i<6;i++) w[i] = w1a[t*6+i];
    double S = 0.0;
    #pragma unroll
    for (int i=0;i<6;i++) S += (double)w[i]*gsum[i];
    double Q = 0.0; int k = 6;
    #pragma unroll
    for (int i=0;i<6;i++)
      #pragma unroll
      for (int j=i;j<6;j++){
        double cf = (i==j) ? 1.0 : 2.0;
        Q += cf*(double)w[i]*(double)w[j]*gsum[k]; k++;
      }
    double inv1 = 1.0/(double)EE;
    double m = S*inv1;
    double v = Q*inv1 - m*m;
    if (v < 0.0) v = 0.0;
    float r = (float)(1.0/sqrt(v + 1e-5));
    float A = r*gg[t];
    g_st[S1A_AB+t] = A;
    g_st[S1A_AB+64+t] = bb[t] - (float)m*A;
  }
}

// ==== stage1 conv-b: recompute y1a inline; h=lrelu(affine); y1b=w1b.h -> g_e2 + stats ====
__global__ __launch_bounds__(256) void k_conv1b(const float* __restrict__ xyz,
                                                const float* __restrict__ w1a, const float* __restrict__ w1b){
  __shared__ float ws[360];
  __shared__ float wbs[3600];
  __shared__ float As[60], Bs[60];
  __shared__ double sred[512];
  int tid = threadIdx.x, lane = tid & 63, wv = tid >> 6;
  for (int i=tid;i<360;i+=256) ws[i]=w1a[i];
  for (int i=tid;i<3600;i+=256) wbs[i]=w1b[i];
  if (tid<60){ As[tid]=g_st[S1A_AB+tid]; Bs[tid]=g_st[S1A_AB+64+tid]; }
  __syncthreads();
  int edge = blockIdx.x*256 + tid;
  int row = edge / KK;
  int b = row >> 11;
  int nbr = g_idx[edge];
  const float* cp = xyz + (size_t)row*3;
  const float* np2 = xyz + ((size_t)((b<<11)+nbr))*3;
  float c0=cp[0], c1=cp[1], c2=cp[2];
  float d0=np2[0]-c0, d1=np2[1]-c1, d2=np2[2]-c2;
  float h[60];
  #pragma unroll 4
  for (int o=0;o<60;o++){
    float y = ws[o*6]*d0 + ws[o*6+1]*d1 + ws[o*6+2]*d2 + ws[o*6+3]*c0 + ws[o*6+4]*c1 + ws[o*6+5]*c2;
    h[o] = lrelu(fmaf(As[o], y, Bs[o]));
  }
  const float4* wb4 = (const float4*)wbs;
  double rs=0.0, rq=0.0;
  for (int o=0;o<60;o++){
    float y=0.f;
    #pragma unroll
    for (int c4=0;c4<15;c4++){
      float4 wvv = wb4[o*15+c4];
      y = fmaf(wvv.x, h[c4*4],   y);
      y = fmaf(wvv.y, h[c4*4+1], y);
      y = fmaf(wvv.z, h[c4*4+2], y);
      y = fmaf(wvv.w, h[c4*4+3], y);
    }
    g_e2[(size_t)o*EE + edge] = y;
    float s=y, q=y*y;
    #pragma unroll
    for (int m=1;m<64;m<<=1){ s += __shfl_xor(s,m); q += __shfl_xor(q,m); }
    if (lane==o){ rs += (double)s; rq += (double)q; }
  }
  sred[wv*128 + lane] = rs;
  sred[wv*128 + 64 + lane] = rq;
  __syncthreads();
  if (tid < 128)
    g_part[(size_t)blockIdx.x*128 + tid] = sred[tid] + sred[128+tid] + sred[256+tid] + sred[384+tid];
}

// ==== stage1 final: x1[bn][o] = max_k lrelu(affine(y1b)).  60x128 blocks ====
__global__ __launch_bounds__(256) void k_final1s(float* __restrict__ outb){
  int o = blockIdx.x >> 7;
  int bn = ((blockIdx.x & 127) << 8) + threadIdx.x;
  int b = bn >> 11, n = bn & 2047;
  float A = g_st[S1B_AB+o], Bv = g_st[S1B_AB+64+o];
  const float* src = g_e2 + (size_t)o*EE + (size_t)bn*KK;
  float mx = NEG_BIG;
  #pragma unroll
  for (int k=0;k<KK;k++) mx = fmaxf(mx, lrelu(fmaf(A, src[k], Bv)));
  g_xpf[(size_t)bn*120 + o] = mx;
  outb[O_XPER + (size_t)(b*120+o)*NN + n] = mx;
}

// ==== stage2 point transforms: U = Wd.x1, V = (Wc-Wd).x1 -> g_e2 [p][64] ====
__global__ __launch_bounds__(256) void k_pgem2(const float* __restrict__ w2a){
  __shared__ float wd[3600], wcd[3600];
  int tid = threadIdx.x;
  for (int i=tid;i<3600;i+=256){
    int o = i/60, c = i%60;
    float a = w2a[o*120+c], bvl = w2a[o*120+60+c];
    wd[i] = a; wcd[i] = bvl - a;
  }
  __syncthreads();
  int p = blockIdx.x*256 + tid;
  float x[60];
  xrow(p, 0, 60, x);
  float* gU = g_e2;
  float* gV = g_e2 + (size_t)PP*64;
  const float4* wd4  = (const float4*)wd;
  const float4* wcd4 = (const float4*)wcd;
  #pragma unroll 4
  for (int o=0;o<60;o++){
    float u=0.f, v=0.f;
    #pragma unroll
    for (int c4=0;c4<15;c4++){
      float4 a4 = wd4[o*15+c4];
      float4 b4 = wcd4[o*15+c4];
      u = fmaf(a4.x, x[c4*4],   u); v = fmaf(b4.x, x[c4*4],   v);
      u = fmaf(a4.y, x[c4*4+1], u); v = fmaf(b4.y, x[c4*4+1], v);
      u = fmaf(a4.z, x[c4*4+2], u); v = fmaf(b4.z, x[c4*4+2], v);
      u = fmaf(a4.w, x[c4*4+3], u); v = fmaf(b4.w, x[c4*4+3], v);
    }
    gU[(size_t)p*64 + o] = u;
    gV[(size_t)p*64 + o] = v;
  }
}

// ==== stage2 conv-a: y2a = U[nbr] + V[center] -> g_e1 + butterfly stats ====
__global__ __launch_bounds__(256) void k_conv2a(){
  __shared__ double sred[512];
  int tid = threadIdx.x, lane = tid & 63, wv = tid >> 6;
  int edge = blockIdx.x*256 + tid;
  int row = edge / KK;
  int b = row >> 11;
  int nbr = g_idx[edge];
  int pn = (b<<11)+nbr;
  const float4* gU = (const float4*)g_e2;
  const float4* gV = (const float4*)(g_e2 + (size_t)PP*64);
  double rs=0.0, rq=0.0;
  #pragma unroll
  for (int o4=0;o4<15;o4++){
    float4 uu = gU[(size_t)pn*16 + o4];
    float4 vv = gV[(size_t)row*16 + o4];
    float y0=uu.x+vv.x, y1=uu.y+vv.y, y2=uu.z+vv.z, y3=uu.w+vv.w;
    g_e1[(size_t)(o4*4+0)*EE + edge] = y0;
    g_e1[(size_t)(o4*4+1)*EE + edge] = y1;
    g_e1[(size_t)(o4*4+2)*EE + edge] = y2;
    g_e1[(size_t)(o4*4+3)*EE + edge] = y3;
    float ys[4] = {y0,y1,y2,y3};
    #pragma unroll
    for (int j=0;j<4;j++){
      float s=ys[j], q=ys[j]*ys[j];
      #pragma unroll
      for (int m=1;m<64;m<<=1){ s += __shfl_xor(s,m); q += __shfl_xor(q,m); }
      if (lane==o4*4+j){ rs += (double)s; rq += (double)q; }
    }
  }
  sred[wv*128 + lane] = rs;
  sred[wv*128 + 64 + lane] = rq;
  __syncthreads();
  if (tid < 128)
    g_part[(size_t)blockIdx.x*128 + tid] = sred[tid] + sred[128+tid] + sred[256+tid] + sred[384+tid];
}

// ==== stage2 conv-b: h=lrelu(affine(y2a)); y2b=w2b.h -> g_e2 + stats ====
__global__ __launch_bounds__(256) void k_conv2b(const float* __restrict__ w2b){
  __shared__ float wbs[3600];
  __shared__ float As[60], Bs[60];
  __shared__ double sred[512];
  int tid = threadIdx.x, lane = tid & 63, wv = tid >> 6;
  for (int i=tid;i<3600;i+=256) wbs[i]=w2b[i];
  if (tid<60){ As[tid]=g_st[S2A_AB+tid]; Bs[tid]=g_st[S2A_AB+64+tid]; }
  __syncthreads();
  int edge = blockIdx.x*256 + tid;
  float h[60];
  #pragma unroll 4
  for (int o=0;o<60;o++) h[o] = lrelu(fmaf(As[o], g_e1[(size_t)o*EE + edge], Bs[o]));
  const float4* wb4 = (const float4*)wbs;
  double rs=0.0, rq=0.0;
  for (int o=0;o<60;o++){
    float y=0.f;
    #pragma unroll
    for (int c4=0;c4<15;c4++){
      float4 wvv = wb4[o*15+c4];
      y = fmaf(wvv.x, h[c4*4],   y);
      y = fmaf(wvv.y, h[c4*4+1], y);
      y = fmaf(wvv.z, h[c4*4+2], y);
      y = fmaf(wvv.w, h[c4*4+3], y);
    }
    g_e2[(size_t)o*EE + edge] = y;
    float s=y, q=y*y;
    #pragma unroll
    for (int m=1;m<64;m<<=1){ s += __shfl_xor(s,m); q += __shfl_xor(q,m); }
    if (lane==o){ rs += (double)s; rq += (double)q; }
  }
  sred[wv*128 + lane] = rs;
  sred[wv*128 + 64 + lane] = rq;
  __syncthreads();
  if (tid < 128)
    g_part[(size_t)blockIdx.x*128 + tid] = sred[tid] + sred[128+tid] + sred[256+tid] + sred[384+tid];
}

// ==== stage2 final: x2 from g_e2 ====
__global__ __launch_bounds__(256) void k_final2s(float* __restrict__ outb){
  int o = blockIdx.x >> 7;
  int bn = ((blockIdx.x & 127) << 8) + threadIdx.x;
  int b = bn >> 11, n = bn & 2047;
  float A = g_st[S2B_AB+o], Bv = g_st[S2B_AB+64+o];
  const float* src = g_e2 + (size_t)o*EE + (size_t)bn*KK;
  float mx = NEG_BIG;
  #pragma unroll
  for (int k=0;k<KK;k++) mx = fmaxf(mx, lrelu(fmaf(A, src[k], Bv)));
  g_xpf[(size_t)bn*120 + 60 + o] = mx;
  outb[O_XPER + (size_t)(b*120+60+o)*NN + n] = mx;
}

// ==== stage3 fused: y3 in registers -> max/min + sum/sumsq partials, no materialization ====
// grid = 1024 = ec(16) x b(16) x seg(4); 256 thr = pj(4) x ei(64); seg covers 512 points
// w row held in 30 NAMED float4 registers (compile-time indexing; launch_bounds(256,1) frees VGPRs)
#define W_DECL(i) float4 W##i;
#define W_LOAD(i) W##i = wp[i];
#define W_DOT(i)  { float4 xv = xr4[i]; \
  a0 = fmaf(W##i.x, xv.x, a0); a1 = fmaf(W##i.y, xv.y, a1); \
  a2 = fmaf(W##i.z, xv.z, a2); a3 = fmaf(W##i.w, xv.w, a3); }
#define W_ALL(OP) \
  OP(0) OP(1) OP(2) OP(3) OP(4) OP(5) OP(6) OP(7) OP(8) OP(9) \
  OP(10) OP(11) OP(12) OP(13) OP(14) OP(15) OP(16) OP(17) OP(18) OP(19) \
  OP(20) OP(21) OP(22) OP(23) OP(24) OP(25) OP(26) OP(27) OP(28) OP(29)

__global__ __launch_bounds__(256, 1) void k_max3s2(const float* __restrict__ wc3){
  __shared__ float xt[64*120];          // 30.7 KB
  __shared__ float redA[256], redB[256], redS[256], redQ[256];
  int tid = threadIdx.x;
  int pj = tid>>6, ei = tid&63;
  int ec = blockIdx.x>>6;
  int b  = (blockIdx.x>>2)&15;
  int seg= blockIdx.x&3;
  int e  = ec*64 + ei;
  W_ALL(W_DECL)
  {
    const float4* wp = (const float4*)(wc3 + (size_t)e*120);
    W_ALL(W_LOAD)
  }
  float mx = NEG_BIG, mn = -NEG_BIG, S = 0.f, Q = 0.f;
  for (int tile=0; tile<8; tile++){
    int p0 = b*2048 + seg*512 + tile*64;
    __syncthreads();
    for (int v=tid; v<1920; v+=256){
      int pk = v/30, c4 = v%30;
      ((float4*)xt)[pk*30+c4] = *(const float4*)(g_xpf + (size_t)(p0+pk)*120 + c4*4);
    }
    __syncthreads();
    for (int k=pj*16; k<pj*16+16; k++){
      const float4* xr4 = (const float4*)(xt + k*120);
      float a0=0.f,a1=0.f,a2=0.f,a3=0.f;
      W_ALL(W_DOT)
      float y = (a0+a1)+(a2+a3);
      mx = fmaxf(mx, y);
      mn = fminf(mn, y);
      S += y;
      Q = fmaf(y, y, Q);
    }
  }
  __syncthreads();
  redA[tid]=mx; redB[tid]=mn; redS[tid]=S; redQ[tid]=Q;
  __syncthreads();
  if (pj==0){
    float M  = fmaxf(fmaxf(redA[ei],redA[64+ei]), fmaxf(redA[128+ei],redA[192+ei]));
    float m2 = fminf(fminf(redB[ei],redB[64+ei]), fminf(redB[128+ei],redB[192+ei]));
    float Ss = (redS[ei]+redS[64+ei])+(redS[128+ei]+redS[192+ei]);
    float Qs = (redQ[ei]+redQ[64+ei])+(redQ[128+ei]+redQ[192+ei]);
    float* MB = (float*)(g_part + MB_OFF);
    int slot = (seg*16+b)*1024 + e;
    MB[slot]          = M;
    MB[65536  + slot] = m2;
    MB[131072 + slot] = Ss;
    MB[196608 + slot] = Qs;
  }
}

// stage3 finalize: reduce 64 S/Q partials per channel -> A3/B3
__global__ __launch_bounds__(64) void k_fin3R(const float* __restrict__ gg, const float* __restrict__ bb){
  int e = blockIdx.x*64 + threadIdx.x;  // grid 16
  const float* MB = (const float*)(g_part + MB_OFF);
  double S=0.0, Q=0.0;
  for (int j=0;j<64;j++){
    S += (double)MB[131072 + j*1024 + e];
    Q += (double)MB[196608 + j*1024 + e];
  }
  double inv3 = 1.0/(double)PP;
  double m = S*inv3;
  double v = Q*inv3 - m*m;
  if (v < 0.0) v = 0.0;
  float r = (float)(1.0/sqrt(v + 1e-5));
  float A = r*gg[e];
  g_st[S3A+e] = A;
  g_st[S3B+e] = bb[e] - (float)m*A;
}

// ---------------- VAE head: g from max/min + affine (monotone commute), then mu/lv/z
__global__ __launch_bounds__(256) void k_head(const float* __restrict__ eps,
                                              const float* __restrict__ wmu, const float* __restrict__ bmu,
                                              const float* __restrict__ wvar, const float* __restrict__ bvar,
                                              float* __restrict__ outb){
  int b = blockIdx.x, j = threadIdx.x;
  __shared__ float gs[1024];
  const float* MB = (const float*)(g_part + MB_OFF);
  for (int i=j;i<1024;i+=256){
    float A = g_st[S3A+i], B = g_st[S3B+i];
    float M = NEG_BIG, m2 = -NEG_BIG;
    #pragma unroll
    for (int sg=0;sg<4;sg++){
      M  = fmaxf(M,  MB[(sg*16+b)*1024 + i]);
      m2 = fminf(m2, MB[65536 + (sg*16+b)*1024 + i]);
    }
    float y = (A > 0.f) ? M : ((A < 0.f) ? m2 : M);
    gs[i] = lrelu(fmaf(A, y, B));
  }
  __syncthreads();
  float mu = bmu[j], lv = bvar[j];
  const float4* wm = (const float4*)(wmu + (size_t)j*1024);
  const float4* wv = (const float4*)(wvar + (size_t)j*1024);
  #pragma unroll 4
  for (int e=0;e<256;e++){
    float4 a = wm[e], c = wv[e];
    const float* g4 = gs + e*4;
    mu = fmaf(a.x,g4[0], fmaf(a.y,g4[1], fmaf(a.z,g4[2], fmaf(a.w,g4[3], mu))));
    lv = fmaf(c.x,g4[0], fmaf(c.y,g4[1], fmaf(c.z,g4[2], fmaf(c.w,g4[3], lv))));
  }
  float z = fmaf(eps[b*256+j], expf(0.5f*lv), mu);
  g_zf[b*256+j] = z;
  outb[O_MU + b*256 + j] = mu;
  outb[O_LV + b*256 + j] = lv;
  outb[O_Z  + b*256 + j] = z;
}

// ---------------- cuboid branch
__global__ __launch_bounds__(256) void k_cuboid(const float* __restrict__ wenc,
                                                const float* __restrict__ wcub1, const float* __restrict__ wcub2,
                                                const float* __restrict__ wk, float* __restrict__ outb){
  int b = blockIdx.x, t = threadIdx.x;
  __shared__ float xc[320*16];
  __shared__ float hh[256*16];
  __shared__ float xq[120*16];
  for (int i=t;i<320*16;i+=256){
    int c = i>>4, m = i&15;
    xc[i] = (c<256) ? g_zf[b*256+c] : lrelu(wenc[(c-256)*16+m]);
  }
  __syncthreads();
  {
    float acc[16];
    #pragma unroll
    for (int m=0;m<16;m++) acc[m]=0.f;
    for (int c=0;c<320;c++){
      float wv = wcub1[(size_t)t*320+c];
      #pragma unroll
      for (int m=0;m<16;m++) acc[m] = fmaf(wv, xc[c*16+m], acc[m]);
    }
    #pragma unroll
    for (int m=0;m<16;m++) hh[t*16+m] = lrelu(acc[m]);
  }
  __syncthreads();
  if (t<120){
    float a2[16];
    #pragma unroll
    for (int m=0;m<16;m++) a2[m]=0.f;
    for (int c=0;c<256;c++){
      float wv = wcub2[(size_t)t*256+c];
      #pragma unroll
      for (int m=0;m<16;m++) a2[m] = fmaf(wv, hh[c*16+m], a2[m]);
    }
    #pragma unroll
    for (int m=0;m<16;m++){
      float v = lrelu(a2[m]);
      xq[t*16+m] = v;
      outb[O_XCUB + b*1920 + t*16 + m] = v;
    }
  }
  __syncthreads();
  if (t<64){
    float a3[16];
    #pragma unroll
    for (int m=0;m<16;m++) a3[m]=0.f;
    for (int c=0;c<120;c++){
      float wv = wk[t*120+c];
      #pragma unroll
      for (int m=0;m<16;m++) a3[m] = fmaf(wv, xq[c*16+m], a3[m]);
    }
    #pragma unroll
    for (int m=0;m<16;m++) g_Kf[b*1024 + t*16 + m] = a3[m];
  }
}

// ---------------- attention
__global__ __launch_bounds__(64) void k_attn(const float* __restrict__ wq, float* __restrict__ outb){
  int p = blockIdx.x*64 + threadIdx.x;
  int b = p >> 11;
  float x[120];
  xrow(p, 0, 120, x);
  float sc[16];
  #pragma unroll
  for (int m=0;m<16;m++) sc[m]=0.f;
  for (int a=0;a<64;a++){
    float q=0.f;
    #pragma unroll
    for (int c=0;c<120;c++) q = fmaf(wq[a*120+c], x[c], q);
    q *= 0.125f;
    const float* kf = g_Kf + b*1024 + a*16;
    #pragma unroll
    for (int m=0;m<16;m++) sc[m] = fmaf(kf[m], q, sc[m]);
  }
  float mx = sc[0];
  #pragma unroll
  for (int m=1;m<16;m++) mx = fmaxf(mx, sc[m]);
  float s=0.f;
  #pragma unroll
  for (int m=0;m<16;m++){ sc[m] = expf(sc[m]-mx); s += sc[m]; }
  float inv = 1.f/s;
  #pragma unroll
  for (int m=0;m<16;m++) outb[O_ASG + (size_t)p*16 + m] = sc[m]*inv;
}

extern "C" void kernel_launch(void* const* d_in, const int* in_sizes, int n_in,
                              void* d_out, int out_size, void* d_ws, size_t ws_size,
                              hipStream_t stream){
  const float* xyz  = (const float*)d_in[0];
  const float* eps  = (const float*)d_in[2];
  const float* w1a  = (const float*)d_in[3];
  const float* w1b  = (const float*)d_in[4];
  const float* w2a  = (const float*)d_in[5];
  const float* w2b  = (const float*)d_in[6];
  const float* wc3  = (const float*)d_in[7];
  const float* wmu  = (const float*)d_in[8];
  const float* bmu  = (const float*)d_in[9];
  const float* wvar = (const float*)d_in[10];
  const float* bvar = (const float*)d_in[11];
  const float* wenc = (const float*)d_in[12];
  const float* wcub1= (const float*)d_in[13];
  const float* wcub2= (const float*)d_in[14];
  const float* wq   = (const float*)d_in[15];
  const float* wk   = (const float*)d_in[16];
  const float* g1a  = (const float*)d_in[17];
  const float* b1a  = (const float*)d_in[18];
  const float* g1b  = (const float*)d_in[19];
  const float* b1b  = (const float*)d_in[20];
  const float* g2a  = (const float*)d_in[21];
  const float* b2a  = (const float*)d_in[22];
  const float* g2b  = (const float*)d_in[23];
  const float* b2b  = (const float*)d_in[24];
  const float* g3   = (const float*)d_in[25];
  const float* b3   = (const float*)d_in[26];
  float* outb = (float*)d_out;

  const double inv1 = 1.0/(double)EE;

  k_knnt<<<2048,128,0,stream>>>(xyz);
  k_knnu<<<128,256,0,stream>>>();
  k_knns1<<<1024,256,0,stream>>>(xyz);
  k_knns2<<<128,256,0,stream>>>();
  k_knns3<<<1024,256,0,stream>>>(xyz);
  // stage 1 (stats1a via feat-Gram; conv1a eliminated)
  k_gram1<<<320,256,0,stream>>>(xyz);
  k_fing1<<<1,64,0,stream>>>(w1a, g1a, b1a);
  k_conv1b<<<2560,256,0,stream>>>(xyz, w1a, w1b);
  k_red60<<<128,256,0,stream>>>(S1B_D, 2560);
  k_fin<<<1,64,0,stream>>>(g1b, b1b, S1B_D, S1B_AB, inv1);
  k_final1s<<<7680,256,0,stream>>>(outb);
  // stage 2
  k_pgem2<<<128,256,0,stream>>>(w2a);
  k_conv2a<<<2560,256,0,stream>>>();
  k_red60<<<128,256,0,stream>>>(S2A_D, 2560);
  k_fin<<<1,64,0,stream>>>(g2a, b2a, S2A_D, S2A_AB, inv1);
  k_conv2b<<<2560,256,0,stream>>>(w2b);
  k_red60<<<128,256,0,stream>>>(S2B_D, 2560);
  k_fin<<<1,64,0,stream>>>(g2b, b2b, S2B_D, S2B_AB, inv1);
  k_final2s<<<7680,256,0,stream>>>(outb);
  // stage 3 (fused: y3 never materialized; stats+max/min in one pass)
  k_max3s2<<<1024,256,0,stream>>>(wc3);
  k_fin3R<<<16,64,0,stream>>>(g3, b3);
  // heads
  k_head<<<16,256,0,stream>>>(eps, wmu, bmu, wvar, bvar, outb);
  k_cuboid<<<16,256,0,stream>>>(wenc, wcub1, wcub2, wk, outb);
  k_attn<<<512,64,0,stream>>>(wq, outb);
}

// Round 27
// 1276.770 us; speedup vs baseline: 1.1242x; 1.0184x over previous
//
#include <hip/hip_runtime.h>

typedef unsigned int u32;
typedef unsigned short u16;

// problem sizes
#define BB 16
#define NN 2048
#define KK 20
#define EE (BB*NN*KK)      // 655360 edges
#define PP (BB*NN)         // 32768 points
#define NCHK 8             // kNN candidate chunks
#define CHKSZ (NN/NCHK)    // 256 candidates per chunk

// output element offsets (fp32 elements, tuple flattened in return order)
#define O_XPER 0
#define O_XCUB 3932160
#define O_Z    3962880
#define O_MU   3966976
#define O_LV   3971072
#define O_ASG  3975168

// ---- static device scratch: all write-before-read each call, no atomics ----
__device__ double g_part[524288];             // stats partials / kNN counters / s3 partials (4 MB)
__device__ double g_std[2560];                // reduced double sums
__device__ float  g_st[2560];                 // BN A/B per stage + stage3 A/B
__device__ float  g_zf[BB*256];               // z
__device__ float  g_Kf[BB*1024];              // Kf (B,64,16)
__device__ u16    g_idx[EE];                  // kNN indices
__device__ float  g_xpf[(size_t)PP*120];      // point-major x_per mirror (15.7 MB)
__device__ float  g_e1[(size_t)EE*60];        // knn chunk-tops -> y2a
__device__ float  g_e2[(size_t)EE*60];        // knn T -> y1b -> U/V -> y2b

// double-sum bases in g_std: per 60-ch stage {sum@+0, sq@+64}
#define S1B_D 128
#define S2A_D 256
#define S2B_D 384
// A/B bases in g_st: per 60-ch stage {A@+0, B@+64}
#define S1A_AB 0
#define S1B_AB 128
#define S2A_AB 256
#define S2B_AB 384
#define S3A 512
#define S3B 1536

// stage3 partials: float view of g_part base (free after last k_red60)
// MX@0, MN@131072, S@262144, Q@393216 (each 128*1024 floats)
#define P3_MX 0
#define P3_MN 131072
#define P3_S  262144
#define P3_Q  393216

#define NEG_BIG -1.0e30f

__device__ __forceinline__ float lrelu(float x){ return x > 0.f ? x : 0.2f*x; }

__device__ __forceinline__ void xrow(int bn, int c0, int cnt, float* d){
  const float* s = g_xpf + (size_t)bn*120 + c0;
  #pragma unroll 4
  for (int i=0;i<cnt;i+=4){
    float4 v = *(const float4*)(s+i);
    d[i]=v.x; d[i+1]=v.y; d[i+2]=v.z; d[i+3]=v.w;
  }
}

// shared pd computation: MUST be bit-identical across all kNN kernels
__device__ __forceinline__ float pdcalc(float4 pm, float qx, float qy, float qz, float qw){
  float dot = fmaf(qx,pm.x, fmaf(qy,pm.y, qz*pm.z));
  float t = fmaf(2.f, dot, -qw);
  return t - pm.w;                      // == -||q-p||^2
}

// ---- float-only top-20 chain (distances only; 2 VALU ops per stage)
#define KT_DECL \
  float td0=NEG_BIG,td1=NEG_BIG,td2=NEG_BIG,td3=NEG_BIG,td4=NEG_BIG, \
        td5=NEG_BIG,td6=NEG_BIG,td7=NEG_BIG,td8=NEG_BIG,td9=NEG_BIG, \
        td10=NEG_BIG,td11=NEG_BIG,td12=NEG_BIG,td13=NEG_BIG,td14=NEG_BIG, \
        td15=NEG_BIG,td16=NEG_BIG,td17=NEG_BIG,td18=NEG_BIG,td19=NEG_BIG;
#define KT_CSW(u,l) { float mx = fmaxf(td##u, td##l); float mn = fminf(td##u, td##l); td##u = mx; td##l = mn; }
#define KT_INSERT(pd) \
  if ((pd) > td19){ \
    td19 = (pd); \
    KT_CSW(18,19) KT_CSW(17,18) KT_CSW(16,17) KT_CSW(15,16) \
    KT_CSW(14,15) KT_CSW(13,14) KT_CSW(12,13) KT_CSW(11,12) \
    KT_CSW(10,11) KT_CSW(9,10)  KT_CSW(8,9)   KT_CSW(7,8)   \
    KT_CSW(6,7)   KT_CSW(5,6)   KT_CSW(4,5)   KT_CSW(3,4)   \
    KT_CSW(2,3)   KT_CSW(1,2)   KT_CSW(0,1) }

// ---------------- kNN pass 1
__global__ __launch_bounds__(128) void k_knnt(const float* __restrict__ xyz){
  __shared__ float4 cand[CHKSZ];
  int qg = blockIdx.x >> 3;
  int c  = blockIdx.x & 7;
  int b  = qg >> 4;
  int n0 = (qg & 15) << 7;
  int t  = threadIdx.x;
  int m0 = c*CHKSZ;
  for (int i=t;i<CHKSZ;i+=128){
    const float* s = xyz + ((size_t)((b<<11)+m0+i))*3;
    float x=s[0], y=s[1], z=s[2];
    cand[i] = make_float4(x,y,z, fmaf(x,x,fmaf(y,y,z*z)));
  }
  __syncthreads();
  int n = n0 + t;
  const float* qs = xyz + ((size_t)((b<<11)+n))*3;
  float qx=qs[0], qy=qs[1], qz=qs[2];
  float qw = fmaf(qx,qx,fmaf(qy,qy,qz*qz));
  KT_DECL
  for (int i=0;i<CHKSZ;i++){
    float pd = pdcalc(cand[i], qx,qy,qz,qw);
    KT_INSERT(pd)
  }
  int p = (b<<11) + n;
  float* outd = g_e1;
  #define KOUT(k) outd[(size_t)(c*KK+k)*PP + p] = td##k;
  KOUT(0) KOUT(1) KOUT(2) KOUT(3) KOUT(4) KOUT(5) KOUT(6) KOUT(7) KOUT(8) KOUT(9)
  KOUT(10) KOUT(11) KOUT(12) KOUT(13) KOUT(14) KOUT(15) KOUT(16) KOUT(17) KOUT(18) KOUT(19)
  #undef KOUT
}

// ---------------- kNN pass 2: exact 20th-largest threshold T[q]
__global__ __launch_bounds__(256) void k_knnu(){
  int q = blockIdx.x*256 + threadIdx.x;
  const float* ind = g_e1;
  KT_DECL
  for (int i=0;i<NCHK*KK;i++){
    float pd = ind[(size_t)i*PP + q];
    KT_INSERT(pd)
  }
  g_e2[q] = td19;
}

// ---------------- kNN pass 3: count pd>T, pd==T per (query, chunk)
__global__ __launch_bounds__(256) void k_knns1(const float* __restrict__ xyz){
  __shared__ float4 cand[CHKSZ];
  int gid = blockIdx.x*256 + threadIdx.x;
  int c = gid >> 15;
  int q = gid & (PP-1);
  int b = q >> 11;
  int t = threadIdx.x;
  for (int i=t;i<CHKSZ;i+=256){
    const float* s = xyz + ((size_t)((b<<11)+c*CHKSZ+i))*3;
    float x=s[0], y=s[1], z=s[2];
    cand[i] = make_float4(x,y,z, fmaf(x,x,fmaf(y,y,z*z)));
  }
  __syncthreads();
  const float* qs = xyz + (size_t)q*3;
  float qx=qs[0], qy=qs[1], qz=qs[2];
  float qw = fmaf(qx,qx,fmaf(qy,qy,qz*qz));
  float T = g_e2[q];
  u32 cgt=0, ceq=0;
  for (int i=0;i<CHKSZ;i++){
    float pd = pdcalc(cand[i], qx,qy,qz,qw);
    cgt += (pd > T) ? 1u : 0u;
    ceq += (pd == T) ? 1u : 0u;
  }
  u32* cntg = (u32*)g_part;
  u32* cnte = cntg + NCHK*PP;
  cntg[c*PP + q] = cgt;
  cnte[c*PP + q] = ceq;
}

// ---------------- kNN pass 4: prefix over chunks
__global__ __launch_bounds__(256) void k_knns2(){
  int q = blockIdx.x*256 + threadIdx.x;
  u32* cntg = (u32*)g_part;
  u32* cnte = cntg + NCHK*PP;
  u32* bg   = cnte + NCHK*PP;
  u32* be   = bg   + NCHK*PP;
  u32 acc = 0;
  for (int c=0;c<NCHK;c++){ bg[c*PP+q] = acc; acc += cntg[c*PP+q]; }
  u32 eacc = acc;
  for (int c=0;c<NCHK;c++){ be[c*PP+q] = eacc; eacc += cnte[c*PP+q]; }
}

// ---------------- kNN pass 5: write indices
__global__ __launch_bounds__(256) void k_knns3(const float* __restrict__ xyz){
  __shared__ float4 cand[CHKSZ];
  int gid = blockIdx.x*256 + threadIdx.x;
  int c = gid >> 15;
  int q = gid & (PP-1);
  int b = q >> 11;
  int t = threadIdx.x;
  for (int i=t;i<CHKSZ;i+=256){
    const float* s = xyz + ((size_t)((b<<11)+c*CHKSZ+i))*3;
    float x=s[0], y=s[1], z=s[2];
    cand[i] = make_float4(x,y,z, fmaf(x,x,fmaf(y,y,z*z)));
  }
  __syncthreads();
  const float* qs = xyz + (size_t)q*3;
  float qx=qs[0], qy=qs[1], qz=qs[2];
  float qw = fmaf(qx,qx,fmaf(qy,qy,qz*qz));
  float T = g_e2[q];
  const u32* cntg = (const u32*)g_part;
  const u32* cnte = cntg + NCHK*PP;
  const u32* bg   = cnte + NCHK*PP;
  const u32* be   = bg   + NCHK*PP;
  u32 wgt = bg[c*PP+q];
  u32 weq = be[c*PP+q];
  u16* o = g_idx + (size_t)q*KK;
  for (int i=0;i<CHKSZ;i++){
    float pd = pdcalc(cand[i], qx,qy,qz,qw);
    int m = c*CHKSZ + i;
    if (pd > T && wgt < KK){ o[wgt] = (u16)m; wgt++; }
    else if (pd == T && weq < KK){ o[weq] = (u16)m; weq++; }
  }
}

// ---------------- reduce per-block double partials into g_std[dbase..] (nblk blocks)
__global__ __launch_bounds__(256) void k_red60(int dbase, int nblk){
  __shared__ double red[256];
  int s = blockIdx.x;                   // slot 0..127
  int t = threadIdx.x;
  double acc = 0.0;
  for (int i=t;i<nblk;i+=256) acc += g_part[(size_t)i*128 + s];
  red[t] = acc; __syncthreads();
  for (int w=128; w>0; w>>=1){ if (t<w) red[t]+=red[t+w]; __syncthreads(); }
  if (t==0) g_std[dbase+s] = red[0];
}

// ---------------- BN finalize in double
__global__ __launch_bounds__(64) void k_fin(const float* __restrict__ g, const float* __restrict__ bb,
                                            int dbase, int abase, double invc){
  int c = threadIdx.x;
  if (c < 60){
    double m = g_std[dbase+c]*invc;
    double v = g_std[dbase+64+c]*invc - m*m;
    if (v < 0.0) v = 0.0;
    float r = (float)(1.0/sqrt(v + 1e-5));
    float a = r*g[c];
    g_st[abase+c] = a;
    g_st[abase+64+c] = bb[c] - (float)m*a;
  }
}

// ==== stage1a stats via 6x6 feat Gram: 320 blocks x 256 thr x 8 edges ====
__global__ __launch_bounds__(256) void k_gram1(const float* __restrict__ xyz){
  __shared__ double sred[128];
  int tid = threadIdx.x, lane = tid & 63, wv = tid >> 6;
  double acc[27];
  #pragma unroll
  for (int k=0;k<27;k++) acc[k]=0.0;
  for (int it=0; it<8; ++it){
    int edge = (it*320 + blockIdx.x)*256 + tid;
    int row = edge / KK;
    int b = row >> 11;
    int nbr = g_idx[edge];
    const float* cp = xyz + (size_t)row*3;
    const float* np2 = xyz + ((size_t)((b<<11)+nbr))*3;
    float f3=cp[0], f4=cp[1], f5=cp[2];
    float f0=np2[0]-f3, f1=np2[1]-f4, f2=np2[2]-f5;
    float f[6] = {f0,f1,f2,f3,f4,f5};
    #pragma unroll
    for (int i=0;i<6;i++) acc[i] += (double)f[i];
    int k=6;
    #pragma unroll
    for (int i=0;i<6;i++)
      #pragma unroll
      for (int j=i;j<6;j++){ acc[k] += (double)f[i]*(double)f[j]; k++; }
  }
  #pragma unroll
  for (int k=0;k<27;k++){
    double s = acc[k];
    #pragma unroll
    for (int m=1;m<64;m<<=1) s += __shfl_xor(s,m);
    if (lane==0) sred[wv*32+k] = s;
  }
  __syncthreads();
  if (tid < 27)
    g_part[(size_t)blockIdx.x*32 + tid] = sred[tid] + sred[32+tid] + sred[64+tid] + sred[96+tid];
}

// finalize stage1a stats from Gram: S = w.fsum, Q = w^T G w
__global__ __launch_bounds__(64) void k_fing1(const float* __restrict__ w1a,
                                              const float* __restrict__ gg, const float* __restrict__ bb){
  __shared__ double gsum[27];
  int t = threadIdx.x;
  if (t < 27){
    double s = 0.0;
    for (int i=0;i<320;i++) s += g_part[(size_t)i*32 + t];
    gsum[t] = s;
  }
  __syncthreads();
  if (t < 60){
    float w[6];
    #pragma unroll
    for (int i=0;i<6;i++) w[i] = w1a[t*6+i];
    double S = 0.0;
    #pragma unroll
    for (int i=0;i<6;i++) S += (double)w[i]*gsum[i];
    double Q = 0.0; int k = 6;
    #pragma unroll
    for (int i=0;i<6;i++)
      #pragma unroll
      for (int j=i;j<6;j++){
        double cf = (i==j) ? 1.0 : 2.0;
        Q += cf*(double)w[i]*(double)w[j]*gsum[k]; k++;
      }
    double inv1 = 1.0/(double)EE;
    double m = S*inv1;
    double v = Q*inv1 - m*m;
    if (v < 0.0) v = 0.0;
    float r = (float)(1.0/sqrt(v + 1e-5));
    float A = r*gg[t];
    g_st[S1A_AB+t] = A;
    g_st[S1A_AB+64+t] = bb[t] - (float)m*A;
  }
}

// ==== stage1 conv-b: recompute y1a inline; h=lrelu(affine); y1b=w1b.h -> g_e2 + stats ====
__global__ __launch_bounds__(256) void k_conv1b(const float* __restrict__ xyz,
                                                const float* __restrict__ w1a, const float* __restrict__ w1b){
  __shared__ float ws[360];
  __shared__ float wbs[3600];
  __shared__ float As[60], Bs[60];
  __shared__ double sred[512];
  int tid = threadIdx.x, lane = tid & 63, wv = tid >> 6;
  for (int i=tid;i<360;i+=256) ws[i]=w1a[i];
  for (int i=tid;i<3600;i+=256) wbs[i]=w1b[i];
  if (tid<60){ As[tid]=g_st[S1A_AB+tid]; Bs[tid]=g_st[S1A_AB+64+tid]; }
  __syncthreads();
  int edge = blockIdx.x*256 + tid;
  int row = edge / KK;
  int b = row >> 11;
  int nbr = g_idx[edge];
  const float* cp = xyz + (size_t)row*3;
  const float* np2 = xyz + ((size_t)((b<<11)+nbr))*3;
  float c0=cp[0], c1=cp[1], c2=cp[2];
  float d0=np2[0]-c0, d1=np2[1]-c1, d2=np2[2]-c2;
  float h[60];
  #pragma unroll 4
  for (int o=0;o<60;o++){
    float y = ws[o*6]*d0 + ws[o*6+1]*d1 + ws[o*6+2]*d2 + ws[o*6+3]*c0 + ws[o*6+4]*c1 + ws[o*6+5]*c2;
    h[o] = lrelu(fmaf(As[o], y, Bs[o]));
  }
  const float4* wb4 = (const float4*)wbs;
  double rs=0.0, rq=0.0;
  for (int o=0;o<60;o++){
    float y=0.f;
    #pragma unroll
    for (int c4=0;c4<15;c4++){
      float4 wvv = wb4[o*15+c4];
      y = fmaf(wvv.x, h[c4*4],   y);
      y = fmaf(wvv.y, h[c4*4+1], y);
      y = fmaf(wvv.z, h[c4*4+2], y);
      y = fmaf(wvv.w, h[c4*4+3], y);
    }
    g_e2[(size_t)o*EE + edge] = y;
    float s=y, q=y*y;
    #pragma unroll
    for (int m=1;m<64;m<<=1){ s += __shfl_xor(s,m); q += __shfl_xor(q,m); }
    if (lane==o){ rs += (double)s; rq += (double)q; }
  }
  sred[wv*128 + lane] = rs;
  sred[wv*128 + 64 + lane] = rq;
  __syncthreads();
  if (tid < 128)
    g_part[(size_t)blockIdx.x*128 + tid] = sred[tid] + sred[128+tid] + sred[256+tid] + sred[384+tid];
}

// ==== stage1 final: x1[bn][o] = max_k lrelu(affine(y1b)).  60x128 blocks ====
__global__ __launch_bounds__(256) void k_final1s(float* __restrict__ outb){
  int o = blockIdx.x >> 7;
  int bn = ((blockIdx.x & 127) << 8) + threadIdx.x;
  int b = bn >> 11, n = bn & 2047;
  float A = g_st[S1B_AB+o], Bv = g_st[S1B_AB+64+o];
  const float* src = g_e2 + (size_t)o*EE + (size_t)bn*KK;
  float mx = NEG_BIG;
  #pragma unroll
  for (int k=0;k<KK;k++) mx = fmaxf(mx, lrelu(fmaf(A, src[k], Bv)));
  g_xpf[(size_t)bn*120 + o] = mx;
  outb[O_XPER + (size_t)(b*120+o)*NN + n] = mx;
}

// ==== stage2 point transforms: U = Wd.x1, V = (Wc-Wd).x1 -> g_e2 [p][64] ====
__global__ __launch_bounds__(256) void k_pgem2(const float* __restrict__ w2a){
  __shared__ float wd[3600], wcd[3600];
  int tid = threadIdx.x;
  for (int i=tid;i<3600;i+=256){
    int o = i/60, c = i%60;
    float a = w2a[o*120+c], bvl = w2a[o*120+60+c];
    wd[i] = a; wcd[i] = bvl - a;
  }
  __syncthreads();
  int p = blockIdx.x*256 + tid;
  float x[60];
  xrow(p, 0, 60, x);
  float* gU = g_e2;
  float* gV = g_e2 + (size_t)PP*64;
  const float4* wd4  = (const float4*)wd;
  const float4* wcd4 = (const float4*)wcd;
  #pragma unroll 4
  for (int o=0;o<60;o++){
    float u=0.f, v=0.f;
    #pragma unroll
    for (int c4=0;c4<15;c4++){
      float4 a4 = wd4[o*15+c4];
      float4 b4 = wcd4[o*15+c4];
      u = fmaf(a4.x, x[c4*4],   u); v = fmaf(b4.x, x[c4*4],   v);
      u = fmaf(a4.y, x[c4*4+1], u); v = fmaf(b4.y, x[c4*4+1], v);
      u = fmaf(a4.z, x[c4*4+2], u); v = fmaf(b4.z, x[c4*4+2], v);
      u = fmaf(a4.w, x[c4*4+3], u); v = fmaf(b4.w, x[c4*4+3], v);
    }
    gU[(size_t)p*64 + o] = u;
    gV[(size_t)p*64 + o] = v;
  }
}

// ==== stage2 conv-a: y2a = U[nbr] + V[center] -> g_e1 + butterfly stats ====
__global__ __launch_bounds__(256) void k_conv2a(){
  __shared__ double sred[512];
  int tid = threadIdx.x, lane = tid & 63, wv = tid >> 6;
  int edge = blockIdx.x*256 + tid;
  int row = edge / KK;
  int b = row >> 11;
  int nbr = g_idx[edge];
  int pn = (b<<11)+nbr;
  const float4* gU = (const float4*)g_e2;
  const float4* gV = (const float4*)(g_e2 + (size_t)PP*64);
  double rs=0.0, rq=0.0;
  #pragma unroll
  for (int o4=0;o4<15;o4++){
    float4 uu = gU[(size_t)pn*16 + o4];
    float4 vv = gV[(size_t)row*16 + o4];
    float y0=uu.x+vv.x, y1=uu.y+vv.y, y2=uu.z+vv.z, y3=uu.w+vv.w;
    g_e1[(size_t)(o4*4+0)*EE + edge] = y0;
    g_e1[(size_t)(o4*4+1)*EE + edge] = y1;
    g_e1[(size_t)(o4*4+2)*EE + edge] = y2;
    g_e1[(size_t)(o4*4+3)*EE + edge] = y3;
    float ys[4] = {y0,y1,y2,y3};
    #pragma unroll
    for (int j=0;j<4;j++){
      float s=ys[j], q=ys[j]*ys[j];
      #pragma unroll
      for (int m=1;m<64;m<<=1){ s += __shfl_xor(s,m); q += __shfl_xor(q,m); }
      if (lane==o4*4+j){ rs += (double)s; rq += (double)q; }
    }
  }
  sred[wv*128 + lane] = rs;
  sred[wv*128 + 64 + lane] = rq;
  __syncthreads();
  if (tid < 128)
    g_part[(size_t)blockIdx.x*128 + tid] = sred[tid] + sred[128+tid] + sred[256+tid] + sred[384+tid];
}

// ==== stage2 conv-b: h=lrelu(affine(y2a)); y2b=w2b.h -> g_e2 + stats ====
__global__ __launch_bounds__(256) void k_conv2b(const float* __restrict__ w2b){
  __shared__ float wbs[3600];
  __shared__ float As[60], Bs[60];
  __shared__ double sred[512];
  int tid = threadIdx.x, lane = tid & 63, wv = tid >> 6;
  for (int i=tid;i<3600;i+=256) wbs[i]=w2b[i];
  if (tid<60){ As[tid]=g_st[S2A_AB+tid]; Bs[tid]=g_st[S2A_AB+64+tid]; }
  __syncthreads();
  int edge = blockIdx.x*256 + tid;
  float h[60];
  #pragma unroll 4
  for (int o=0;o<60;o++) h[o] = lrelu(fmaf(As[o], g_e1[(size_t)o*EE + edge], Bs[o]));
  const float4* wb4 = (const float4*)wbs;
  double rs=0.0, rq=0.0;
  for (int o=0;o<60;o++){
    float y=0.f;
    #pragma unroll
    for (int c4=0;c4<15;c4++){
      float4 wvv = wb4[o*15+c4];
      y = fmaf(wvv.x, h[c4*4],   y);
      y = fmaf(wvv.y, h[c4*4+1], y);
      y = fmaf(wvv.z, h[c4*4+2], y);
      y = fmaf(wvv.w, h[c4*4+3], y);
    }
    g_e2[(size_t)o*EE + edge] = y;
    float s=y, q=y*y;
    #pragma unroll
    for (int m=1;m<64;m<<=1){ s += __shfl_xor(s,m); q += __shfl_xor(q,m); }
    if (lane==o){ rs += (double)s; rq += (double)q; }
  }
  sred[wv*128 + lane] = rs;
  sred[wv*128 + 64 + lane] = rq;
  __syncthreads();
  if (tid < 128)
    g_part[(size_t)blockIdx.x*128 + tid] = sred[tid] + sred[128+tid] + sred[256+tid] + sred[384+tid];
}

// ==== stage2 final: x2 from g_e2 ====
__global__ __launch_bounds__(256) void k_final2s(float* __restrict__ outb){
  int o = blockIdx.x >> 7;
  int bn = ((blockIdx.x & 127) << 8) + threadIdx.x;
  int b = bn >> 11, n = bn & 2047;
  float A = g_st[S2B_AB+o], Bv = g_st[S2B_AB+64+o];
  const float* src = g_e2 + (size_t)o*EE + (size_t)bn*KK;
  float mx = NEG_BIG;
  #pragma unroll
  for (int k=0;k<KK;k++) mx = fmaxf(mx, lrelu(fmaf(A, src[k], Bv)));
  g_xpf[(size_t)bn*120 + 60 + o] = mx;
  outb[O_XPER + (size_t)(b*120+60+o)*NN + n] = mx;
}

// ==== stage3 fused, half-channel scheme: W half-row (15 float4) REGISTER-resident ====
// grid = 1024 = seg(8) x b(16) x ec(8); 256 thr = 4 waves x 64 lanes
// wave wv owns channels ec*128 + wv*32 + (lane&31); lane>=32 computes upper half (c=60..119)
#define WH_DECL(i) float4 W##i;
#define WH_LOAD(i) W##i = wp[i];
#define WH_DOT(i)  { float4 xv = xp[i]; \
  a0 = fmaf(W##i.x, xv.x, a0); a1 = fmaf(W##i.y, xv.y, a1); \
  a2 = fmaf(W##i.z, xv.z, a2); a3 = fmaf(W##i.w, xv.w, a3); }
#define WH_ALL(OP) \
  OP(0) OP(1) OP(2) OP(3) OP(4) OP(5) OP(6) OP(7) OP(8) OP(9) \
  OP(10) OP(11) OP(12) OP(13) OP(14)

__global__ __launch_bounds__(256) void k_max3s2(const float* __restrict__ wc3){
  __shared__ float xt[64*120];          // 30.7 KB
  int tid = threadIdx.x;
  int lane = tid & 63, wv = tid >> 6;
  int half = lane >> 5;                 // 0: c=0..59, 1: c=60..119
  int ec  = blockIdx.x & 7;
  int b   = (blockIdx.x >> 3) & 15;
  int seg = blockIdx.x >> 7;            // 0..7, 256 points each
  int e   = ec*128 + wv*32 + (lane & 31);
  WH_ALL(WH_DECL)
  {
    const float4* wp = (const float4*)(wc3 + (size_t)e*120 + half*60);
    WH_ALL(WH_LOAD)
  }
  float mx = NEG_BIG, mn = -NEG_BIG, S = 0.f, Q = 0.f;
  for (int tile=0; tile<4; tile++){
    int p0 = b*2048 + seg*256 + tile*64;
    __syncthreads();
    for (int v=tid; v<1920; v+=256){
      int pk = v/30, c4 = v%30;
      ((float4*)xt)[pk*30+c4] = *(const float4*)(g_xpf + (size_t)(p0+pk)*120 + c4*4);
    }
    __syncthreads();
    for (int k=0;k<64;k++){
      const float4* xp = (const float4*)(xt + k*120) + half*15;
      float a0=0.f,a1=0.f,a2=0.f,a3=0.f;
      WH_ALL(WH_DOT)
      float p = (a0+a1)+(a2+a3);
      float y = p + __shfl_xor(p, 32);  // combine halves
      mx = fmaxf(mx, y);
      mn = fminf(mn, y);
      S += y;
      Q = fmaf(y, y, Q);
    }
  }
  if (half == 0){
    float* MB = (float*)g_part;
    int slot = (seg*16+b)*1024 + e;
    MB[P3_MX + slot] = mx;
    MB[P3_MN + slot] = mn;
    MB[P3_S  + slot] = S;
    MB[P3_Q  + slot] = Q;
  }
}

// stage3 finalize: reduce 128 S/Q partials per channel -> A3/B3
__global__ __launch_bounds__(64) void k_fin3R(const float* __restrict__ gg, const float* __restrict__ bb){
  int e = blockIdx.x*64 + threadIdx.x;  // grid 16
  const float* MB = (const float*)g_part;
  double S=0.0, Q=0.0;
  for (int j=0;j<128;j++){
    S += (double)MB[P3_S + j*1024 + e];
    Q += (double)MB[P3_Q + j*1024 + e];
  }
  double inv3 = 1.0/(double)PP;
  double m = S*inv3;
  double v = Q*inv3 - m*m;
  if (v < 0.0) v = 0.0;
  float r = (float)(1.0/sqrt(v + 1e-5));
  float A = r*gg[e];
  g_st[S3A+e] = A;
  g_st[S3B+e] = bb[e] - (float)m*A;
}

// ---------------- VAE head: g from max/min + affine (monotone commute), then mu/lv/z
__global__ __launch_bounds__(256) void k_head(const float* __restrict__ eps,
                                              const float* __restrict__ wmu, const float* __restrict__ bmu,
                                              const float* __restrict__ wvar, const float* __restrict__ bvar,
                                              float* __restrict__ outb){
  int b = blockIdx.x, j = threadIdx.x;
  __shared__ float gs[1024];
  const float* MB = (const float*)g_part;
  for (int i=j;i<1024;i+=256){
    float A = g_st[S3A+i], B = g_st[S3B+i];
    float M = NEG_BIG, m2 = -NEG_BIG;
    #pragma unroll
    for (int sg=0;sg<8;sg++){
      M  = fmaxf(M,  MB[P3_MX + (sg*16+b)*1024 + i]);
      m2 = fminf(m2, MB[P3_MN + (sg*16+b)*1024 + i]);
    }
    float y = (A > 0.f) ? M : ((A < 0.f) ? m2 : M);
    gs[i] = lrelu(fmaf(A, y, B));
  }
  __syncthreads();
  float mu = bmu[j], lv = bvar[j];
  const float4* wm = (const float4*)(wmu + (size_t)j*1024);
  const float4* wv = (const float4*)(wvar + (size_t)j*1024);
  #pragma unroll 4
  for (int e=0;e<256;e++){
    float4 a = wm[e], c = wv[e];
    const float* g4 = gs + e*4;
    mu = fmaf(a.x,g4[0], fmaf(a.y,g4[1], fmaf(a.z,g4[2], fmaf(a.w,g4[3], mu))));
    lv = fmaf(c.x,g4[0], fmaf(c.y,g4[1], fmaf(c.z,g4[2], fmaf(c.w,g4[3], lv))));
  }
  float z = fmaf(eps[b*256+j], expf(0.5f*lv), mu);
  g_zf[b*256+j] = z;
  outb[O_MU + b*256 + j] = mu;
  outb[O_LV + b*256 + j] = lv;
  outb[O_Z  + b*256 + j] = z;
}

// ---------------- cuboid branch
__global__ __launch_bounds__(256) void k_cuboid(const float* __restrict__ wenc,
                                                const float* __restrict__ wcub1, const float* __restrict__ wcub2,
                                                const float* __restrict__ wk, float* __restrict__ outb){
  int b = blockIdx.x, t = threadIdx.x;
  __shared__ float xc[320*16];
  __shared__ float hh[256*16];
  __shared__ float xq[120*16];
  for (int i=t;i<320*16;i+=256){
    int c = i>>4, m = i&15;
    xc[i] = (c<256) ? g_zf[b*256+c] : lrelu(wenc[(c-256)*16+m]);
  }
  __syncthreads();
  {
    float acc[16];
    #pragma unroll
    for (int m=0;m<16;m++) acc[m]=0.f;
    for (int c=0;c<320;c++){
      float wv = wcub1[(size_t)t*320+c];
      #pragma unroll
      for (int m=0;m<16;m++) acc[m] = fmaf(wv, xc[c*16+m], acc[m]);
    }
    #pragma unroll
    for (int m=0;m<16;m++) hh[t*16+m] = lrelu(acc[m]);
  }
  __syncthreads();
  if (t<120){
    float a2[16];
    #pragma unroll
    for (int m=0;m<16;m++) a2[m]=0.f;
    for (int c=0;c<256;c++){
      float wv = wcub2[(size_t)t*256+c];
      #pragma unroll
      for (int m=0;m<16;m++) a2[m] = fmaf(wv, hh[c*16+m], a2[m]);
    }
    #pragma unroll
    for (int m=0;m<16;m++){
      float v = lrelu(a2[m]);
      xq[t*16+m] = v;
      outb[O_XCUB + b*1920 + t*16 + m] = v;
    }
  }
  __syncthreads();
  if (t<64){
    float a3[16];
    #pragma unroll
    for (int m=0;m<16;m++) a3[m]=0.f;
    for (int c=0;c<120;c++){
      float wv = wk[t*120+c];
      #pragma unroll
      for (int m=0;m<16;m++) a3[m] = fmaf(wv, xq[c*16+m], a3[m]);
    }
    #pragma unroll
    for (int m=0;m<16;m++) g_Kf[b*1024 + t*16 + m] = a3[m];
  }
}

// ---------------- attention
__global__ __launch_bounds__(64) void k_attn(const float* __restrict__ wq, float* __restrict__ outb){
  int p = blockIdx.x*64 + threadIdx.x;
  int b = p >> 11;
  float x[120];
  xrow(p, 0, 120, x);
  float sc[16];
  #pragma unroll
  for (int m=0;m<16;m++) sc[m]=0.f;
  for (int a=0;a<64;a++){
    float q=0.f;
    #pragma unroll
    for (int c=0;c<120;c++) q = fmaf(wq[a*120+c], x[c], q);
    q *= 0.125f;
    const float* kf = g_Kf + b*1024 + a*16;
    #pragma unroll
    for (int m=0;m<16;m++) sc[m] = fmaf(kf[m], q, sc[m]);
  }
  float mx = sc[0];
  #pragma unroll
  for (int m=1;m<16;m++) mx = fmaxf(mx, sc[m]);
  float s=0.f;
  #pragma unroll
  for (int m=0;m<16;m++){ sc[m] = expf(sc[m]-mx); s += sc[m]; }
  float inv = 1.f/s;
  #pragma unroll
  for (int m=0;m<16;m++) outb[O_ASG + (size_t)p*16 + m] = sc[m]*inv;
}

extern "C" void kernel_launch(void* const* d_in, const int* in_sizes, int n_in,
                              void* d_out, int out_size, void* d_ws, size_t ws_size,
                              hipStream_t stream){
  const float* xyz  = (const float*)d_in[0];
  const float* eps  = (const float*)d_in[2];
  const float* w1a  = (const float*)d_in[3];
  const float* w1b  = (const float*)d_in[4];
  const float* w2a  = (const float*)d_in[5];
  const float* w2b  = (const float*)d_in[6];
  const float* wc3  = (const float*)d_in[7];
  const float* wmu  = (const float*)d_in[8];
  const float* bmu  = (const float*)d_in[9];
  const float* wvar = (const float*)d_in[10];
  const float* bvar = (const float*)d_in[11];
  const float* wenc = (const float*)d_in[12];
  const float* wcub1= (const float*)d_in[13];
  const float* wcub2= (const float*)d_in[14];
  const float* wq   = (const float*)d_in[15];
  const float* wk   = (const float*)d_in[16];
  const float* g1a  = (const float*)d_in[17];
  const float* b1a  = (const float*)d_in[18];
  const float* g1b  = (const float*)d_in[19];
  const float* b1b  = (const float*)d_in[20];
  const float* g2a  = (const float*)d_in[21];
  const float* b2a  = (const float*)d_in[22];
  const float* g2b  = (const float*)d_in[23];
  const float* b2b  = (const float*)d_in[24];
  const float* g3   = (const float*)d_in[25];
  const float* b3   = (const float*)d_in[26];
  float* outb = (float*)d_out;

  const double inv1 = 1.0/(double)EE;

  k_knnt<<<2048,128,0,stream>>>(xyz);
  k_knnu<<<128,256,0,stream>>>();
  k_knns1<<<1024,256,0,stream>>>(xyz);
  k_knns2<<<128,256,0,stream>>>();
  k_knns3<<<1024,256,0,stream>>>(xyz);
  // stage 1 (stats1a via feat-Gram; conv1a eliminated)
  k_gram1<<<320,256,0,stream>>>(xyz);
  k_fing1<<<1,64,0,stream>>>(w1a, g1a, b1a);
  k_conv1b<<<2560,256,0,stream>>>(xyz, w1a, w1b);
  k_red60<<<128,256,0,stream>>>(S1B_D, 2560);
  k_fin<<<1,64,0,stream>>>(g1b, b1b, S1B_D, S1B_AB, inv1);
  k_final1s<<<7680,256,0,stream>>>(outb);
  // stage 2
  k_pgem2<<<128,256,0,stream>>>(w2a);
  k_conv2a<<<2560,256,0,stream>>>();
  k_red60<<<128,256,0,stream>>>(S2A_D, 2560);
  k_fin<<<1,64,0,stream>>>(g2a, b2a, S2A_D, S2A_AB, inv1);
  k_conv2b<<<2560,256,0,stream>>>(w2b);
  k_red60<<<128,256,0,stream>>>(S2B_D, 2560);
  k_fin<<<1,64,0,stream>>>(g2b, b2b, S2B_D, S2B_AB, inv1);
  k_final2s<<<7680,256,0,stream>>>(outb);
  // stage 3 (fused: half-channel register scheme; y3 never materialized)
  k_max3s2<<<1024,256,0,stream>>>(wc3);
  k_fin3R<<<16,64,0,stream>>>(g3, b3);
  // heads
  k_head<<<16,256,0,stream>>>(eps, wmu, bmu, wvar, bvar, outb);
  k_cuboid<<<16,256,0,stream>>>(wenc, wcub1, wcub2, wk, outb);
  k_attn<<<512,64,0,stream>>>(wq, outb);
}

// Round 28
// 1228.962 us; speedup vs baseline: 1.1680x; 1.0389x over previous
//
#include <hip/hip_runtime.h>

typedef unsigned int u32;
typedef unsigned short u16;

// problem sizes
#define BB 16
#define NN 2048
#define KK 20
#define EE (BB*NN*KK)      // 655360 edges
#define PP (BB*NN)         // 32768 points
#define NCHK 8             // kNN candidate chunks
#define CHKSZ (NN/NCHK)    // 256 candidates per chunk

// output element offsets (fp32 elements, tuple flattened in return order)
#define O_XPER 0
#define O_XCUB 3932160
#define O_Z    3962880
#define O_MU   3966976
#define O_LV   3971072
#define O_ASG  3975168

// ---- static device scratch: all write-before-read each call, no atomics ----
__device__ double g_part[524288];             // stats partials / kNN counters / s3 partials (4 MB)
__device__ double g_std[2560];                // reduced double sums
__device__ float  g_st[2560];                 // BN A/B per stage + stage3 A/B
__device__ float  g_zf[BB*256];               // z
__device__ float  g_Kf[BB*1024];              // Kf (B,64,16)
__device__ u16    g_idx[EE];                  // kNN indices
__device__ float  g_xpf[(size_t)PP*120];      // point-major x_per mirror (15.7 MB)
__device__ float  g_e1[(size_t)EE*60];        // knn chunk-tops -> y2a
__device__ float  g_e2[(size_t)EE*60];        // knn T -> y1b -> U/V -> y2b

// double-sum bases in g_std: per 60-ch stage {sum@+0, sq@+64}
#define S1B_D 128
#define S2A_D 256
#define S2B_D 384
// A/B bases in g_st: per 60-ch stage {A@+0, B@+64}
#define S1A_AB 0
#define S1B_AB 128
#define S2A_AB 256
#define S2B_AB 384
#define S3A 512
#define S3B 1536

// stage3 partials: float view of g_part base (free after last k_red60)
// MX@0, MN@131072, S@262144, Q@393216 (each 128*1024 floats)
#define P3_MX 0
#define P3_MN 131072
#define P3_S  262144
#define P3_Q  393216

#define NEG_BIG -1.0e30f

__device__ __forceinline__ float lrelu(float x){ return x > 0.f ? x : 0.2f*x; }

__device__ __forceinline__ void xrow(int bn, int c0, int cnt, float* d){
  const float* s = g_xpf + (size_t)bn*120 + c0;
  #pragma unroll 4
  for (int i=0;i<cnt;i+=4){
    float4 v = *(const float4*)(s+i);
    d[i]=v.x; d[i+1]=v.y; d[i+2]=v.z; d[i+3]=v.w;
  }
}

// shared pd computation: MUST be bit-identical across all kNN kernels
__device__ __forceinline__ float pdcalc(float4 pm, float qx, float qy, float qz, float qw){
  float dot = fmaf(qx,pm.x, fmaf(qy,pm.y, qz*pm.z));
  float t = fmaf(2.f, dot, -qw);
  return t - pm.w;                      // == -||q-p||^2
}

// ---- float-only top-20 chain (distances only; 2 VALU ops per stage)
#define KT_DECL \
  float td0=NEG_BIG,td1=NEG_BIG,td2=NEG_BIG,td3=NEG_BIG,td4=NEG_BIG, \
        td5=NEG_BIG,td6=NEG_BIG,td7=NEG_BIG,td8=NEG_BIG,td9=NEG_BIG, \
        td10=NEG_BIG,td11=NEG_BIG,td12=NEG_BIG,td13=NEG_BIG,td14=NEG_BIG, \
        td15=NEG_BIG,td16=NEG_BIG,td17=NEG_BIG,td18=NEG_BIG,td19=NEG_BIG;
#define KT_CSW(u,l) { float mx = fmaxf(td##u, td##l); float mn = fminf(td##u, td##l); td##u = mx; td##l = mn; }
#define KT_INSERT(pd) \
  if ((pd) > td19){ \
    td19 = (pd); \
    KT_CSW(18,19) KT_CSW(17,18) KT_CSW(16,17) KT_CSW(15,16) \
    KT_CSW(14,15) KT_CSW(13,14) KT_CSW(12,13) KT_CSW(11,12) \
    KT_CSW(10,11) KT_CSW(9,10)  KT_CSW(8,9)   KT_CSW(7,8)   \
    KT_CSW(6,7)   KT_CSW(5,6)   KT_CSW(4,5)   KT_CSW(3,4)   \
    KT_CSW(2,3)   KT_CSW(1,2)   KT_CSW(0,1) }

// ---------------- kNN pass 1
__global__ __launch_bounds__(128) void k_knnt(const float* __restrict__ xyz){
  __shared__ float4 cand[CHKSZ];
  int qg = blockIdx.x >> 3;
  int c  = blockIdx.x & 7;
  int b  = qg >> 4;
  int n0 = (qg & 15) << 7;
  int t  = threadIdx.x;
  int m0 = c*CHKSZ;
  for (int i=t;i<CHKSZ;i+=128){
    const float* s = xyz + ((size_t)((b<<11)+m0+i))*3;
    float x=s[0], y=s[1], z=s[2];
    cand[i] = make_float4(x,y,z, fmaf(x,x,fmaf(y,y,z*z)));
  }
  __syncthreads();
  int n = n0 + t;
  const float* qs = xyz + ((size_t)((b<<11)+n))*3;
  float qx=qs[0], qy=qs[1], qz=qs[2];
  float qw = fmaf(qx,qx,fmaf(qy,qy,qz*qz));
  KT_DECL
  for (int i=0;i<CHKSZ;i++){
    float pd = pdcalc(cand[i], qx,qy,qz,qw);
    KT_INSERT(pd)
  }
  int p = (b<<11) + n;
  float* outd = g_e1;
  #define KOUT(k) outd[(size_t)(c*KK+k)*PP + p] = td##k;
  KOUT(0) KOUT(1) KOUT(2) KOUT(3) KOUT(4) KOUT(5) KOUT(6) KOUT(7) KOUT(8) KOUT(9)
  KOUT(10) KOUT(11) KOUT(12) KOUT(13) KOUT(14) KOUT(15) KOUT(16) KOUT(17) KOUT(18) KOUT(19)
  #undef KOUT
}

// ---------------- kNN pass 2: exact 20th-largest threshold T[q]
__global__ __launch_bounds__(256) void k_knnu(){
  int q = blockIdx.x*256 + threadIdx.x;
  const float* ind = g_e1;
  KT_DECL
  for (int i=0;i<NCHK*KK;i++){
    float pd = ind[(size_t)i*PP + q];
    KT_INSERT(pd)
  }
  g_e2[q] = td19;
}

// ---------------- kNN pass 3: count pd>T, pd==T per (query, chunk)
__global__ __launch_bounds__(256) void k_knns1(const float* __restrict__ xyz){
  __shared__ float4 cand[CHKSZ];
  int gid = blockIdx.x*256 + threadIdx.x;
  int c = gid >> 15;
  int q = gid & (PP-1);
  int b = q >> 11;
  int t = threadIdx.x;
  for (int i=t;i<CHKSZ;i+=256){
    const float* s = xyz + ((size_t)((b<<11)+c*CHKSZ+i))*3;
    float x=s[0], y=s[1], z=s[2];
    cand[i] = make_float4(x,y,z, fmaf(x,x,fmaf(y,y,z*z)));
  }
  __syncthreads();
  const float* qs = xyz + (size_t)q*3;
  float qx=qs[0], qy=qs[1], qz=qs[2];
  float qw = fmaf(qx,qx,fmaf(qy,qy,qz*qz));
  float T = g_e2[q];
  u32 cgt=0, ceq=0;
  for (int i=0;i<CHKSZ;i++){
    float pd = pdcalc(cand[i], qx,qy,qz,qw);
    cgt += (pd > T) ? 1u : 0u;
    ceq += (pd == T) ? 1u : 0u;
  }
  u32* cntg = (u32*)g_part;
  u32* cnte = cntg + NCHK*PP;
  cntg[c*PP + q] = cgt;
  cnte[c*PP + q] = ceq;
}

// ---------------- kNN pass 4: prefix over chunks
__global__ __launch_bounds__(256) void k_knns2(){
  int q = blockIdx.x*256 + threadIdx.x;
  u32* cntg = (u32*)g_part;
  u32* cnte = cntg + NCHK*PP;
  u32* bg   = cnte + NCHK*PP;
  u32* be   = bg   + NCHK*PP;
  u32 acc = 0;
  for (int c=0;c<NCHK;c++){ bg[c*PP+q] = acc; acc += cntg[c*PP+q]; }
  u32 eacc = acc;
  for (int c=0;c<NCHK;c++){ be[c*PP+q] = eacc; eacc += cnte[c*PP+q]; }
}

// ---------------- kNN pass 5: write indices
__global__ __launch_bounds__(256) void k_knns3(const float* __restrict__ xyz){
  __shared__ float4 cand[CHKSZ];
  int gid = blockIdx.x*256 + threadIdx.x;
  int c = gid >> 15;
  int q = gid & (PP-1);
  int b = q >> 11;
  int t = threadIdx.x;
  for (int i=t;i<CHKSZ;i+=256){
    const float* s = xyz + ((size_t)((b<<11)+c*CHKSZ+i))*3;
    float x=s[0], y=s[1], z=s[2];
    cand[i] = make_float4(x,y,z, fmaf(x,x,fmaf(y,y,z*z)));
  }
  __syncthreads();
  const float* qs = xyz + (size_t)q*3;
  float qx=qs[0], qy=qs[1], qz=qs[2];
  float qw = fmaf(qx,qx,fmaf(qy,qy,qz*qz));
  float T = g_e2[q];
  const u32* cntg = (const u32*)g_part;
  const u32* cnte = cntg + NCHK*PP;
  const u32* bg   = cnte + NCHK*PP;
  const u32* be   = bg   + NCHK*PP;
  u32 wgt = bg[c*PP+q];
  u32 weq = be[c*PP+q];
  u16* o = g_idx + (size_t)q*KK;
  for (int i=0;i<CHKSZ;i++){
    float pd = pdcalc(cand[i], qx,qy,qz,qw);
    int m = c*CHKSZ + i;
    if (pd > T && wgt < KK){ o[wgt] = (u16)m; wgt++; }
    else if (pd == T && weq < KK){ o[weq] = (u16)m; weq++; }
  }
}

// ---------------- reduce per-block double partials into g_std[dbase..] (nblk blocks)
__global__ __launch_bounds__(256) void k_red60(int dbase, int nblk){
  __shared__ double red[256];
  int s = blockIdx.x;                   // slot 0..127
  int t = threadIdx.x;
  double acc = 0.0;
  for (int i=t;i<nblk;i+=256) acc += g_part[(size_t)i*128 + s];
  red[t] = acc; __syncthreads();
  for (int w=128; w>0; w>>=1){ if (t<w) red[t]+=red[t+w]; __syncthreads(); }
  if (t==0) g_std[dbase+s] = red[0];
}

// ---------------- BN finalize in double
__global__ __launch_bounds__(64) void k_fin(const float* __restrict__ g, const float* __restrict__ bb,
                                            int dbase, int abase, double invc){
  int c = threadIdx.x;
  if (c < 60){
    double m = g_std[dbase+c]*invc;
    double v = g_std[dbase+64+c]*invc - m*m;
    if (v < 0.0) v = 0.0;
    float r = (float)(1.0/sqrt(v + 1e-5));
    float a = r*g[c];
    g_st[abase+c] = a;
    g_st[abase+64+c] = bb[c] - (float)m*a;
  }
}

// ==== stage1a stats via 6x6 feat Gram: 320 blocks x 256 thr x 8 edges ====
__global__ __launch_bounds__(256) void k_gram1(const float* __restrict__ xyz){
  __shared__ double sred[128];
  int tid = threadIdx.x, lane = tid & 63, wv = tid >> 6;
  double acc[27];
  #pragma unroll
  for (int k=0;k<27;k++) acc[k]=0.0;
  for (int it=0; it<8; ++it){
    int edge = (it*320 + blockIdx.x)*256 + tid;
    int row = edge / KK;
    int b = row >> 11;
    int nbr = g_idx[edge];
    const float* cp = xyz + (size_t)row*3;
    const float* np2 = xyz + ((size_t)((b<<11)+nbr))*3;
    float f3=cp[0], f4=cp[1], f5=cp[2];
    float f0=np2[0]-f3, f1=np2[1]-f4, f2=np2[2]-f5;
    float f[6] = {f0,f1,f2,f3,f4,f5};
    #pragma unroll
    for (int i=0;i<6;i++) acc[i] += (double)f[i];
    int k=6;
    #pragma unroll
    for (int i=0;i<6;i++)
      #pragma unroll
      for (int j=i;j<6;j++){ acc[k] += (double)f[i]*(double)f[j]; k++; }
  }
  #pragma unroll
  for (int k=0;k<27;k++){
    double s = acc[k];
    #pragma unroll
    for (int m=1;m<64;m<<=1) s += __shfl_xor(s,m);
    if (lane==0) sred[wv*32+k] = s;
  }
  __syncthreads();
  if (tid < 27)
    g_part[(size_t)blockIdx.x*32 + tid] = sred[tid] + sred[32+tid] + sred[64+tid] + sred[96+tid];
}

// finalize stage1a stats from Gram: S = w.fsum, Q = w^T G w
__global__ __launch_bounds__(64) void k_fing1(const float* __restrict__ w1a,
                                              const float* __restrict__ gg, const float* __restrict__ bb){
  __shared__ double gsum[27];
  int t = threadIdx.x;
  if (t < 27){
    double s = 0.0;
    for (int i=0;i<320;i++) s += g_part[(size_t)i*32 + t];
    gsum[t] = s;
  }
  __syncthreads();
  if (t < 60){
    float w[6];
    #pragma unroll
    for (int i=0;i<6;i++) w[i] = w1a[t*6+i];
    double S = 0.0;
    #pragma unroll
    for (int i=0;i<6;i++) S += (double)w[i]*gsum[i];
    double Q = 0.0; int k = 6;
    #pragma unroll
    for (int i=0;i<6;i++)
      #pragma unroll
      for (int j=i;j<6;j++){
        double cf = (i==j) ? 1.0 : 2.0;
        Q += cf*(double)w[i]*(double)w[j]*gsum[k]; k++;
      }
    double inv1 = 1.0/(double)EE;
    double m = S*inv1;
    double v = Q*inv1 - m*m;
    if (v < 0.0) v = 0.0;
    float r = (float)(1.0/sqrt(v + 1e-5));
    float A = r*gg[t];
    g_st[S1A_AB+t] = A;
    g_st[S1A_AB+64+t] = bb[t] - (float)m*A;
  }
}

// ==== stage1 conv-b (2 edges/thread): recompute y1a inline; h=lrelu(affine); y1b -> g_e2 + stats ====
__global__ __launch_bounds__(256) void k_conv1b(const float* __restrict__ xyz,
                                                const float* __restrict__ w1a, const float* __restrict__ w1b){
  __shared__ float ws[360];
  __shared__ float wbs[3600];
  __shared__ float As[60], Bs[60];
  __shared__ double sred[512];
  int tid = threadIdx.x, lane = tid & 63, wv = tid >> 6;
  for (int i=tid;i<360;i+=256) ws[i]=w1a[i];
  for (int i=tid;i<3600;i+=256) wbs[i]=w1b[i];
  if (tid<60){ As[tid]=g_st[S1A_AB+tid]; Bs[tid]=g_st[S1A_AB+64+tid]; }
  __syncthreads();
  int e0 = blockIdx.x*512 + tid;
  int e1 = e0 + 256;
  int row0 = e0 / KK, row1 = e1 / KK;
  int b0 = row0 >> 11, b1 = row1 >> 11;
  int nb0 = g_idx[e0], nb1 = g_idx[e1];
  const float* cp0 = xyz + (size_t)row0*3;
  const float* np0 = xyz + ((size_t)((b0<<11)+nb0))*3;
  const float* cp1 = xyz + (size_t)row1*3;
  const float* np1 = xyz + ((size_t)((b1<<11)+nb1))*3;
  float c00=cp0[0], c01=cp0[1], c02=cp0[2];
  float d00=np0[0]-c00, d01=np0[1]-c01, d02=np0[2]-c02;
  float c10=cp1[0], c11=cp1[1], c12=cp1[2];
  float d10=np1[0]-c10, d11=np1[1]-c11, d12=np1[2]-c12;
  float h0[60], h1[60];
  #pragma unroll 4
  for (int o=0;o<60;o++){
    float w0=ws[o*6], w1=ws[o*6+1], w2=ws[o*6+2], w3=ws[o*6+3], w4=ws[o*6+4], w5=ws[o*6+5];
    float ya = w0*d00 + w1*d01 + w2*d02 + w3*c00 + w4*c01 + w5*c02;
    float yb = w0*d10 + w1*d11 + w2*d12 + w3*c10 + w4*c11 + w5*c12;
    h0[o] = lrelu(fmaf(As[o], ya, Bs[o]));
    h1[o] = lrelu(fmaf(As[o], yb, Bs[o]));
  }
  const float4* wb4 = (const float4*)wbs;
  double rs=0.0, rq=0.0;
  for (int o=0;o<60;o++){
    float y0=0.f, y1=0.f;
    #pragma unroll
    for (int c4=0;c4<15;c4++){
      float4 wvv = wb4[o*15+c4];
      y0 = fmaf(wvv.x, h0[c4*4],   y0);  y1 = fmaf(wvv.x, h1[c4*4],   y1);
      y0 = fmaf(wvv.y, h0[c4*4+1], y0);  y1 = fmaf(wvv.y, h1[c4*4+1], y1);
      y0 = fmaf(wvv.z, h0[c4*4+2], y0);  y1 = fmaf(wvv.z, h1[c4*4+2], y1);
      y0 = fmaf(wvv.w, h0[c4*4+3], y0);  y1 = fmaf(wvv.w, h1[c4*4+3], y1);
    }
    g_e2[(size_t)o*EE + e0] = y0;
    g_e2[(size_t)o*EE + e1] = y1;
    float s=y0+y1, q=fmaf(y0,y0,y1*y1);
    #pragma unroll
    for (int m=1;m<64;m<<=1){ s += __shfl_xor(s,m); q += __shfl_xor(q,m); }
    if (lane==o){ rs += (double)s; rq += (double)q; }
  }
  sred[wv*128 + lane] = rs;
  sred[wv*128 + 64 + lane] = rq;
  __syncthreads();
  if (tid < 128)
    g_part[(size_t)blockIdx.x*128 + tid] = sred[tid] + sred[128+tid] + sred[256+tid] + sred[384+tid];
}

// ==== stage1 final: x1[bn][o] = max_k lrelu(affine(y1b)).  60x128 blocks ====
__global__ __launch_bounds__(256) void k_final1s(float* __restrict__ outb){
  int o = blockIdx.x >> 7;
  int bn = ((blockIdx.x & 127) << 8) + threadIdx.x;
  int b = bn >> 11, n = bn & 2047;
  float A = g_st[S1B_AB+o], Bv = g_st[S1B_AB+64+o];
  const float* src = g_e2 + (size_t)o*EE + (size_t)bn*KK;
  float mx = NEG_BIG;
  #pragma unroll
  for (int k=0;k<KK;k++) mx = fmaxf(mx, lrelu(fmaf(A, src[k], Bv)));
  g_xpf[(size_t)bn*120 + o] = mx;
  outb[O_XPER + (size_t)(b*120+o)*NN + n] = mx;
}

// ==== stage2 point transforms: U = Wd.x1, V = (Wc-Wd).x1 -> g_e2 [p][64] ====
__global__ __launch_bounds__(256) void k_pgem2(const float* __restrict__ w2a){
  __shared__ float wd[3600], wcd[3600];
  int tid = threadIdx.x;
  for (int i=tid;i<3600;i+=256){
    int o = i/60, c = i%60;
    float a = w2a[o*120+c], bvl = w2a[o*120+60+c];
    wd[i] = a; wcd[i] = bvl - a;
  }
  __syncthreads();
  int p = blockIdx.x*256 + tid;
  float x[60];
  xrow(p, 0, 60, x);
  float* gU = g_e2;
  float* gV = g_e2 + (size_t)PP*64;
  const float4* wd4  = (const float4*)wd;
  const float4* wcd4 = (const float4*)wcd;
  #pragma unroll 4
  for (int o=0;o<60;o++){
    float u=0.f, v=0.f;
    #pragma unroll
    for (int c4=0;c4<15;c4++){
      float4 a4 = wd4[o*15+c4];
      float4 b4 = wcd4[o*15+c4];
      u = fmaf(a4.x, x[c4*4],   u); v = fmaf(b4.x, x[c4*4],   v);
      u = fmaf(a4.y, x[c4*4+1], u); v = fmaf(b4.y, x[c4*4+1], v);
      u = fmaf(a4.z, x[c4*4+2], u); v = fmaf(b4.z, x[c4*4+2], v);
      u = fmaf(a4.w, x[c4*4+3], u); v = fmaf(b4.w, x[c4*4+3], v);
    }
    gU[(size_t)p*64 + o] = u;
    gV[(size_t)p*64 + o] = v;
  }
}

// ==== stage2 conv-a: y2a = U[nbr] + V[center] -> g_e1 + butterfly stats ====
__global__ __launch_bounds__(256) void k_conv2a(){
  __shared__ double sred[512];
  int tid = threadIdx.x, lane = tid & 63, wv = tid >> 6;
  int edge = blockIdx.x*256 + tid;
  int row = edge / KK;
  int b = row >> 11;
  int nbr = g_idx[edge];
  int pn = (b<<11)+nbr;
  const float4* gU = (const float4*)g_e2;
  const float4* gV = (const float4*)(g_e2 + (size_t)PP*64);
  double rs=0.0, rq=0.0;
  #pragma unroll
  for (int o4=0;o4<15;o4++){
    float4 uu = gU[(size_t)pn*16 + o4];
    float4 vv = gV[(size_t)row*16 + o4];
    float y0=uu.x+vv.x, y1=uu.y+vv.y, y2=uu.z+vv.z, y3=uu.w+vv.w;
    g_e1[(size_t)(o4*4+0)*EE + edge] = y0;
    g_e1[(size_t)(o4*4+1)*EE + edge] = y1;
    g_e1[(size_t)(o4*4+2)*EE + edge] = y2;
    g_e1[(size_t)(o4*4+3)*EE + edge] = y3;
    float ys[4] = {y0,y1,y2,y3};
    #pragma unroll
    for (int j=0;j<4;j++){
      float s=ys[j], q=ys[j]*ys[j];
      #pragma unroll
      for (int m=1;m<64;m<<=1){ s += __shfl_xor(s,m); q += __shfl_xor(q,m); }
      if (lane==o4*4+j){ rs += (double)s; rq += (double)q; }
    }
  }
  sred[wv*128 + lane] = rs;
  sred[wv*128 + 64 + lane] = rq;
  __syncthreads();
  if (tid < 128)
    g_part[(size_t)blockIdx.x*128 + tid] = sred[tid] + sred[128+tid] + sred[256+tid] + sred[384+tid];
}

// ==== stage2 conv-b (2 edges/thread): h=lrelu(affine(y2a)); y2b=w2b.h -> g_e2 + stats ====
__global__ __launch_bounds__(256) void k_conv2b(const float* __restrict__ w2b){
  __shared__ float wbs[3600];
  __shared__ float As[60], Bs[60];
  __shared__ double sred[512];
  int tid = threadIdx.x, lane = tid & 63, wv = tid >> 6;
  for (int i=tid;i<3600;i+=256) wbs[i]=w2b[i];
  if (tid<60){ As[tid]=g_st[S2A_AB+tid]; Bs[tid]=g_st[S2A_AB+64+tid]; }
  __syncthreads();
  int e0 = blockIdx.x*512 + tid;
  int e1 = e0 + 256;
  float h0[60], h1[60];
  #pragma unroll 4
  for (int o=0;o<60;o++){
    h0[o] = lrelu(fmaf(As[o], g_e1[(size_t)o*EE + e0], Bs[o]));
    h1[o] = lrelu(fmaf(As[o], g_e1[(size_t)o*EE + e1], Bs[o]));
  }
  const float4* wb4 = (const float4*)wbs;
  double rs=0.0, rq=0.0;
  for (int o=0;o<60;o++){
    float y0=0.f, y1=0.f;
    #pragma unroll
    for (int c4=0;c4<15;c4++){
      float4 wvv = wb4[o*15+c4];
      y0 = fmaf(wvv.x, h0[c4*4],   y0);  y1 = fmaf(wvv.x, h1[c4*4],   y1);
      y0 = fmaf(wvv.y, h0[c4*4+1], y0);  y1 = fmaf(wvv.y, h1[c4*4+1], y1);
      y0 = fmaf(wvv.z, h0[c4*4+2], y0);  y1 = fmaf(wvv.z, h1[c4*4+2], y1);
      y0 = fmaf(wvv.w, h0[c4*4+3], y0);  y1 = fmaf(wvv.w, h1[c4*4+3], y1);
    }
    g_e2[(size_t)o*EE + e0] = y0;
    g_e2[(size_t)o*EE + e1] = y1;
    float s=y0+y1, q=fmaf(y0,y0,y1*y1);
    #pragma unroll
    for (int m=1;m<64;m<<=1){ s += __shfl_xor(s,m); q += __shfl_xor(q,m); }
    if (lane==o){ rs += (double)s; rq += (double)q; }
  }
  sred[wv*128 + lane] = rs;
  sred[wv*128 + 64 + lane] = rq;
  __syncthreads();
  if (tid < 128)
    g_part[(size_t)blockIdx.x*128 + tid] = sred[tid] + sred[128+tid] + sred[256+tid] + sred[384+tid];
}

// ==== stage2 final: x2 from g_e2 ====
__global__ __launch_bounds__(256) void k_final2s(float* __restrict__ outb){
  int o = blockIdx.x >> 7;
  int bn = ((blockIdx.x & 127) << 8) + threadIdx.x;
  int b = bn >> 11, n = bn & 2047;
  float A = g_st[S2B_AB+o], Bv = g_st[S2B_AB+64+o];
  const float* src = g_e2 + (size_t)o*EE + (size_t)bn*KK;
  float mx = NEG_BIG;
  #pragma unroll
  for (int k=0;k<KK;k++) mx = fmaxf(mx, lrelu(fmaf(A, src[k], Bv)));
  g_xpf[(size_t)bn*120 + 60 + o] = mx;
  outb[O_XPER + (size_t)(b*120+60+o)*NN + n] = mx;
}

// ==== stage3 fused, half-channel scheme: W half-row (15 float4) REGISTER-resident ====
// grid = 1024 = seg(8) x b(16) x ec(8); 256 thr = 4 waves x 64 lanes
// wave wv owns channels ec*128 + wv*32 + (lane&31); lane>=32 computes upper half (c=60..119)
#define WH_DECL(i) float4 W##i;
#define WH_LOAD(i) W##i = wp[i];
#define WH_DOT(i)  { float4 xv = xp[i]; \
  a0 = fmaf(W##i.x, xv.x, a0); a1 = fmaf(W##i.y, xv.y, a1); \
  a2 = fmaf(W##i.z, xv.z, a2); a3 = fmaf(W##i.w, xv.w, a3); }
#define WH_ALL(OP) \
  OP(0) OP(1) OP(2) OP(3) OP(4) OP(5) OP(6) OP(7) OP(8) OP(9) \
  OP(10) OP(11) OP(12) OP(13) OP(14)

__global__ __launch_bounds__(256) void k_max3s2(const float* __restrict__ wc3){
  __shared__ float xt[64*120];          // 30.7 KB
  int tid = threadIdx.x;
  int lane = tid & 63, wv = tid >> 6;
  int half = lane >> 5;                 // 0: c=0..59, 1: c=60..119
  int ec  = blockIdx.x & 7;
  int b   = (blockIdx.x >> 3) & 15;
  int seg = blockIdx.x >> 7;            // 0..7, 256 points each
  int e   = ec*128 + wv*32 + (lane & 31);
  WH_ALL(WH_DECL)
  {
    const float4* wp = (const float4*)(wc3 + (size_t)e*120 + half*60);
    WH_ALL(WH_LOAD)
  }
  float mx = NEG_BIG, mn = -NEG_BIG, S = 0.f, Q = 0.f;
  for (int tile=0; tile<4; tile++){
    int p0 = b*2048 + seg*256 + tile*64;
    __syncthreads();
    for (int v=tid; v<1920; v+=256){
      int pk = v/30, c4 = v%30;
      ((float4*)xt)[pk*30+c4] = *(const float4*)(g_xpf + (size_t)(p0+pk)*120 + c4*4);
    }
    __syncthreads();
    for (int k=0;k<64;k++){
      const float4* xp = (const float4*)(xt + k*120) + half*15;
      float a0=0.f,a1=0.f,a2=0.f,a3=0.f;
      WH_ALL(WH_DOT)
      float p = (a0+a1)+(a2+a3);
      float y = p + __shfl_xor(p, 32);  // combine halves
      mx = fmaxf(mx, y);
      mn = fminf(mn, y);
      S += y;
      Q = fmaf(y, y, Q);
    }
  }
  if (half == 0){
    float* MB = (float*)g_part;
    int slot = (seg*16+b)*1024 + e;
    MB[P3_MX + slot] = mx;
    MB[P3_MN + slot] = mn;
    MB[P3_S  + slot] = S;
    MB[P3_Q  + slot] = Q;
  }
}

// stage3 finalize: reduce 128 S/Q partials per channel -> A3/B3
__global__ __launch_bounds__(64) void k_fin3R(const float* __restrict__ gg, const float* __restrict__ bb){
  int e = blockIdx.x*64 + threadIdx.x;  // grid 16
  const float* MB = (const float*)g_part;
  double S=0.0, Q=0.0;
  for (int j=0;j<128;j++){
    S += (double)MB[P3_S + j*1024 + e];
    Q += (double)MB[P3_Q + j*1024 + e];
  }
  double inv3 = 1.0/(double)PP;
  double m = S*inv3;
  double v = Q*inv3 - m*m;
  if (v < 0.0) v = 0.0;
  float r = (float)(1.0/sqrt(v + 1e-5));
  float A = r*gg[e];
  g_st[S3A+e] = A;
  g_st[S3B+e] = bb[e] - (float)m*A;
}

// ---------------- VAE head: g from max/min + affine (monotone commute), then mu/lv/z
__global__ __launch_bounds__(256) void k_head(const float* __restrict__ eps,
                                              const float* __restrict__ wmu, const float* __restrict__ bmu,
                                              const float* __restrict__ wvar, const float* __restrict__ bvar,
                                              float* __restrict__ outb){
  int b = blockIdx.x, j = threadIdx.x;
  __shared__ float gs[1024];
  const float* MB = (const float*)g_part;
  for (int i=j;i<1024;i+=256){
    float A = g_st[S3A+i], B = g_st[S3B+i];
    float M = NEG_BIG, m2 = -NEG_BIG;
    #pragma unroll
    for (int sg=0;sg<8;sg++){
      M  = fmaxf(M,  MB[P3_MX + (sg*16+b)*1024 + i]);
      m2 = fminf(m2, MB[P3_MN + (sg*16+b)*1024 + i]);
    }
    float y = (A > 0.f) ? M : ((A < 0.f) ? m2 : M);
    gs[i] = lrelu(fmaf(A, y, B));
  }
  __syncthreads();
  float mu = bmu[j], lv = bvar[j];
  const float4* wm = (const float4*)(wmu + (size_t)j*1024);
  const float4* wv = (const float4*)(wvar + (size_t)j*1024);
  #pragma unroll 4
  for (int e=0;e<256;e++){
    float4 a = wm[e], c = wv[e];
    const float* g4 = gs + e*4;
    mu = fmaf(a.x,g4[0], fmaf(a.y,g4[1], fmaf(a.z,g4[2], fmaf(a.w,g4[3], mu))));
    lv = fmaf(c.x,g4[0], fmaf(c.y,g4[1], fmaf(c.z,g4[2], fmaf(c.w,g4[3], lv))));
  }
  float z = fmaf(eps[b*256+j], expf(0.5f*lv), mu);
  g_zf[b*256+j] = z;
  outb[O_MU + b*256 + j] = mu;
  outb[O_LV + b*256 + j] = lv;
  outb[O_Z  + b*256 + j] = z;
}

// ---------------- cuboid branch
__global__ __launch_bounds__(256) void k_cuboid(const float* __restrict__ wenc,
                                                const float* __restrict__ wcub1, const float* __restrict__ wcub2,
                                                const float* __restrict__ wk, float* __restrict__ outb){
  int b = blockIdx.x, t = threadIdx.x;
  __shared__ float xc[320*16];
  __shared__ float hh[256*16];
  __shared__ float xq[120*16];
  for (int i=t;i<320*16;i+=256){
    int c = i>>4, m = i&15;
    xc[i] = (c<256) ? g_zf[b*256+c] : lrelu(wenc[(c-256)*16+m]);
  }
  __syncthreads();
  {
    float acc[16];
    #pragma unroll
    for (int m=0;m<16;m++) acc[m]=0.f;
    for (int c=0;c<320;c++){
      float wv = wcub1[(size_t)t*320+c];
      #pragma unroll
      for (int m=0;m<16;m++) acc[m] = fmaf(wv, xc[c*16+m], acc[m]);
    }
    #pragma unroll
    for (int m=0;m<16;m++) hh[t*16+m] = lrelu(acc[m]);
  }
  __syncthreads();
  if (t<120){
    float a2[16];
    #pragma unroll
    for (int m=0;m<16;m++) a2[m]=0.f;
    for (int c=0;c<256;c++){
      float wv = wcub2[(size_t)t*256+c];
      #pragma unroll
      for (int m=0;m<16;m++) a2[m] = fmaf(wv, hh[c*16+m], a2[m]);
    }
    #pragma unroll
    for (int m=0;m<16;m++){
      float v = lrelu(a2[m]);
      xq[t*16+m] = v;
      outb[O_XCUB + b*1920 + t*16 + m] = v;
    }
  }
  __syncthreads();
  if (t<64){
    float a3[16];
    #pragma unroll
    for (int m=0;m<16;m++) a3[m]=0.f;
    for (int c=0;c<120;c++){
      float wv = wk[t*120+c];
      #pragma unroll
      for (int m=0;m<16;m++) a3[m] = fmaf(wv, xq[c*16+m], a3[m]);
    }
    #pragma unroll
    for (int m=0;m<16;m++) g_Kf[b*1024 + t*16 + m] = a3[m];
  }
}

// ---------------- attention
__global__ __launch_bounds__(64) void k_attn(const float* __restrict__ wq, float* __restrict__ outb){
  int p = blockIdx.x*64 + threadIdx.x;
  int b = p >> 11;
  float x[120];
  xrow(p, 0, 120, x);
  float sc[16];
  #pragma unroll
  for (int m=0;m<16;m++) sc[m]=0.f;
  for (int a=0;a<64;a++){
    float q=0.f;
    #pragma unroll
    for (int c=0;c<120;c++) q = fmaf(wq[a*120+c], x[c], q);
    q *= 0.125f;
    const float* kf = g_Kf + b*1024 + a*16;
    #pragma unroll
    for (int m=0;m<16;m++) sc[m] = fmaf(kf[m], q, sc[m]);
  }
  float mx = sc[0];
  #pragma unroll
  for (int m=1;m<16;m++) mx = fmaxf(mx, sc[m]);
  float s=0.f;
  #pragma unroll
  for (int m=0;m<16;m++){ sc[m] = expf(sc[m]-mx); s += sc[m]; }
  float inv = 1.f/s;
  #pragma unroll
  for (int m=0;m<16;m++) outb[O_ASG + (size_t)p*16 + m] = sc[m]*inv;
}

extern "C" void kernel_launch(void* const* d_in, const int* in_sizes, int n_in,
                              void* d_out, int out_size, void* d_ws, size_t ws_size,
                              hipStream_t stream){
  const float* xyz  = (const float*)d_in[0];
  const float* eps  = (const float*)d_in[2];
  const float* w1a  = (const float*)d_in[3];
  const float* w1b  = (const float*)d_in[4];
  const float* w2a  = (const float*)d_in[5];
  const float* w2b  = (const float*)d_in[6];
  const float* wc3  = (const float*)d_in[7];
  const float* wmu  = (const float*)d_in[8];
  const float* bmu  = (const float*)d_in[9];
  const float* wvar = (const float*)d_in[10];
  const float* bvar = (const float*)d_in[11];
  const float* wenc = (const float*)d_in[12];
  const float* wcub1= (const float*)d_in[13];
  const float* wcub2= (const float*)d_in[14];
  const float* wq   = (const float*)d_in[15];
  const float* wk   = (const float*)d_in[16];
  const float* g1a  = (const float*)d_in[17];
  const float* b1a  = (const float*)d_in[18];
  const float* g1b  = (const float*)d_in[19];
  const float* b1b  = (const float*)d_in[20];
  const float* g2a  = (const float*)d_in[21];
  const float* b2a  = (const float*)d_in[22];
  const float* g2b  = (const float*)d_in[23];
  const float* b2b  = (const float*)d_in[24];
  const float* g3   = (const float*)d_in[25];
  const float* b3   = (const float*)d_in[26];
  float* outb = (float*)d_out;

  const double inv1 = 1.0/(double)EE;

  k_knnt<<<2048,128,0,stream>>>(xyz);
  k_knnu<<<128,256,0,stream>>>();
  k_knns1<<<1024,256,0,stream>>>(xyz);
  k_knns2<<<128,256,0,stream>>>();
  k_knns3<<<1024,256,0,stream>>>(xyz);
  // stage 1 (stats1a via feat-Gram; conv1a eliminated)
  k_gram1<<<320,256,0,stream>>>(xyz);
  k_fing1<<<1,64,0,stream>>>(w1a, g1a, b1a);
  k_conv1b<<<1280,256,0,stream>>>(xyz, w1a, w1b);
  k_red60<<<128,256,0,stream>>>(S1B_D, 1280);
  k_fin<<<1,64,0,stream>>>(g1b, b1b, S1B_D, S1B_AB, inv1);
  k_final1s<<<7680,256,0,stream>>>(outb);
  // stage 2
  k_pgem2<<<128,256,0,stream>>>(w2a);
  k_conv2a<<<2560,256,0,stream>>>();
  k_red60<<<128,256,0,stream>>>(S2A_D, 2560);
  k_fin<<<1,64,0,stream>>>(g2a, b2a, S2A_D, S2A_AB, inv1);
  k_conv2b<<<1280,256,0,stream>>>(w2b);
  k_red60<<<128,256,0,stream>>>(S2B_D, 1280);
  k_fin<<<1,64,0,stream>>>(g2b, b2b, S2B_D, S2B_AB, inv1);
  k_final2s<<<7680,256,0,stream>>>(outb);
  // stage 3 (fused: half-channel register scheme; y3 never materialized)
  k_max3s2<<<1024,256,0,stream>>>(wc3);
  k_fin3R<<<16,64,0,stream>>>(g3, b3);
  // heads
  k_head<<<16,256,0,stream>>>(eps, wmu, bmu, wvar, bvar, outb);
  k_cuboid<<<16,256,0,stream>>>(wenc, wcub1, wcub2, wk, outb);
  k_attn<<<512,64,0,stream>>>(wq, outb);
}

// Round 29
// 1215.340 us; speedup vs baseline: 1.1810x; 1.0112x over previous
//
#include <hip/hip_runtime.h>

typedef unsigned int u32;
typedef unsigned short u16;

// problem sizes
#define BB 16
#define NN 2048
#define KK 20
#define EE (BB*NN*KK)      // 655360 edges
#define PP (BB*NN)         // 32768 points
#define NCHK 8             // kNN candidate chunks
#define CHKSZ (NN/NCHK)    // 256 candidates per chunk

// output element offsets (fp32 elements, tuple flattened in return order)
#define O_XPER 0
#define O_XCUB 3932160
#define O_Z    3962880
#define O_MU   3966976
#define O_LV   3971072
#define O_ASG  3975168

// ---- static device scratch: all write-before-read each call, no atomics ----
__device__ double g_part[524288];             // stats partials / kNN counters / s3 partials (4 MB)
__device__ double g_std[2560];                // reduced double sums
__device__ float  g_st[2560];                 // BN A/B per stage + stage3 A/B
__device__ float  g_zf[BB*256];               // z
__device__ float  g_Kf[BB*1024];              // Kf (B,64,16)
__device__ u16    g_idx[EE];                  // kNN indices
__device__ float  g_xpf[(size_t)PP*120];      // point-major x_per mirror (15.7 MB)
__device__ float  g_e1[(size_t)EE*60];        // knn chunk-tops -> y2a
__device__ float  g_e2[(size_t)EE*60];        // knn T -> y1b -> U/V -> y2b

// double-sum bases in g_std: per 60-ch stage {sum@+0, sq@+64}
#define S1B_D 128
#define S2A_D 256
#define S2B_D 384
// A/B bases in g_st: per 60-ch stage {A@+0, B@+64}
#define S1A_AB 0
#define S1B_AB 128
#define S2A_AB 256
#define S2B_AB 384
#define S3A 512
#define S3B 1536

// stage3 partials: float view of g_part base (free after last k_red60)
// MX@0, MN@131072, S@262144, Q@393216 (each 128*1024 floats)
#define P3_MX 0
#define P3_MN 131072
#define P3_S  262144
#define P3_Q  393216

#define NEG_BIG -1.0e30f

__device__ __forceinline__ float lrelu(float x){ return x > 0.f ? x : 0.2f*x; }

__device__ __forceinline__ void xrow(int bn, int c0, int cnt, float* d){
  const float* s = g_xpf + (size_t)bn*120 + c0;
  #pragma unroll
  for (int i=0;i<cnt;i+=4){
    float4 v = *(const float4*)(s+i);
    d[i]=v.x; d[i+1]=v.y; d[i+2]=v.z; d[i+3]=v.w;
  }
}

// shared pd computation: MUST be bit-identical across all kNN kernels
__device__ __forceinline__ float pdcalc(float4 pm, float qx, float qy, float qz, float qw){
  float dot = fmaf(qx,pm.x, fmaf(qy,pm.y, qz*pm.z));
  float t = fmaf(2.f, dot, -qw);
  return t - pm.w;                      // == -||q-p||^2
}

// ---- float-only top-20 chain (distances only; 2 VALU ops per stage)
#define KT_DECL \
  float td0=NEG_BIG,td1=NEG_BIG,td2=NEG_BIG,td3=NEG_BIG,td4=NEG_BIG, \
        td5=NEG_BIG,td6=NEG_BIG,td7=NEG_BIG,td8=NEG_BIG,td9=NEG_BIG, \
        td10=NEG_BIG,td11=NEG_BIG,td12=NEG_BIG,td13=NEG_BIG,td14=NEG_BIG, \
        td15=NEG_BIG,td16=NEG_BIG,td17=NEG_BIG,td18=NEG_BIG,td19=NEG_BIG;
#define KT_CSW(u,l) { float mx = fmaxf(td##u, td##l); float mn = fminf(td##u, td##l); td##u = mx; td##l = mn; }
#define KT_INSERT(pd) \
  if ((pd) > td19){ \
    td19 = (pd); \
    KT_CSW(18,19) KT_CSW(17,18) KT_CSW(16,17) KT_CSW(15,16) \
    KT_CSW(14,15) KT_CSW(13,14) KT_CSW(12,13) KT_CSW(11,12) \
    KT_CSW(10,11) KT_CSW(9,10)  KT_CSW(8,9)   KT_CSW(7,8)   \
    KT_CSW(6,7)   KT_CSW(5,6)   KT_CSW(4,5)   KT_CSW(3,4)   \
    KT_CSW(2,3)   KT_CSW(1,2)   KT_CSW(0,1) }

// ---------------- kNN pass 1
__global__ __launch_bounds__(128) void k_knnt(const float* __restrict__ xyz){
  __shared__ float4 cand[CHKSZ];
  int qg = blockIdx.x >> 3;
  int c  = blockIdx.x & 7;
  int b  = qg >> 4;
  int n0 = (qg & 15) << 7;
  int t  = threadIdx.x;
  int m0 = c*CHKSZ;
  for (int i=t;i<CHKSZ;i+=128){
    const float* s = xyz + ((size_t)((b<<11)+m0+i))*3;
    float x=s[0], y=s[1], z=s[2];
    cand[i] = make_float4(x,y,z, fmaf(x,x,fmaf(y,y,z*z)));
  }
  __syncthreads();
  int n = n0 + t;
  const float* qs = xyz + ((size_t)((b<<11)+n))*3;
  float qx=qs[0], qy=qs[1], qz=qs[2];
  float qw = fmaf(qx,qx,fmaf(qy,qy,qz*qz));
  KT_DECL
  for (int i=0;i<CHKSZ;i++){
    float pd = pdcalc(cand[i], qx,qy,qz,qw);
    KT_INSERT(pd)
  }
  int p = (b<<11) + n;
  float* outd = g_e1;
  #define KOUT(k) outd[(size_t)(c*KK+k)*PP + p] = td##k;
  KOUT(0) KOUT(1) KOUT(2) KOUT(3) KOUT(4) KOUT(5) KOUT(6) KOUT(7) KOUT(8) KOUT(9)
  KOUT(10) KOUT(11) KOUT(12) KOUT(13) KOUT(14) KOUT(15) KOUT(16) KOUT(17) KOUT(18) KOUT(19)
  #undef KOUT
}

// ---------------- kNN pass 2: exact 20th-largest threshold T[q]
__global__ __launch_bounds__(256) void k_knnu(){
  int q = blockIdx.x*256 + threadIdx.x;
  const float* ind = g_e1;
  KT_DECL
  for (int i=0;i<NCHK*KK;i++){
    float pd = ind[(size_t)i*PP + q];
    KT_INSERT(pd)
  }
  g_e2[q] = td19;
}

// ---------------- kNN pass 3: count pd>T, pd==T per (query, chunk)
__global__ __launch_bounds__(256) void k_knns1(const float* __restrict__ xyz){
  __shared__ float4 cand[CHKSZ];
  int gid = blockIdx.x*256 + threadIdx.x;
  int c = gid >> 15;
  int q = gid & (PP-1);
  int b = q >> 11;
  int t = threadIdx.x;
  for (int i=t;i<CHKSZ;i+=256){
    const float* s = xyz + ((size_t)((b<<11)+c*CHKSZ+i))*3;
    float x=s[0], y=s[1], z=s[2];
    cand[i] = make_float4(x,y,z, fmaf(x,x,fmaf(y,y,z*z)));
  }
  __syncthreads();
  const float* qs = xyz + (size_t)q*3;
  float qx=qs[0], qy=qs[1], qz=qs[2];
  float qw = fmaf(qx,qx,fmaf(qy,qy,qz*qz));
  float T = g_e2[q];
  u32 cgt=0, ceq=0;
  for (int i=0;i<CHKSZ;i++){
    float pd = pdcalc(cand[i], qx,qy,qz,qw);
    cgt += (pd > T) ? 1u : 0u;
    ceq += (pd == T) ? 1u : 0u;
  }
  u32* cntg = (u32*)g_part;
  u32* cnte = cntg + NCHK*PP;
  cntg[c*PP + q] = cgt;
  cnte[c*PP + q] = ceq;
}

// ---------------- kNN pass 4: prefix over chunks
__global__ __launch_bounds__(256) void k_knns2(){
  int q = blockIdx.x*256 + threadIdx.x;
  u32* cntg = (u32*)g_part;
  u32* cnte = cntg + NCHK*PP;
  u32* bg   = cnte + NCHK*PP;
  u32* be   = bg   + NCHK*PP;
  u32 acc = 0;
  for (int c=0;c<NCHK;c++){ bg[c*PP+q] = acc; acc += cntg[c*PP+q]; }
  u32 eacc = acc;
  for (int c=0;c<NCHK;c++){ be[c*PP+q] = eacc; eacc += cnte[c*PP+q]; }
}

// ---------------- kNN pass 5: write indices
__global__ __launch_bounds__(256) void k_knns3(const float* __restrict__ xyz){
  __shared__ float4 cand[CHKSZ];
  int gid = blockIdx.x*256 + threadIdx.x;
  int c = gid >> 15;
  int q = gid & (PP-1);
  int b = q >> 11;
  int t = threadIdx.x;
  for (int i=t;i<CHKSZ;i+=256){
    const float* s = xyz + ((size_t)((b<<11)+c*CHKSZ+i))*3;
    float x=s[0], y=s[1], z=s[2];
    cand[i] = make_float4(x,y,z, fmaf(x,x,fmaf(y,y,z*z)));
  }
  __syncthreads();
  const float* qs = xyz + (size_t)q*3;
  float qx=qs[0], qy=qs[1], qz=qs[2];
  float qw = fmaf(qx,qx,fmaf(qy,qy,qz*qz));
  float T = g_e2[q];
  const u32* cntg = (const u32*)g_part;
  const u32* cnte = cntg + NCHK*PP;
  const u32* bg   = cnte + NCHK*PP;
  const u32* be   = bg   + NCHK*PP;
  u32 wgt = bg[c*PP+q];
  u32 weq = be[c*PP+q];
  u16* o = g_idx + (size_t)q*KK;
  for (int i=0;i<CHKSZ;i++){
    float pd = pdcalc(cand[i], qx,qy,qz,qw);
    int m = c*CHKSZ + i;
    if (pd > T && wgt < KK){ o[wgt] = (u16)m; wgt++; }
    else if (pd == T && weq < KK){ o[weq] = (u16)m; weq++; }
  }
}

// ---------------- reduce per-block double partials into g_std[dbase..] (nblk blocks)
__global__ __launch_bounds__(256) void k_red60(int dbase, int nblk){
  __shared__ double red[256];
  int s = blockIdx.x;                   // slot 0..127
  int t = threadIdx.x;
  double acc = 0.0;
  for (int i=t;i<nblk;i+=256) acc += g_part[(size_t)i*128 + s];
  red[t] = acc; __syncthreads();
  for (int w=128; w>0; w>>=1){ if (t<w) red[t]+=red[t+w]; __syncthreads(); }
  if (t==0) g_std[dbase+s] = red[0];
}

// ---------------- BN finalize in double
__global__ __launch_bounds__(64) void k_fin(const float* __restrict__ g, const float* __restrict__ bb,
                                            int dbase, int abase, double invc){
  int c = threadIdx.x;
  if (c < 60){
    double m = g_std[dbase+c]*invc;
    double v = g_std[dbase+64+c]*invc - m*m;
    if (v < 0.0) v = 0.0;
    float r = (float)(1.0/sqrt(v + 1e-5));
    float a = r*g[c];
    g_st[abase+c] = a;
    g_st[abase+64+c] = bb[c] - (float)m*a;
  }
}

// ==== stage1a stats via 6x6 feat Gram: 320 blocks x 256 thr x 8 edges ====
__global__ __launch_bounds__(256) void k_gram1(const float* __restrict__ xyz){
  __shared__ double sred[128];
  int tid = threadIdx.x, lane = tid & 63, wv = tid >> 6;
  double acc[27];
  #pragma unroll
  for (int k=0;k<27;k++) acc[k]=0.0;
  for (int it=0; it<8; ++it){
    int edge = (it*320 + blockIdx.x)*256 + tid;
    int row = edge / KK;
    int b = row >> 11;
    int nbr = g_idx[edge];
    const float* cp = xyz + (size_t)row*3;
    const float* np2 = xyz + ((size_t)((b<<11)+nbr))*3;
    float f3=cp[0], f4=cp[1], f5=cp[2];
    float f0=np2[0]-f3, f1=np2[1]-f4, f2=np2[2]-f5;
    float f[6] = {f0,f1,f2,f3,f4,f5};
    #pragma unroll
    for (int i=0;i<6;i++) acc[i] += (double)f[i];
    int k=6;
    #pragma unroll
    for (int i=0;i<6;i++)
      #pragma unroll
      for (int j=i;j<6;j++){ acc[k] += (double)f[i]*(double)f[j]; k++; }
  }
  #pragma unroll
  for (int k=0;k<27;k++){
    double s = acc[k];
    #pragma unroll
    for (int m=1;m<64;m<<=1) s += __shfl_xor(s,m);
    if (lane==0) sred[wv*32+k] = s;
  }
  __syncthreads();
  if (tid < 27)
    g_part[(size_t)blockIdx.x*32 + tid] = sred[tid] + sred[32+tid] + sred[64+tid] + sred[96+tid];
}

// finalize stage1a stats from Gram: S = w.fsum, Q = w^T G w
__global__ __launch_bounds__(64) void k_fing1(const float* __restrict__ w1a,
                                              const float* __restrict__ gg, const float* __restrict__ bb){
  __shared__ double gsum[27];
  int t = threadIdx.x;
  if (t < 27){
    double s = 0.0;
    for (int i=0;i<320;i++) s += g_part[(size_t)i*32 + t];
    gsum[t] = s;
  }
  __syncthreads();
  if (t < 60){
    float w[6];
    #pragma unroll
    for (int i=0;i<6;i++) w[i] = w1a[t*6+i];
    double S = 0.0;
    #pragma unroll
    for (int i=0;i<6;i++) S += (double)w[i]*gsum[i];
    double Q = 0.0; int k = 6;
    #pragma unroll
    for (int i=0;i<6;i++)
      #pragma unroll
      for (int j=i;j<6;j++){
        double cf = (i==j) ? 1.0 : 2.0;
        Q += cf*(double)w[i]*(double)w[j]*gsum[k]; k++;
      }
    double inv1 = 1.0/(double)EE;
    double m = S*inv1;
    double v = Q*inv1 - m*m;
    if (v < 0.0) v = 0.0;
    float r = (float)(1.0/sqrt(v + 1e-5));
    float A = r*gg[t];
    g_st[S1A_AB+t] = A;
    g_st[S1A_AB+64+t] = bb[t] - (float)m*A;
  }
}

// ==== stage1 conv-b (2 edges/thread): recompute y1a inline; h=lrelu(affine); y1b -> g_e2 + stats ====
__global__ __launch_bounds__(256, 2) void k_conv1b(const float* __restrict__ xyz,
                                                const float* __restrict__ w1a, const float* __restrict__ w1b){
  __shared__ float ws[360];
  __shared__ float wbs[3600];
  __shared__ float As[60], Bs[60];
  __shared__ double sred[512];
  int tid = threadIdx.x, lane = tid & 63, wv = tid >> 6;
  for (int i=tid;i<360;i+=256) ws[i]=w1a[i];
  for (int i=tid;i<3600;i+=256) wbs[i]=w1b[i];
  if (tid<60){ As[tid]=g_st[S1A_AB+tid]; Bs[tid]=g_st[S1A_AB+64+tid]; }
  __syncthreads();
  int e0 = blockIdx.x*512 + tid;
  int e1 = e0 + 256;
  int row0 = e0 / KK, row1 = e1 / KK;
  int b0 = row0 >> 11, b1 = row1 >> 11;
  int nb0 = g_idx[e0], nb1 = g_idx[e1];
  const float* cp0 = xyz + (size_t)row0*3;
  const float* np0 = xyz + ((size_t)((b0<<11)+nb0))*3;
  const float* cp1 = xyz + (size_t)row1*3;
  const float* np1 = xyz + ((size_t)((b1<<11)+nb1))*3;
  float c00=cp0[0], c01=cp0[1], c02=cp0[2];
  float d00=np0[0]-c00, d01=np0[1]-c01, d02=np0[2]-c02;
  float c10=cp1[0], c11=cp1[1], c12=cp1[2];
  float d10=np1[0]-c10, d11=np1[1]-c11, d12=np1[2]-c12;
  float h0[60], h1[60];
  #pragma unroll
  for (int o=0;o<60;o++){
    float w0=ws[o*6], w1=ws[o*6+1], w2=ws[o*6+2], w3=ws[o*6+3], w4=ws[o*6+4], w5=ws[o*6+5];
    float ya = w0*d00 + w1*d01 + w2*d02 + w3*c00 + w4*c01 + w5*c02;
    float yb = w0*d10 + w1*d11 + w2*d12 + w3*c10 + w4*c11 + w5*c12;
    h0[o] = lrelu(fmaf(As[o], ya, Bs[o]));
    h1[o] = lrelu(fmaf(As[o], yb, Bs[o]));
  }
  #pragma unroll
  for (int o=0;o<60;o++){ asm volatile("" : "+v"(h0[o]), "+v"(h1[o])); }
  const float4* wb4 = (const float4*)wbs;
  double rs=0.0, rq=0.0;
  for (int o=0;o<60;o++){
    float y0=0.f, y1=0.f;
    #pragma unroll
    for (int c4=0;c4<15;c4++){
      float4 wvv = wb4[o*15+c4];
      y0 = fmaf(wvv.x, h0[c4*4],   y0);  y1 = fmaf(wvv.x, h1[c4*4],   y1);
      y0 = fmaf(wvv.y, h0[c4*4+1], y0);  y1 = fmaf(wvv.y, h1[c4*4+1], y1);
      y0 = fmaf(wvv.z, h0[c4*4+2], y0);  y1 = fmaf(wvv.z, h1[c4*4+2], y1);
      y0 = fmaf(wvv.w, h0[c4*4+3], y0);  y1 = fmaf(wvv.w, h1[c4*4+3], y1);
    }
    g_e2[(size_t)o*EE + e0] = y0;
    g_e2[(size_t)o*EE + e1] = y1;
    float s=y0+y1, q=fmaf(y0,y0,y1*y1);
    #pragma unroll
    for (int m=1;m<64;m<<=1){ s += __shfl_xor(s,m); q += __shfl_xor(q,m); }
    if (lane==o){ rs += (double)s; rq += (double)q; }
  }
  sred[wv*128 + lane] = rs;
  sred[wv*128 + 64 + lane] = rq;
  __syncthreads();
  if (tid < 128)
    g_part[(size_t)blockIdx.x*128 + tid] = sred[tid] + sred[128+tid] + sred[256+tid] + sred[384+tid];
}

// ==== stage1 final: x1[bn][o] = max_k lrelu(affine(y1b)).  60x128 blocks ====
__global__ __launch_bounds__(256) void k_final1s(float* __restrict__ outb){
  int o = blockIdx.x >> 7;
  int bn = ((blockIdx.x & 127) << 8) + threadIdx.x;
  int b = bn >> 11, n = bn & 2047;
  float A = g_st[S1B_AB+o], Bv = g_st[S1B_AB+64+o];
  const float* src = g_e2 + (size_t)o*EE + (size_t)bn*KK;
  float mx = NEG_BIG;
  #pragma unroll
  for (int k=0;k<KK;k++) mx = fmaxf(mx, lrelu(fmaf(A, src[k], Bv)));
  g_xpf[(size_t)bn*120 + o] = mx;
  outb[O_XPER + (size_t)(b*120+o)*NN + n] = mx;
}

// ==== stage2 point transforms: U = Wd.x1, V = (Wc-Wd).x1 -> g_e2 [p][64] ====
__global__ __launch_bounds__(256) void k_pgem2(const float* __restrict__ w2a){
  __shared__ float wd[3600], wcd[3600];
  int tid = threadIdx.x;
  for (int i=tid;i<3600;i+=256){
    int o = i/60, c = i%60;
    float a = w2a[o*120+c], bvl = w2a[o*120+60+c];
    wd[i] = a; wcd[i] = bvl - a;
  }
  __syncthreads();
  int p = blockIdx.x*256 + tid;
  float x[60];
  xrow(p, 0, 60, x);
  float* gU = g_e2;
  float* gV = g_e2 + (size_t)PP*64;
  const float4* wd4  = (const float4*)wd;
  const float4* wcd4 = (const float4*)wcd;
  #pragma unroll 4
  for (int o=0;o<60;o++){
    float u=0.f, v=0.f;
    #pragma unroll
    for (int c4=0;c4<15;c4++){
      float4 a4 = wd4[o*15+c4];
      float4 b4 = wcd4[o*15+c4];
      u = fmaf(a4.x, x[c4*4],   u); v = fmaf(b4.x, x[c4*4],   v);
      u = fmaf(a4.y, x[c4*4+1], u); v = fmaf(b4.y, x[c4*4+1], v);
      u = fmaf(a4.z, x[c4*4+2], u); v = fmaf(b4.z, x[c4*4+2], v);
      u = fmaf(a4.w, x[c4*4+3], u); v = fmaf(b4.w, x[c4*4+3], v);
    }
    gU[(size_t)p*64 + o] = u;
    gV[(size_t)p*64 + o] = v;
  }
}

// ==== stage2 conv-a: y2a = U[nbr] + V[center] -> g_e1 + butterfly stats ====
__global__ __launch_bounds__(256) void k_conv2a(){
  __shared__ double sred[512];
  int tid = threadIdx.x, lane = tid & 63, wv = tid >> 6;
  int edge = blockIdx.x*256 + tid;
  int row = edge / KK;
  int b = row >> 11;
  int nbr = g_idx[edge];
  int pn = (b<<11)+nbr;
  const float4* gU = (const float4*)g_e2;
  const float4* gV = (const float4*)(g_e2 + (size_t)PP*64);
  double rs=0.0, rq=0.0;
  #pragma unroll
  for (int o4=0;o4<15;o4++){
    float4 uu = gU[(size_t)pn*16 + o4];
    float4 vv = gV[(size_t)row*16 + o4];
    float y0=uu.x+vv.x, y1=uu.y+vv.y, y2=uu.z+vv.z, y3=uu.w+vv.w;
    g_e1[(size_t)(o4*4+0)*EE + edge] = y0;
    g_e1[(size_t)(o4*4+1)*EE + edge] = y1;
    g_e1[(size_t)(o4*4+2)*EE + edge] = y2;
    g_e1[(size_t)(o4*4+3)*EE + edge] = y3;
    float ys[4] = {y0,y1,y2,y3};
    #pragma unroll
    for (int j=0;j<4;j++){
      float s=ys[j], q=ys[j]*ys[j];
      #pragma unroll
      for (int m=1;m<64;m<<=1){ s += __shfl_xor(s,m); q += __shfl_xor(q,m); }
      if (lane==o4*4+j){ rs += (double)s; rq += (double)q; }
    }
  }
  sred[wv*128 + lane] = rs;
  sred[wv*128 + 64 + lane] = rq;
  __syncthreads();
  if (tid < 128)
    g_part[(size_t)blockIdx.x*128 + tid] = sred[tid] + sred[128+tid] + sred[256+tid] + sred[384+tid];
}

// ==== stage2 conv-b (2 edges/thread): h=lrelu(affine(y2a)); y2b=w2b.h -> g_e2 + stats ====
__global__ __launch_bounds__(256, 2) void k_conv2b(const float* __restrict__ w2b){
  __shared__ float wbs[3600];
  __shared__ float As[60], Bs[60];
  __shared__ double sred[512];
  int tid = threadIdx.x, lane = tid & 63, wv = tid >> 6;
  for (int i=tid;i<3600;i+=256) wbs[i]=w2b[i];
  if (tid<60){ As[tid]=g_st[S2A_AB+tid]; Bs[tid]=g_st[S2A_AB+64+tid]; }
  __syncthreads();
  int e0 = blockIdx.x*512 + tid;
  int e1 = e0 + 256;
  float h0[60], h1[60];
  #pragma unroll
  for (int o=0;o<60;o++){
    h0[o] = lrelu(fmaf(As[o], g_e1[(size_t)o*EE + e0], Bs[o]));
    h1[o] = lrelu(fmaf(As[o], g_e1[(size_t)o*EE + e1], Bs[o]));
  }
  #pragma unroll
  for (int o=0;o<60;o++){ asm volatile("" : "+v"(h0[o]), "+v"(h1[o])); }
  const float4* wb4 = (const float4*)wbs;
  double rs=0.0, rq=0.0;
  for (int o=0;o<60;o++){
    float y0=0.f, y1=0.f;
    #pragma unroll
    for (int c4=0;c4<15;c4++){
      float4 wvv = wb4[o*15+c4];
      y0 = fmaf(wvv.x, h0[c4*4],   y0);  y1 = fmaf(wvv.x, h1[c4*4],   y1);
      y0 = fmaf(wvv.y, h0[c4*4+1], y0);  y1 = fmaf(wvv.y, h1[c4*4+1], y1);
      y0 = fmaf(wvv.z, h0[c4*4+2], y0);  y1 = fmaf(wvv.z, h1[c4*4+2], y1);
      y0 = fmaf(wvv.w, h0[c4*4+3], y0);  y1 = fmaf(wvv.w, h1[c4*4+3], y1);
    }
    g_e2[(size_t)o*EE + e0] = y0;
    g_e2[(size_t)o*EE + e1] = y1;
    float s=y0+y1, q=fmaf(y0,y0,y1*y1);
    #pragma unroll
    for (int m=1;m<64;m<<=1){ s += __shfl_xor(s,m); q += __shfl_xor(q,m); }
    if (lane==o){ rs += (double)s; rq += (double)q; }
  }
  sred[wv*128 + lane] = rs;
  sred[wv*128 + 64 + lane] = rq;
  __syncthreads();
  if (tid < 128)
    g_part[(size_t)blockIdx.x*128 + tid] = sred[tid] + sred[128+tid] + sred[256+tid] + sred[384+tid];
}

// ==== stage2 final: x2 from g_e2 ====
__global__ __launch_bounds__(256) void k_final2s(float* __restrict__ outb){
  int o = blockIdx.x >> 7;
  int bn = ((blockIdx.x & 127) << 8) + threadIdx.x;
  int b = bn >> 11, n = bn & 2047;
  float A = g_st[S2B_AB+o], Bv = g_st[S2B_AB+64+o];
  const float* src = g_e2 + (size_t)o*EE + (size_t)bn*KK;
  float mx = NEG_BIG;
  #pragma unroll
  for (int k=0;k<KK;k++) mx = fmaxf(mx, lrelu(fmaf(A, src[k], Bv)));
  g_xpf[(size_t)bn*120 + 60 + o] = mx;
  outb[O_XPER + (size_t)(b*120+60+o)*NN + n] = mx;
}

// ==== stage3 fused, half-channel scheme: W half-row (15 float4) REGISTER-resident ====
// grid = 1024 = seg(8) x b(16) x ec(8); 256 thr = 4 waves x 64 lanes
// wave wv owns channels ec*128 + wv*32 + (lane&31); lane>=32 computes upper half (c=60..119)
#define WH_DECL(i) float4 W##i;
#define WH_LOAD(i) W##i = wp[i];
#define WH_PIN(i)  asm volatile("" : "+v"(W##i.x), "+v"(W##i.y), "+v"(W##i.z), "+v"(W##i.w));
#define WH_DOT(i)  { float4 xv = xp[i]; \
  a0 = fmaf(W##i.x, xv.x, a0); a1 = fmaf(W##i.y, xv.y, a1); \
  a2 = fmaf(W##i.z, xv.z, a2); a3 = fmaf(W##i.w, xv.w, a3); }
#define WH_ALL(OP) \
  OP(0) OP(1) OP(2) OP(3) OP(4) OP(5) OP(6) OP(7) OP(8) OP(9) \
  OP(10) OP(11) OP(12) OP(13) OP(14)

__global__ __launch_bounds__(256, 4) void k_max3s2(const float* __restrict__ wc3){
  __shared__ float xt[64*120];          // 30.7 KB
  int tid = threadIdx.x;
  int lane = tid & 63, wv = tid >> 6;
  int half = lane >> 5;                 // 0: c=0..59, 1: c=60..119
  int ec  = blockIdx.x & 7;
  int b   = (blockIdx.x >> 3) & 15;
  int seg = blockIdx.x >> 7;            // 0..7, 256 points each
  int e   = ec*128 + wv*32 + (lane & 31);
  WH_ALL(WH_DECL)
  {
    const float4* wp = (const float4*)(wc3 + (size_t)e*120 + half*60);
    WH_ALL(WH_LOAD)
  }
  WH_ALL(WH_PIN)
  float mx = NEG_BIG, mn = -NEG_BIG, S = 0.f, Q = 0.f;
  for (int tile=0; tile<4; tile++){
    int p0 = b*2048 + seg*256 + tile*64;
    __syncthreads();
    for (int v=tid; v<1920; v+=256){
      int pk = v/30, c4 = v%30;
      ((float4*)xt)[pk*30+c4] = *(const float4*)(g_xpf + (size_t)(p0+pk)*120 + c4*4);
    }
    __syncthreads();
    for (int k=0;k<64;k++){
      const float4* xp = (const float4*)(xt + k*120) + half*15;
      float a0=0.f,a1=0.f,a2=0.f,a3=0.f;
      WH_ALL(WH_DOT)
      float p = (a0+a1)+(a2+a3);
      float y = p + __shfl_xor(p, 32);  // combine halves
      mx = fmaxf(mx, y);
      mn = fminf(mn, y);
      S += y;
      Q = fmaf(y, y, Q);
    }
  }
  if (half == 0){
    float* MB = (float*)g_part;
    int slot = (seg*16+b)*1024 + e;
    MB[P3_MX + slot] = mx;
    MB[P3_MN + slot] = mn;
    MB[P3_S  + slot] = S;
    MB[P3_Q  + slot] = Q;
  }
}

// stage3 finalize: reduce 128 S/Q partials per channel -> A3/B3
__global__ __launch_bounds__(64) void k_fin3R(const float* __restrict__ gg, const float* __restrict__ bb){
  int e = blockIdx.x*64 + threadIdx.x;  // grid 16
  const float* MB = (const float*)g_part;
  double S=0.0, Q=0.0;
  for (int j=0;j<128;j++){
    S += (double)MB[P3_S + j*1024 + e];
    Q += (double)MB[P3_Q + j*1024 + e];
  }
  double inv3 = 1.0/(double)PP;
  double m = S*inv3;
  double v = Q*inv3 - m*m;
  if (v < 0.0) v = 0.0;
  float r = (float)(1.0/sqrt(v + 1e-5));
  float A = r*gg[e];
  g_st[S3A+e] = A;
  g_st[S3B+e] = bb[e] - (float)m*A;
}

// ---------------- VAE head: g from max/min + affine (monotone commute), then mu/lv/z
__global__ __launch_bounds__(256) void k_head(const float* __restrict__ eps,
                                              const float* __restrict__ wmu, const float* __restrict__ bmu,
                                              const float* __restrict__ wvar, const float* __restrict__ bvar,
                                              float* __restrict__ outb){
  int b = blockIdx.x, j = threadIdx.x;
  __shared__ float gs[1024];
  const float* MB = (const float*)g_part;
  for (int i=j;i<1024;i+=256){
    float A = g_st[S3A+i], B = g_st[S3B+i];
    float M = NEG_BIG, m2 = -NEG_BIG;
    #pragma unroll
    for (int sg=0;sg<8;sg++){
      M  = fmaxf(M,  MB[P3_MX + (sg*16+b)*1024 + i]);
      m2 = fminf(m2, MB[P3_MN + (sg*16+b)*1024 + i]);
    }
    float y = (A > 0.f) ? M : ((A < 0.f) ? m2 : M);
    gs[i] = lrelu(fmaf(A, y, B));
  }
  __syncthreads();
  float mu = bmu[j], lv = bvar[j];
  const float4* wm = (const float4*)(wmu + (size_t)j*1024);
  const float4* wv = (const float4*)(wvar + (size_t)j*1024);
  #pragma unroll 4
  for (int e=0;e<256;e++){
    float4 a = wm[e], c = wv[e];
    const float* g4 = gs + e*4;
    mu = fmaf(a.x,g4[0], fmaf(a.y,g4[1], fmaf(a.z,g4[2], fmaf(a.w,g4[3], mu))));
    lv = fmaf(c.x,g4[0], fmaf(c.y,g4[1], fmaf(c.z,g4[2], fmaf(c.w,g4[3], lv))));
  }
  float z = fmaf(eps[b*256+j], expf(0.5f*lv), mu);
  g_zf[b*256+j] = z;
  outb[O_MU + b*256 + j] = mu;
  outb[O_LV + b*256 + j] = lv;
  outb[O_Z  + b*256 + j] = z;
}

// ---------------- cuboid branch
__global__ __launch_bounds__(256) void k_cuboid(const float* __restrict__ wenc,
                                                const float* __restrict__ wcub1, const float* __restrict__ wcub2,
                                                const float* __restrict__ wk, float* __restrict__ outb){
  int b = blockIdx.x, t = threadIdx.x;
  __shared__ float xc[320*16];
  __shared__ float hh[256*16];
  __shared__ float xq[120*16];
  for (int i=t;i<320*16;i+=256){
    int c = i>>4, m = i&15;
    xc[i] = (c<256) ? g_zf[b*256+c] : lrelu(wenc[(c-256)*16+m]);
  }
  __syncthreads();
  {
    float acc[16];
    #pragma unroll
    for (int m=0;m<16;m++) acc[m]=0.f;
    for (int c=0;c<320;c++){
      float wv = wcub1[(size_t)t*320+c];
      #pragma unroll
      for (int m=0;m<16;m++) acc[m] = fmaf(wv, xc[c*16+m], acc[m]);
    }
    #pragma unroll
    for (int m=0;m<16;m++) hh[t*16+m] = lrelu(acc[m]);
  }
  __syncthreads();
  if (t<120){
    float a2[16];
    #pragma unroll
    for (int m=0;m<16;m++) a2[m]=0.f;
    for (int c=0;c<256;c++){
      float wv = wcub2[(size_t)t*256+c];
      #pragma unroll
      for (int m=0;m<16;m++) a2[m] = fmaf(wv, hh[c*16+m], a2[m]);
    }
    #pragma unroll
    for (int m=0;m<16;m++){
      float v = lrelu(a2[m]);
      xq[t*16+m] = v;
      outb[O_XCUB + b*1920 + t*16 + m] = v;
    }
  }
  __syncthreads();
  if (t<64){
    float a3[16];
    #pragma unroll
    for (int m=0;m<16;m++) a3[m]=0.f;
    for (int c=0;c<120;c++){
      float wv = wk[t*120+c];
      #pragma unroll
      for (int m=0;m<16;m++) a3[m] = fmaf(wv, xq[c*16+m], a3[m]);
    }
    #pragma unroll
    for (int m=0;m<16;m++) g_Kf[b*1024 + t*16 + m] = a3[m];
  }
}

// ---------------- attention
__global__ __launch_bounds__(64) void k_attn(const float* __restrict__ wq, float* __restrict__ outb){
  int p = blockIdx.x*64 + threadIdx.x;
  int b = p >> 11;
  float x[120];
  xrow(p, 0, 120, x);
  float sc[16];
  #pragma unroll
  for (int m=0;m<16;m++) sc[m]=0.f;
  for (int a=0;a<64;a++){
    float q=0.f;
    #pragma unroll
    for (int c=0;c<120;c++) q = fmaf(wq[a*120+c], x[c], q);
    q *= 0.125f;
    const float* kf = g_Kf + b*1024 + a*16;
    #pragma unroll
    for (int m=0;m<16;m++) sc[m] = fmaf(kf[m], q, sc[m]);
  }
  float mx = sc[0];
  #pragma unroll
  for (int m=1;m<16;m++) mx = fmaxf(mx, sc[m]);
  float s=0.f;
  #pragma unroll
  for (int m=0;m<16;m++){ sc[m] = expf(sc[m]-mx); s += sc[m]; }
  float inv = 1.f/s;
  #pragma unroll
  for (int m=0;m<16;m++) outb[O_ASG + (size_t)p*16 + m] = sc[m]*inv;
}

extern "C" void kernel_launch(void* const* d_in, const int* in_sizes, int n_in,
                              void* d_out, int out_size, void* d_ws, size_t ws_size,
                              hipStream_t stream){
  const float* xyz  = (const float*)d_in[0];
  const float* eps  = (const float*)d_in[2];
  const float* w1a  = (const float*)d_in[3];
  const float* w1b  = (const float*)d_in[4];
  const float* w2a  = (const float*)d_in[5];
  const float* w2b  = (const float*)d_in[6];
  const float* wc3  = (const float*)d_in[7];
  const float* wmu  = (const float*)d_in[8];
  const float* bmu  = (const float*)d_in[9];
  const float* wvar = (const float*)d_in[10];
  const float* bvar = (const float*)d_in[11];
  const float* wenc = (const float*)d_in[12];
  const float* wcub1= (const float*)d_in[13];
  const float* wcub2= (const float*)d_in[14];
  const float* wq   = (const float*)d_in[15];
  const float* wk   = (const float*)d_in[16];
  const float* g1a  = (const float*)d_in[17];
  const float* b1a  = (const float*)d_in[18];
  const float* g1b  = (const float*)d_in[19];
  const float* b1b  = (const float*)d_in[20];
  const float* g2a  = (const float*)d_in[21];
  const float* b2a  = (const float*)d_in[22];
  const float* g2b  = (const float*)d_in[23];
  const float* b2b  = (const float*)d_in[24];
  const float* g3   = (const float*)d_in[25];
  const float* b3   = (const float*)d_in[26];
  float* outb = (float*)d_out;

  const double inv1 = 1.0/(double)EE;

  k_knnt<<<2048,128,0,stream>>>(xyz);
  k_knnu<<<128,256,0,stream>>>();
  k_knns1<<<1024,256,0,stream>>>(xyz);
  k_knns2<<<128,256,0,stream>>>();
  k_knns3<<<1024,256,0,stream>>>(xyz);
  // stage 1 (stats1a via feat-Gram; conv1a eliminated)
  k_gram1<<<320,256,0,stream>>>(xyz);
  k_fing1<<<1,64,0,stream>>>(w1a, g1a, b1a);
  k_conv1b<<<1280,256,0,stream>>>(xyz, w1a, w1b);
  k_red60<<<128,256,0,stream>>>(S1B_D, 1280);
  k_fin<<<1,64,0,stream>>>(g1b, b1b, S1B_D, S1B_AB, inv1);
  k_final1s<<<7680,256,0,stream>>>(outb);
  // stage 2
  k_pgem2<<<128,256,0,stream>>>(w2a);
  k_conv2a<<<2560,256,0,stream>>>();
  k_red60<<<128,256,0,stream>>>(S2A_D, 2560);
  k_fin<<<1,64,0,stream>>>(g2a, b2a, S2A_D, S2A_AB, inv1);
  k_conv2b<<<1280,256,0,stream>>>(w2b);
  k_red60<<<128,256,0,stream>>>(S2B_D, 1280);
  k_fin<<<1,64,0,stream>>>(g2b, b2b, S2B_D, S2B_AB, inv1);
  k_final2s<<<7680,256,0,stream>>>(outb);
  // stage 3 (fused: half-channel register scheme; y3 never materialized)
  k_max3s2<<<1024,256,0,stream>>>(wc3);
  k_fin3R<<<16,64,0,stream>>>(g3, b3);
  // heads
  k_head<<<16,256,0,stream>>>(eps, wmu, bmu, wvar, bvar, outb);
  k_cuboid<<<16,256,0,stream>>>(wenc, wcub1, wcub2, wk, outb);
  k_attn<<<512,64,0,stream>>>(wq, outb);
}